// Round 2
// baseline (8500.265 us; speedup 1.0000x reference)
//
#include <hip/hip_runtime.h>
#include <hip/hip_bf16.h>
#include <cstdint>

#define C_NU 100000
#define C_NI 100000
#define C_DIM 64
#define C_Q 5
#define C_NE 2000000
#define C_B 4096
#define C_P 10
#define BROWS 128
#define BSH 7
#define NB 782   // ceil(100000/128)

// ---------------- Threefry-2x32 (JAX-compatible), 20 rounds ----------------
__host__ __device__ static inline void tf2x32(uint32_t k0, uint32_t k1,
                                              uint32_t& x0, uint32_t& x1) {
  uint32_t k2 = k0 ^ k1 ^ 0x1BD11BDAu;
#define TFR(r) { x0 += x1; x1 = (x1 << r) | (x1 >> (32 - r)); x1 ^= x0; }
  x0 += k0; x1 += k1;
  TFR(13) TFR(15) TFR(26) TFR(6)
  x0 += k1; x1 += k2 + 1u;
  TFR(17) TFR(29) TFR(16) TFR(24)
  x0 += k2; x1 += k0 + 2u;
  TFR(13) TFR(15) TFR(26) TFR(6)
  x0 += k0; x1 += k1 + 3u;
  TFR(17) TFR(29) TFR(16) TFR(24)
  x0 += k1; x1 += k2 + 4u;
  TFR(13) TFR(15) TFR(26) TFR(6)
  x0 += k2; x1 += k0 + 5u;
#undef TFR
}

// partitionable-mode random bits at flat index idx (hi counter = 0)
__device__ static inline float tf_uniform(uint32_t k0, uint32_t k1, uint32_t idx) {
  uint32_t x0 = 0u, x1 = idx;
  tf2x32(k0, k1, x0, x1);
  uint32_t bits = x0 ^ x1;
  return __uint_as_float((bits >> 9) | 0x3F800000u) - 1.0f;
}

__device__ static inline float leaky(float x) { return x >= 0.f ? x : 0.5f * x; }

// ---------------- constant maps for the 16 info_nce calls ----------------
// normbuf slots: 0:Zu1 1:Zu2 2:Zi1 3:Zi2 4:Zdu1 5:Zdu2 6:Zdi1 7:Zdi2 8:Gu1 9:Gu2 10:Gi1 11:Gi2
__constant__ int c_gsel[16] = {0,1,2,3, 0,2, 4,5,6,7, 4,6, 0,1,2,3};
__constant__ int c_hsrc[16] = {8,9,10,11, 1,3, 8,9,10,11, 5,7, 4,5,6,7};
// W order: 0:ng0 1:ng1 2:nn 3:dg0 4:dg1 5:dd 6:nd0 7:nd1
__constant__ int c_wsel[16] = {0,1,0,1, 2,2, 3,4,3,4, 5,5, 6,7,6,7};
// slots: 0:n 1:d 2:nn 3:dd 4:nd (5: loss_r sum)
__constant__ int c_slot[16] = {0,0,0,0, 2,2, 1,1,1,1, 3,3, 4,4,4,4};

struct WPtrs { const float* W[8]; };
struct NceKeys { uint32_t k0[16]; uint32_t k1[16]; };
struct DropKeys { uint32_t a[8]; };  // [d0l0k0,d0l0k1, d0l1k0,d0l1k1, d1l0k0,d1l0k1, d1l1k0,d1l1k1]

// ---------------- bucket build ----------------

__global__ __launch_bounds__(512) void hist_kernel(
    const int* __restrict__ rows, const int* __restrict__ cols,
    uint32_t* __restrict__ hist) {
  __shared__ uint32_t lh[2 * NB];
  const int tid = threadIdx.x;
  for (int i = tid; i < 2 * NB; i += 512) lh[i] = 0u;
  __syncthreads();
  for (int e = blockIdx.x * 512 + tid; e < C_NE; e += gridDim.x * 512) {
    atomicAdd(&lh[rows[e] >> BSH], 1u);
    atomicAdd(&lh[NB + (cols[e] >> BSH)], 1u);
  }
  __syncthreads();
  for (int i = tid; i < 2 * NB; i += 512)
    if (lh[i]) atomicAdd(&hist[i], lh[i]);
}

__global__ __launch_bounds__(1024) void scan_kernel(
    const uint32_t* __restrict__ hist, uint32_t* __restrict__ starts,
    uint32_t* __restrict__ cursors) {
  __shared__ uint32_t s[1024];
  const int t = threadIdx.x;
  for (int dir = 0; dir < 2; ++dir) {
    uint32_t h = (t < NB) ? hist[dir * NB + t] : 0u;
    s[t] = h;
    __syncthreads();
    for (int off = 1; off < 1024; off <<= 1) {
      uint32_t v = (t >= off) ? s[t - off] : 0u;
      __syncthreads();
      s[t] += v;
      __syncthreads();
    }
    if (t < NB) {
      starts[dir * (NB + 1) + t + 1] = s[t];
      cursors[dir * NB + t] = s[t] - h;
    }
    if (t == 0) starts[dir * (NB + 1)] = 0u;
    __syncthreads();
  }
}

__global__ __launch_bounds__(256) void scatter_kernel(
    const int* __restrict__ rows, const int* __restrict__ cols,
    const float* __restrict__ vals, uint32_t* __restrict__ cursors,
    uint32_t* __restrict__ pk0, float* __restrict__ bv0,
    uint32_t* __restrict__ pk1, float* __restrict__ bv1, DropKeys dk) {
  int e = blockIdx.x * 256 + threadIdx.x;
  if (e >= C_NE) return;
  const int r = rows[e], c = cols[e];
  const float v = vals[e];
  const uint32_t ue = (uint32_t)e;
  uint32_t k00 = (tf_uniform(dk.a[0], dk.a[1], ue) < 0.9f) ? 1u : 0u;
  uint32_t k01 = (tf_uniform(dk.a[2], dk.a[3], ue) < 0.9f) ? 1u : 0u;
  uint32_t k10 = (tf_uniform(dk.a[4], dk.a[5], ue) < 0.9f) ? 1u : 0u;
  uint32_t k11 = (tf_uniform(dk.a[6], dk.a[7], ue) < 0.9f) ? 1u : 0u;
  uint32_t p0 = (uint32_t)c | ((uint32_t)(r & 127) << 17) | (k00 << 24) | (k01 << 25);
  uint32_t s0 = atomicAdd(&cursors[r >> BSH], 1u);
  pk0[s0] = p0; bv0[s0] = v;
  uint32_t p1 = (uint32_t)r | ((uint32_t)(c & 127) << 17) | (k10 << 24) | (k11 << 25);
  uint32_t s1 = atomicAdd(&cursors[NB + (c >> BSH)], 1u);
  pk1[s1] = p1; bv1[s1] = v;
}

// ---------------- fused spmm + act + noise + residual update ----------------
__global__ __launch_bounds__(512) void spmm_fused(
    const uint32_t* __restrict__ bpk, const float* __restrict__ bvl,
    const uint32_t* __restrict__ starts, const float* __restrict__ Ein,
    const float* __restrict__ Eprev, float* __restrict__ Enext,
    float* __restrict__ Zout, float* __restrict__ Zdout,
    uint32_t nk0, uint32_t nk1, int layer, int nrows) {
  __shared__ float Zs[BROWS * 64];
  __shared__ float Zds[BROWS * 64];
  const int tid = threadIdx.x, lane = tid & 63, wid = tid >> 6;
  for (int i = tid; i < BROWS * 64; i += 512) { Zs[i] = 0.f; Zds[i] = 0.f; }
  __syncthreads();
  const int b = blockIdx.x;
  const uint32_t s0 = starts[b];
  const int cnt = (int)(starts[b + 1] - s0);
  const float inv_keep = 1.0f / 0.9f;
  for (int base = wid << 6; base < cnt; base += 512) {
    const int n = min(64, cnt - base);
    uint32_t pkv = 0u; float vv = 0.f;
    if (lane < n) {
      pkv = bpk[s0 + base + lane];
      vv = bvl[s0 + base + lane];
    }
    if (n == 64) {
#pragma unroll 8
      for (int k = 0; k < 64; ++k) {
        const uint32_t p = (uint32_t)__shfl((int)pkv, k);
        const float vk = __shfl(vv, k);
        const float x = Ein[(size_t)(p & 0x1FFFFu) * 64 + lane];
        const int o = (int)((p >> 17) & 127u) * 64 + lane;
        atomicAdd(&Zs[o], vk * x);
        if ((p >> (24 + layer)) & 1u) atomicAdd(&Zds[o], vk * inv_keep * x);
      }
    } else {
      for (int k = 0; k < n; ++k) {
        const uint32_t p = (uint32_t)__shfl((int)pkv, k);
        const float vk = __shfl(vv, k);
        const float x = Ein[(size_t)(p & 0x1FFFFu) * 64 + lane];
        const int o = (int)((p >> 17) & 127u) * 64 + lane;
        atomicAdd(&Zs[o], vk * x);
        if ((p >> (24 + layer)) & 1u) atomicAdd(&Zds[o], vk * inv_keep * x);
      }
    }
  }
  __syncthreads();
  const int row0 = b * BROWS;
  const int rh = min(BROWS, nrows - row0);
  for (int r = wid; r < rh; r += 8) {
    const uint32_t gr = (uint32_t)(row0 + r);
    float z = leaky(Zs[r * 64 + lane]);
    const float zd = leaky(Zds[r * 64 + lane]);
    const float u = tf_uniform(nk0, nk1, gr * 64u + (uint32_t)lane);
    float ss = u * u;
#pragma unroll
    for (int off = 1; off < 64; off <<= 1) ss += __shfl_xor(ss, off);
    const float nrm = fmaxf(sqrtf(ss), 1e-12f);
    const float sg = (z > 0.f) ? 1.f : (z < 0.f ? -1.f : 0.f);
    z += sg * (u / nrm) * 0.1f;
    const size_t j = (size_t)gr * 64 + lane;
    const float en = z + zd + Eprev[j];
    Zout[j] = z;
    Zdout[j] = zd;
    Enext[j] = en;
  }
}

// M[q][d] = sum_n T[q][n] * E[n][d]   (T is [5][n] row-major)
__global__ __launch_bounds__(256) void svd_reduce(
    const float* __restrict__ T, const float* __restrict__ E,
    float* __restrict__ M, int n) {
  int wid = (int)(((long long)blockIdx.x * blockDim.x + threadIdx.x) >> 6);
  int lane = threadIdx.x & 63;
  int nw = (gridDim.x * blockDim.x) >> 6;
  float acc[5] = {0.f, 0.f, 0.f, 0.f, 0.f};
  for (int i = wid; i < n; i += nw) {
    float x = E[(size_t)i * 64 + lane];
#pragma unroll
    for (int q = 0; q < 5; ++q) acc[q] += T[(size_t)q * n + i] * x;
  }
#pragma unroll
  for (int q = 0; q < 5; ++q) atomicAdd(&M[q * 64 + lane], acc[q]);
}

// gather batch rows & L2-normalize; blockIdx.y selects {Z, Zd, G}
__global__ __launch_bounds__(256) void gather_norm(
    const int* __restrict__ ids, const float* __restrict__ Z,
    const float* __restrict__ Zd, const float* __restrict__ mul_s,
    const float* __restrict__ M, float* __restrict__ oZ,
    float* __restrict__ oZd, float* __restrict__ oG) {
  long long t = (long long)blockIdx.x * blockDim.x + threadIdx.x;
  int b = (int)(t >> 6);
  int d = (int)(t & 63);
  if (b >= C_B) return;
  int id = ids[b];
  float v;
  float* out;
  if (blockIdx.y == 0) { v = Z[(size_t)id * 64 + d]; out = oZ; }
  else if (blockIdx.y == 1) { v = Zd[(size_t)id * 64 + d]; out = oZd; }
  else {
    float s = 0.f;
#pragma unroll
    for (int q = 0; q < 5; ++q) s += mul_s[(size_t)id * 5 + q] * M[q * 64 + d];
    v = leaky(s);
    out = oG;
  }
  float ss = v * v;
#pragma unroll
  for (int off = 1; off < 64; off <<= 1) ss += __shfl_xor(ss, off);
  float nrm = fmaxf(sqrtf(ss), 1e-12f);
  out[(size_t)b * 64 + d] = v / nrm;
}

// hyper[call] = normbuf[hsrc[call]] @ W[wsel[call]]
__global__ __launch_bounds__(256) void hyper_kernel(
    const float* __restrict__ normbuf, float* __restrict__ hyper, WPtrs wp) {
  int call = blockIdx.y;
  long long t = (long long)blockIdx.x * blockDim.x + threadIdx.x;
  int b = (int)(t >> 6);
  int d = (int)(t & 63);
  if (b >= C_B) return;
  const float* xn = normbuf + (size_t)c_hsrc[call] * C_B * 64 + (size_t)b * 64;
  const float* W = wp.W[c_wsel[call]];
  float x = xn[d];
  float h = 0.f;
  for (int k = 0; k < 64; ++k) {
    float xk = __shfl(x, k);
    h += xk * W[k * 64 + d];
  }
  hyper[(size_t)call * C_B * 64 + (size_t)b * 64 + d] = h;
}

// LDS chunk swizzle: spreads strided row reads across banks
__device__ static inline int swz(int r, int c) {
  int chunk = (c >> 2) ^ ((r + (r >> 2)) & 15);
  return r * 64 + (chunk << 2) + (c & 3);
}
__device__ static inline int swz4(int r, int k4) {
  return r * 64 + (((k4 ^ ((r + (r >> 2)) & 15))) << 2);
}

// fused info_nce: scores=gnn@hyper^T, exp, row-sum, diag, mask, reduce
__global__ __launch_bounds__(256) void nce_kernel(
    const float* __restrict__ normbuf, const float* __restrict__ hyper,
    float* __restrict__ slots, NceKeys nk) {
  const int call = blockIdx.y;
  const float* G = normbuf + (size_t)c_gsel[call] * C_B * 64;
  const float* H = hyper + (size_t)call * C_B * 64;
  const int br = blockIdx.x * 64;
  __shared__ float Gt[64 * 64];
  __shared__ float Ht[64 * 64];
  __shared__ float red[64][17];
  __shared__ float posr[64];
  const int tid = threadIdx.x;
  for (int i = tid; i < 64 * 64; i += 256) {
    int r = i >> 6, c = i & 63;
    Gt[swz(r, c)] = G[(size_t)(br + r) * 64 + c];
  }
  const int ty = tid >> 4, tx = tid & 15;
  float rs[4] = {0.f, 0.f, 0.f, 0.f};
  float ps[4] = {0.f, 0.f, 0.f, 0.f};
  for (int jt = 0; jt < C_B / 64; ++jt) {
    __syncthreads();
    for (int i = tid; i < 64 * 64; i += 256) {
      int r = i >> 6, c = i & 63;
      Ht[swz(r, c)] = H[(size_t)(jt * 64 + r) * 64 + c];
    }
    __syncthreads();
    float s[4][4] = {};
    for (int k4 = 0; k4 < 16; ++k4) {
      float4 g[4], h[4];
#pragma unroll
      for (int i = 0; i < 4; ++i) g[i] = *(const float4*)&Gt[swz4(ty * 4 + i, k4)];
#pragma unroll
      for (int j = 0; j < 4; ++j) h[j] = *(const float4*)&Ht[swz4(tx * 4 + j, k4)];
#pragma unroll
      for (int i = 0; i < 4; ++i)
#pragma unroll
        for (int j = 0; j < 4; ++j)
          s[i][j] += g[i].x * h[j].x + g[i].y * h[j].y + g[i].z * h[j].z + g[i].w * h[j].w;
    }
#pragma unroll
    for (int i = 0; i < 4; ++i) {
      int grow = br + ty * 4 + i;
#pragma unroll
      for (int j = 0; j < 4; ++j) {
        float e = __expf(s[i][j] * 5.0f);  // /TEMP
        rs[i] += e;
        if (jt * 64 + tx * 4 + j == grow) ps[i] = e;
      }
    }
  }
#pragma unroll
  for (int i = 0; i < 4; ++i) {
    red[ty * 4 + i][tx] = rs[i];
    if (ps[i] != 0.f) posr[ty * 4 + i] = ps[i];
  }
  __syncthreads();
  if (tid < 64) {
    float ns = 0.f;
#pragma unroll
    for (int k = 0; k < 16; ++k) ns += red[tid][k];
    float p = posr[tid];
    float v = -__logf(p / (ns + 1e-8f) + 1e-8f);
    int b = br + tid;
    float u = tf_uniform(nk.k0[call], nk.k1[call], (uint32_t)b);
    float contrib = (u > 0.5f) ? v : 0.f;
    for (int off = 32; off; off >>= 1) contrib += __shfl_down(contrib, off);
    if (tid == 0) atomicAdd(&slots[c_slot[call]], contrib);
  }
}

__global__ __launch_bounds__(256) void loss_r_kernel(
    const float* __restrict__ E0u, const float* __restrict__ Eu1,
    const float* __restrict__ Eu2, const float* __restrict__ E0i,
    const float* __restrict__ Ei1, const float* __restrict__ Ei2,
    const int* __restrict__ uids, const int* __restrict__ pos,
    const int* __restrict__ neg, float* __restrict__ slots) {
  long long t = (long long)blockIdx.x * blockDim.x + threadIdx.x;
  int b = (int)(t >> 6);
  int d = (int)(t & 63);
  if (b >= C_B) return;
  size_t ju = (size_t)uids[b] * 64 + d;
  float u = E0u[ju] + Eu1[ju] + Eu2[ju];
  float bpr = 0.f, pmin = 3.4e38f, nmax = -3.4e38f;
  for (int p = 0; p < C_P; ++p) {
    size_t jp = (size_t)pos[b * C_P + p] * 64 + d;
    size_t jn = (size_t)neg[b * C_P + p] * 64 + d;
    float pe = E0i[jp] + Ei1[jp] + Ei2[jp];
    float ne = E0i[jn] + Ei1[jn] + Ei2[jn];
    float psc = u * pe, nsc = u * ne;
#pragma unroll
    for (int off = 1; off < 64; off <<= 1) {
      psc += __shfl_xor(psc, off);
      nsc += __shfl_xor(nsc, off);
    }
    pmin = fminf(pmin, psc);
    nmax = fmaxf(nmax, nsc);
    bpr += fmaxf(1.f - psc + nsc, 0.f);
  }
  if (d == 0) {
    float hd = (nmax - pmin > 0.005f) ? 10.f * (nmax - pmin) : 0.f;
    atomicAdd(&slots[5], bpr + hd);
  }
}

__global__ void final_kernel(const float* __restrict__ slots, float* __restrict__ out) {
  if (threadIdx.x == 0 && blockIdx.x == 0) {
    float n = slots[0], dl = slots[1], nn = slots[2], dd = slots[3], nd = slots[4];
    float lr = slots[5] / (float)C_B;
    out[0] = lr + 0.2f * (n + dl) + 0.2f * (nn + dd + nd);
    out[1] = lr;
    out[2] = dl;
    out[3] = n;
  }
}

// ---------------- host ----------------
extern "C" void kernel_launch(void* const* d_in, const int* in_sizes, int n_in,
                              void* d_out, int out_size, void* d_ws, size_t ws_size,
                              hipStream_t stream) {
  (void)in_sizes; (void)n_in; (void)out_size;
  const float* E_u_0   = (const float*)d_in[0];
  const float* E_i_0   = (const float*)d_in[1];
  const float* adjvals = (const float*)d_in[2];
  const float* u_mul_s = (const float*)d_in[3];
  const float* v_mul_s = (const float*)d_in[4];
  const float* ut      = (const float*)d_in[5];
  const float* vt      = (const float*)d_in[6];
  const float* W_nn    = (const float*)d_in[7];
  const float* W_dd    = (const float*)d_in[8];
  const float* W_ng    = (const float*)d_in[9];
  const float* W_dg    = (const float*)d_in[10];
  const float* W_nd    = (const float*)d_in[11];
  const int* adj_rows  = (const int*)d_in[12];
  const int* adj_cols  = (const int*)d_in[13];
  const int* uids      = (const int*)d_in[14];
  const int* iids      = (const int*)d_in[15];
  const int* pos       = (const int*)d_in[16];
  const int* neg       = (const int*)d_in[17];
  float* out = (float*)d_out;

  const size_t NU64 = (size_t)C_NU * 64;
  const size_t NI64 = (size_t)C_NI * 64;
  const size_t B64  = (size_t)C_B * 64;

  float* w = (float*)d_ws;
  float* Eu1 = w; w += NU64;
  float* Eu2 = w; w += NU64;
  float* Ei1 = w; w += NI64;
  float* Ei2 = w; w += NI64;
  float* Zu  = w; w += NU64;
  float* Zdu = w; w += NU64;
  float* Zi  = w; w += NI64;
  float* Zdi = w; w += NI64;
  float* Mu = w; w += 512;
  float* Mi = w; w += 512;
  float* normbuf = w; w += 12 * B64;
  float* hyper = w; w += 16 * B64;
  float* slots = w; w += 16;
  uint32_t* hist = (uint32_t*)w; w += 2 * NB;
  uint32_t* starts = (uint32_t*)w; w += 2 * (NB + 1);
  uint32_t* cursors = (uint32_t*)w; w += 2 * NB;
  uint32_t* pk0 = (uint32_t*)w; w += C_NE;
  float* bv0 = w; w += C_NE;
  uint32_t* pk1 = (uint32_t*)w; w += C_NE;
  float* bv1 = w; w += C_NE;
  if ((size_t)((char*)w - (char*)d_ws) > ws_size) return;  // ws too small

  // ---- host-side JAX key derivation (partitionable threefry) ----
  auto ksplit = [](uint32_t a, uint32_t b, uint32_t idx, uint32_t& o0, uint32_t& o1) {
    uint32_t x0 = 0u, x1 = idx;
    tf2x32(a, b, x0, x1);
    o0 = x0; o1 = x1;
  };
  uint32_t rk0 = 0u, rk1 = 42u;
  uint32_t lk[2][4][2];  // [layer][k1 dropU, k2 dropI, k3 noiseU, k4 noiseI][pair]
  for (int l = 0; l < 2; ++l) {
    uint32_t n0, n1;
    ksplit(rk0, rk1, 0u, n0, n1);
    for (int i = 0; i < 4; ++i) ksplit(rk0, rk1, (uint32_t)(i + 1), lk[l][i][0], lk[l][i][1]);
    rk0 = n0; rk1 = n1;
  }
  NceKeys nk;
  {
    uint32_t mk0 = 0u, mk1 = 7u;
    for (int i = 0; i < 16; ++i) {
      uint32_t n0, n1;
      ksplit(mk0, mk1, 0u, n0, n1);
      ksplit(mk0, mk1, 1u, nk.k0[i], nk.k1[i]);
      mk0 = n0; mk1 = n1;
    }
  }
  DropKeys dk;
  dk.a[0] = lk[0][0][0]; dk.a[1] = lk[0][0][1];  // dir0 layer0
  dk.a[2] = lk[1][0][0]; dk.a[3] = lk[1][0][1];  // dir0 layer1
  dk.a[4] = lk[0][1][0]; dk.a[5] = lk[0][1][1];  // dir1 layer0
  dk.a[6] = lk[1][1][0]; dk.a[7] = lk[1][1][1];  // dir1 layer1
  WPtrs wp;
  wp.W[0] = W_ng; wp.W[1] = W_ng + 4096;
  wp.W[2] = W_nn;
  wp.W[3] = W_dg; wp.W[4] = W_dg + 4096;
  wp.W[5] = W_dd;
  wp.W[6] = W_nd; wp.W[7] = W_nd + 4096;

  // ---- build buckets (once; shared by both layers) ----
  hipMemsetAsync(hist, 0, 2 * NB * 4, stream);
  hipMemsetAsync(slots, 0, 16 * 4, stream);
  hist_kernel<<<256, 512, 0, stream>>>(adj_rows, adj_cols, hist);
  scan_kernel<<<1, 1024, 0, stream>>>(hist, starts, cursors);
  scatter_kernel<<<(C_NE + 255) / 256, 256, 0, stream>>>(
      adj_rows, adj_cols, adjvals, cursors, pk0, bv0, pk1, bv1, dk);

  const int gb = (int)(B64 / 256);  // 1024

  for (int l = 0; l < 2; ++l) {
    const float* Eu_prev = (l == 0) ? E_u_0 : Eu1;
    const float* Ei_prev = (l == 0) ? E_i_0 : Ei1;
    float* Eu_next = (l == 0) ? Eu1 : Eu2;
    float* Ei_next = (l == 0) ? Ei1 : Ei2;
    hipMemsetAsync(Mu, 0, 1024 * 4, stream);
    svd_reduce<<<1024, 256, 0, stream>>>(vt, Ei_prev, Mu, C_NI);
    svd_reduce<<<1024, 256, 0, stream>>>(ut, Eu_prev, Mi, C_NU);
    // dir0: gather items -> users
    spmm_fused<<<NB, 512, 0, stream>>>(pk0, bv0, starts, Ei_prev, Eu_prev,
                                       Eu_next, Zu, Zdu,
                                       lk[l][2][0], lk[l][2][1], l, C_NU);
    // dir1: gather users -> items
    spmm_fused<<<NB, 512, 0, stream>>>(pk1, bv1, starts + (NB + 1), Eu_prev,
                                       Ei_prev, Ei_next, Zi, Zdi,
                                       lk[l][3][0], lk[l][3][1], l, C_NI);
    gather_norm<<<dim3(gb, 3), 256, 0, stream>>>(
        uids, Zu, Zdu, u_mul_s, Mu,
        normbuf + (size_t)(0 + l) * B64, normbuf + (size_t)(4 + l) * B64,
        normbuf + (size_t)(8 + l) * B64);
    gather_norm<<<dim3(gb, 3), 256, 0, stream>>>(
        iids, Zi, Zdi, v_mul_s, Mi,
        normbuf + (size_t)(2 + l) * B64, normbuf + (size_t)(6 + l) * B64,
        normbuf + (size_t)(10 + l) * B64);
  }

  hyper_kernel<<<dim3(gb, 16), 256, 0, stream>>>(normbuf, hyper, wp);
  nce_kernel<<<dim3(C_B / 64, 16), 256, 0, stream>>>(normbuf, hyper, slots, nk);
  loss_r_kernel<<<gb, 256, 0, stream>>>(E_u_0, Eu1, Eu2, E_i_0, Ei1, Ei2,
                                        uids, pos, neg, slots);
  final_kernel<<<1, 1, 0, stream>>>(slots, out);
}

// Round 3
// 2264.983 us; speedup vs baseline: 3.7529x; 3.7529x over previous
//
#include <hip/hip_runtime.h>
#include <hip/hip_bf16.h>
#include <cstdint>

#define C_NU 100000
#define C_NI 100000
#define C_DIM 64
#define C_Q 5
#define C_NE 2000000
#define C_B 4096
#define C_P 10
#define NROW 100000
#define NBLK1 196   // ceil(100000/512)

// ---------------- Threefry-2x32 (JAX-compatible), 20 rounds ----------------
__host__ __device__ static inline void tf2x32(uint32_t k0, uint32_t k1,
                                              uint32_t& x0, uint32_t& x1) {
  uint32_t k2 = k0 ^ k1 ^ 0x1BD11BDAu;
#define TFR(r) { x0 += x1; x1 = (x1 << r) | (x1 >> (32 - r)); x1 ^= x0; }
  x0 += k0; x1 += k1;
  TFR(13) TFR(15) TFR(26) TFR(6)
  x0 += k1; x1 += k2 + 1u;
  TFR(17) TFR(29) TFR(16) TFR(24)
  x0 += k2; x1 += k0 + 2u;
  TFR(13) TFR(15) TFR(26) TFR(6)
  x0 += k0; x1 += k1 + 3u;
  TFR(17) TFR(29) TFR(16) TFR(24)
  x0 += k1; x1 += k2 + 4u;
  TFR(13) TFR(15) TFR(26) TFR(6)
  x0 += k2; x1 += k0 + 5u;
#undef TFR
}

// partitionable-mode random bits at flat index idx (hi counter = 0)
__device__ static inline float tf_uniform(uint32_t k0, uint32_t k1, uint32_t idx) {
  uint32_t x0 = 0u, x1 = idx;
  tf2x32(k0, k1, x0, x1);
  uint32_t bits = x0 ^ x1;
  return __uint_as_float((bits >> 9) | 0x3F800000u) - 1.0f;
}

__device__ static inline float leaky(float x) { return x >= 0.f ? x : 0.5f * x; }

// ---------------- constant maps for the 16 info_nce calls ----------------
// normbuf slots: 0:Zu1 1:Zu2 2:Zi1 3:Zi2 4:Zdu1 5:Zdu2 6:Zdi1 7:Zdi2 8:Gu1 9:Gu2 10:Gi1 11:Gi2
__constant__ int c_gsel[16] = {0,1,2,3, 0,2, 4,5,6,7, 4,6, 0,1,2,3};
__constant__ int c_hsrc[16] = {8,9,10,11, 1,3, 8,9,10,11, 5,7, 4,5,6,7};
// W order: 0:ng0 1:ng1 2:nn 3:dg0 4:dg1 5:dd 6:nd0 7:nd1
__constant__ int c_wsel[16] = {0,1,0,1, 2,2, 3,4,3,4, 5,5, 6,7,6,7};
// slots: 0:n 1:d 2:nn 3:dd 4:nd (5: loss_r sum)
__constant__ int c_slot[16] = {0,0,0,0, 2,2, 1,1,1,1, 3,3, 4,4,4,4};

struct WPtrs { const float* W[8]; };
struct NceKeys { uint32_t k0[16]; uint32_t k1[16]; };
struct DropKeys { uint32_t a[8]; };  // [d0l0, d0l1, d1l0, d1l1] key pairs

// ---------------- per-row bucket build ----------------

__global__ __launch_bounds__(256) void hist_kernel(
    const int* __restrict__ rows, const int* __restrict__ cols,
    uint32_t* __restrict__ hist) {
  for (int e = blockIdx.x * 256 + threadIdx.x; e < C_NE; e += gridDim.x * 256) {
    atomicAdd(&hist[rows[e]], 1u);
    atomicAdd(&hist[NROW + cols[e]], 1u);
  }
}

// block-local exclusive scan of 512-entry chunks; writes block sums
__global__ __launch_bounds__(512) void scan1_kernel(
    const uint32_t* __restrict__ hist, uint32_t* __restrict__ starts,
    uint32_t* __restrict__ bsum) {
  __shared__ uint32_t s[512];
  const int dir = blockIdx.y, b = blockIdx.x, t = threadIdx.x;
  const int idx = b * 512 + t;
  uint32_t v = (idx < NROW) ? hist[dir * NROW + idx] : 0u;
  s[t] = v;
  __syncthreads();
  for (int off = 1; off < 512; off <<= 1) {
    uint32_t a = (t >= off) ? s[t - off] : 0u;
    __syncthreads();
    s[t] += a;
    __syncthreads();
  }
  if (idx < NROW) starts[dir * (NROW + 1) + idx] = s[t] - v;  // local exclusive
  if (t == 511) bsum[dir * NBLK1 + b] = s[511];
}

// scan the per-block sums -> block offsets; set sentinel totals
__global__ __launch_bounds__(256) void scan2_kernel(
    const uint32_t* __restrict__ bsum, uint32_t* __restrict__ boff,
    uint32_t* __restrict__ starts) {
  __shared__ uint32_t s[256];
  const int t = threadIdx.x;
  for (int dir = 0; dir < 2; ++dir) {
    uint32_t v = (t < NBLK1) ? bsum[dir * NBLK1 + t] : 0u;
    s[t] = v;
    __syncthreads();
    for (int off = 1; off < 256; off <<= 1) {
      uint32_t a = (t >= off) ? s[t - off] : 0u;
      __syncthreads();
      s[t] += a;
      __syncthreads();
    }
    if (t < NBLK1) boff[dir * NBLK1 + t] = s[t] - v;  // exclusive
    if (t == 255) starts[dir * (NROW + 1) + NROW] = s[255];  // total
    __syncthreads();
  }
}

// add block offsets; init cursors (cursors aliases hist memory)
__global__ __launch_bounds__(512) void scan3_kernel(
    uint32_t* __restrict__ starts, const uint32_t* __restrict__ boff,
    uint32_t* __restrict__ cursors) {
  const int dir = blockIdx.y, b = blockIdx.x, t = threadIdx.x;
  const int idx = b * 512 + t;
  if (idx >= NROW) return;
  uint32_t st = starts[dir * (NROW + 1) + idx] + boff[dir * NBLK1 + b];
  starts[dir * (NROW + 1) + idx] = st;
  cursors[dir * NROW + idx] = st;
}

// pack edges into per-row CSR order; keep bits from threefry on original edge id
__global__ __launch_bounds__(256) void scatter_kernel(
    const int* __restrict__ rows, const int* __restrict__ cols,
    const float* __restrict__ vals, uint32_t* __restrict__ cursors,
    uint2* __restrict__ edges0, uint2* __restrict__ edges1, DropKeys dk) {
  int e = blockIdx.x * 256 + threadIdx.x;
  if (e >= C_NE) return;
  const int r = rows[e], c = cols[e];
  const uint32_t vb = __float_as_uint(vals[e]);
  const uint32_t ue = (uint32_t)e;
  uint32_t k00 = (tf_uniform(dk.a[0], dk.a[1], ue) < 0.9f) ? 1u : 0u;
  uint32_t k01 = (tf_uniform(dk.a[2], dk.a[3], ue) < 0.9f) ? 1u : 0u;
  uint32_t k10 = (tf_uniform(dk.a[4], dk.a[5], ue) < 0.9f) ? 1u : 0u;
  uint32_t k11 = (tf_uniform(dk.a[6], dk.a[7], ue) < 0.9f) ? 1u : 0u;
  uint32_t s0 = atomicAdd(&cursors[r], 1u);
  edges0[s0] = make_uint2((uint32_t)c | (k00 << 17) | (k01 << 18), vb);
  uint32_t s1 = atomicAdd(&cursors[NROW + c], 1u);
  edges1[s1] = make_uint2((uint32_t)r | (k10 << 17) | (k11 << 18), vb);
}

// ---------------- fused spmm (one wave per dst row) ----------------
__global__ __launch_bounds__(256) void spmm_row(
    const uint2* __restrict__ edges, const uint32_t* __restrict__ starts,
    const float* __restrict__ Ein, const float* __restrict__ Eprev,
    float* __restrict__ Enext, float* __restrict__ Zout,
    float* __restrict__ Zdout, uint32_t nk0, uint32_t nk1, int layer) {
  const int row = blockIdx.x * 4 + (threadIdx.x >> 6);
  const int lane = threadIdx.x & 63;
  if (row >= NROW) return;
  const uint32_t s0 = starts[row], s1 = starts[row + 1];
  const uint32_t kbit = 1u << (17 + layer);
  float z = 0.f, zd = 0.f;
  uint32_t e = s0;
  for (; e + 4 <= s1; e += 4) {
    const uint2 q0 = edges[e], q1 = edges[e + 1], q2 = edges[e + 2], q3 = edges[e + 3];
    const float x0 = Ein[(size_t)(q0.x & 0x1FFFFu) * 64 + lane];
    const float x1 = Ein[(size_t)(q1.x & 0x1FFFFu) * 64 + lane];
    const float x2 = Ein[(size_t)(q2.x & 0x1FFFFu) * 64 + lane];
    const float x3 = Ein[(size_t)(q3.x & 0x1FFFFu) * 64 + lane];
    const float t0 = __uint_as_float(q0.y) * x0;
    const float t1 = __uint_as_float(q1.y) * x1;
    const float t2 = __uint_as_float(q2.y) * x2;
    const float t3 = __uint_as_float(q3.y) * x3;
    z += t0; if (q0.x & kbit) zd += t0;
    z += t1; if (q1.x & kbit) zd += t1;
    z += t2; if (q2.x & kbit) zd += t2;
    z += t3; if (q3.x & kbit) zd += t3;
  }
  for (; e < s1; ++e) {
    const uint2 q = edges[e];
    const float x = Ein[(size_t)(q.x & 0x1FFFFu) * 64 + lane];
    const float t = __uint_as_float(q.y) * x;
    z += t; if (q.x & kbit) zd += t;
  }
  z = leaky(z);
  zd = leaky(zd * (1.0f / 0.9f));
  // noise-augmented view
  const float u = tf_uniform(nk0, nk1, (uint32_t)row * 64u + (uint32_t)lane);
  float ss = u * u;
#pragma unroll
  for (int off = 1; off < 64; off <<= 1) ss += __shfl_xor(ss, off);
  const float nrm = fmaxf(sqrtf(ss), 1e-12f);
  const float sg = (z > 0.f) ? 1.f : (z < 0.f ? -1.f : 0.f);
  z += sg * (u / nrm) * 0.1f;
  const size_t j = (size_t)row * 64 + lane;
  const float en = z + zd + Eprev[j];
  Zout[j] = z;
  Zdout[j] = zd;
  Enext[j] = en;
}

// M[q][d] = sum_n T[q][n] * E[n][d]   (T is [5][n] row-major)
__global__ __launch_bounds__(256) void svd_reduce(
    const float* __restrict__ T, const float* __restrict__ E,
    float* __restrict__ M, int n) {
  int wid = (int)(((long long)blockIdx.x * blockDim.x + threadIdx.x) >> 6);
  int lane = threadIdx.x & 63;
  int nw = (gridDim.x * blockDim.x) >> 6;
  float acc[5] = {0.f, 0.f, 0.f, 0.f, 0.f};
  for (int i = wid; i < n; i += nw) {
    float x = E[(size_t)i * 64 + lane];
#pragma unroll
    for (int q = 0; q < 5; ++q) acc[q] += T[(size_t)q * n + i] * x;
  }
#pragma unroll
  for (int q = 0; q < 5; ++q) atomicAdd(&M[q * 64 + lane], acc[q]);
}

// gather batch rows & L2-normalize; blockIdx.y selects {Z, Zd, G}
__global__ __launch_bounds__(256) void gather_norm(
    const int* __restrict__ ids, const float* __restrict__ Z,
    const float* __restrict__ Zd, const float* __restrict__ mul_s,
    const float* __restrict__ M, float* __restrict__ oZ,
    float* __restrict__ oZd, float* __restrict__ oG) {
  long long t = (long long)blockIdx.x * blockDim.x + threadIdx.x;
  int b = (int)(t >> 6);
  int d = (int)(t & 63);
  if (b >= C_B) return;
  int id = ids[b];
  float v;
  float* out;
  if (blockIdx.y == 0) { v = Z[(size_t)id * 64 + d]; out = oZ; }
  else if (blockIdx.y == 1) { v = Zd[(size_t)id * 64 + d]; out = oZd; }
  else {
    float s = 0.f;
#pragma unroll
    for (int q = 0; q < 5; ++q) s += mul_s[(size_t)id * 5 + q] * M[q * 64 + d];
    v = leaky(s);
    out = oG;
  }
  float ss = v * v;
#pragma unroll
  for (int off = 1; off < 64; off <<= 1) ss += __shfl_xor(ss, off);
  float nrm = fmaxf(sqrtf(ss), 1e-12f);
  out[(size_t)b * 64 + d] = v / nrm;
}

// hyper[call] = normbuf[hsrc[call]] @ W[wsel[call]]
__global__ __launch_bounds__(256) void hyper_kernel(
    const float* __restrict__ normbuf, float* __restrict__ hyper, WPtrs wp) {
  int call = blockIdx.y;
  long long t = (long long)blockIdx.x * blockDim.x + threadIdx.x;
  int b = (int)(t >> 6);
  int d = (int)(t & 63);
  if (b >= C_B) return;
  const float* xn = normbuf + (size_t)c_hsrc[call] * C_B * 64 + (size_t)b * 64;
  const float* W = wp.W[c_wsel[call]];
  float x = xn[d];
  float h = 0.f;
  for (int k = 0; k < 64; ++k) {
    float xk = __shfl(x, k);
    h += xk * W[k * 64 + d];
  }
  hyper[(size_t)call * C_B * 64 + (size_t)b * 64 + d] = h;
}

// LDS chunk swizzle: spreads strided row reads across banks
__device__ static inline int swz(int r, int c) {
  int chunk = (c >> 2) ^ ((r + (r >> 2)) & 15);
  return r * 64 + (chunk << 2) + (c & 3);
}
__device__ static inline int swz4(int r, int k4) {
  return r * 64 + (((k4 ^ ((r + (r >> 2)) & 15))) << 2);
}

// fused info_nce: scores=gnn@hyper^T, exp, row-sum, diag, mask, reduce
__global__ __launch_bounds__(256) void nce_kernel(
    const float* __restrict__ normbuf, const float* __restrict__ hyper,
    float* __restrict__ slots, NceKeys nk) {
  const int call = blockIdx.y;
  const float* G = normbuf + (size_t)c_gsel[call] * C_B * 64;
  const float* H = hyper + (size_t)call * C_B * 64;
  const int br = blockIdx.x * 64;
  __shared__ float Gt[64 * 64];
  __shared__ float Ht[64 * 64];
  __shared__ float red[64][17];
  __shared__ float posr[64];
  const int tid = threadIdx.x;
  for (int i = tid; i < 64 * 64; i += 256) {
    int r = i >> 6, c = i & 63;
    Gt[swz(r, c)] = G[(size_t)(br + r) * 64 + c];
  }
  const int ty = tid >> 4, tx = tid & 15;
  float rs[4] = {0.f, 0.f, 0.f, 0.f};
  float ps[4] = {0.f, 0.f, 0.f, 0.f};
  for (int jt = 0; jt < C_B / 64; ++jt) {
    __syncthreads();
    for (int i = tid; i < 64 * 64; i += 256) {
      int r = i >> 6, c = i & 63;
      Ht[swz(r, c)] = H[(size_t)(jt * 64 + r) * 64 + c];
    }
    __syncthreads();
    float s[4][4] = {};
    for (int k4 = 0; k4 < 16; ++k4) {
      float4 g[4], h[4];
#pragma unroll
      for (int i = 0; i < 4; ++i) g[i] = *(const float4*)&Gt[swz4(ty * 4 + i, k4)];
#pragma unroll
      for (int j = 0; j < 4; ++j) h[j] = *(const float4*)&Ht[swz4(tx * 4 + j, k4)];
#pragma unroll
      for (int i = 0; i < 4; ++i)
#pragma unroll
        for (int j = 0; j < 4; ++j)
          s[i][j] += g[i].x * h[j].x + g[i].y * h[j].y + g[i].z * h[j].z + g[i].w * h[j].w;
    }
#pragma unroll
    for (int i = 0; i < 4; ++i) {
      int grow = br + ty * 4 + i;
#pragma unroll
      for (int j = 0; j < 4; ++j) {
        float e = __expf(s[i][j] * 5.0f);  // /TEMP
        rs[i] += e;
        if (jt * 64 + tx * 4 + j == grow) ps[i] = e;
      }
    }
  }
#pragma unroll
  for (int i = 0; i < 4; ++i) {
    red[ty * 4 + i][tx] = rs[i];
    if (ps[i] != 0.f) posr[ty * 4 + i] = ps[i];
  }
  __syncthreads();
  if (tid < 64) {
    float ns = 0.f;
#pragma unroll
    for (int k = 0; k < 16; ++k) ns += red[tid][k];
    float p = posr[tid];
    float v = -__logf(p / (ns + 1e-8f) + 1e-8f);
    int b = br + tid;
    float u = tf_uniform(nk.k0[call], nk.k1[call], (uint32_t)b);
    float contrib = (u > 0.5f) ? v : 0.f;
    for (int off = 32; off; off >>= 1) contrib += __shfl_down(contrib, off);
    if (tid == 0) atomicAdd(&slots[c_slot[call]], contrib);
  }
}

__global__ __launch_bounds__(256) void loss_r_kernel(
    const float* __restrict__ E0u, const float* __restrict__ Eu1,
    const float* __restrict__ Eu2, const float* __restrict__ E0i,
    const float* __restrict__ Ei1, const float* __restrict__ Ei2,
    const int* __restrict__ uids, const int* __restrict__ pos,
    const int* __restrict__ neg, float* __restrict__ slots) {
  long long t = (long long)blockIdx.x * blockDim.x + threadIdx.x;
  int b = (int)(t >> 6);
  int d = (int)(t & 63);
  if (b >= C_B) return;
  size_t ju = (size_t)uids[b] * 64 + d;
  float u = E0u[ju] + Eu1[ju] + Eu2[ju];
  float bpr = 0.f, pmin = 3.4e38f, nmax = -3.4e38f;
  for (int p = 0; p < C_P; ++p) {
    size_t jp = (size_t)pos[b * C_P + p] * 64 + d;
    size_t jn = (size_t)neg[b * C_P + p] * 64 + d;
    float pe = E0i[jp] + Ei1[jp] + Ei2[jp];
    float ne = E0i[jn] + Ei1[jn] + Ei2[jn];
    float psc = u * pe, nsc = u * ne;
#pragma unroll
    for (int off = 1; off < 64; off <<= 1) {
      psc += __shfl_xor(psc, off);
      nsc += __shfl_xor(nsc, off);
    }
    pmin = fminf(pmin, psc);
    nmax = fmaxf(nmax, nsc);
    bpr += fmaxf(1.f - psc + nsc, 0.f);
  }
  if (d == 0) {
    float hd = (nmax - pmin > 0.005f) ? 10.f * (nmax - pmin) : 0.f;
    atomicAdd(&slots[5], bpr + hd);
  }
}

__global__ void final_kernel(const float* __restrict__ slots, float* __restrict__ out) {
  if (threadIdx.x == 0 && blockIdx.x == 0) {
    float n = slots[0], dl = slots[1], nn = slots[2], dd = slots[3], nd = slots[4];
    float lr = slots[5] / (float)C_B;
    out[0] = lr + 0.2f * (n + dl) + 0.2f * (nn + dd + nd);
    out[1] = lr;
    out[2] = dl;
    out[3] = n;
  }
}

// ---------------- host ----------------
extern "C" void kernel_launch(void* const* d_in, const int* in_sizes, int n_in,
                              void* d_out, int out_size, void* d_ws, size_t ws_size,
                              hipStream_t stream) {
  (void)in_sizes; (void)n_in; (void)out_size;
  const float* E_u_0   = (const float*)d_in[0];
  const float* E_i_0   = (const float*)d_in[1];
  const float* adjvals = (const float*)d_in[2];
  const float* u_mul_s = (const float*)d_in[3];
  const float* v_mul_s = (const float*)d_in[4];
  const float* ut      = (const float*)d_in[5];
  const float* vt      = (const float*)d_in[6];
  const float* W_nn    = (const float*)d_in[7];
  const float* W_dd    = (const float*)d_in[8];
  const float* W_ng    = (const float*)d_in[9];
  const float* W_dg    = (const float*)d_in[10];
  const float* W_nd    = (const float*)d_in[11];
  const int* adj_rows  = (const int*)d_in[12];
  const int* adj_cols  = (const int*)d_in[13];
  const int* uids      = (const int*)d_in[14];
  const int* iids      = (const int*)d_in[15];
  const int* pos       = (const int*)d_in[16];
  const int* neg       = (const int*)d_in[17];
  float* out = (float*)d_out;

  const size_t NU64 = (size_t)C_NU * 64;
  const size_t NI64 = (size_t)C_NI * 64;
  const size_t B64  = (size_t)C_B * 64;

  float* w = (float*)d_ws;
  float* Eu1 = w; w += NU64;
  float* Eu2 = w; w += NU64;
  float* Ei1 = w; w += NI64;
  float* Ei2 = w; w += NI64;
  float* Zu  = w; w += NU64;
  float* Zdu = w; w += NU64;
  float* Zi  = w; w += NI64;
  float* Zdi = w; w += NI64;
  float* Mu = w; w += 512;
  float* Mi = w; w += 512;
  float* normbuf = w; w += 12 * B64;
  float* slots = w; w += 16;
  // edges (8B-aligned: offset so far is even # floats)
  uint2* edges0 = (uint2*)w; w += 2 * C_NE;   // 2M uint2
  uint2* edges1 = (uint2*)w; w += 2 * C_NE;
  // hyper ALIASES the edges region (edges dead before hyper_kernel runs)
  float* hyper = (float*)edges0;              // needs 16*B64 = 4.2M floats <= 8M
  uint32_t* hist = (uint32_t*)w; w += 2 * NROW;
  uint32_t* cursors = hist;                   // alias: hist dead after scan1
  uint32_t* starts = (uint32_t*)w; w += 2 * (NROW + 1);
  uint32_t* bsum = (uint32_t*)w; w += 2 * NBLK1;
  uint32_t* boff = (uint32_t*)w; w += 2 * NBLK1;
  if ((size_t)((char*)w - (char*)d_ws) > ws_size) return;  // ws too small

  // ---- host-side JAX key derivation (partitionable threefry) ----
  auto ksplit = [](uint32_t a, uint32_t b, uint32_t idx, uint32_t& o0, uint32_t& o1) {
    uint32_t x0 = 0u, x1 = idx;
    tf2x32(a, b, x0, x1);
    o0 = x0; o1 = x1;
  };
  uint32_t rk0 = 0u, rk1 = 42u;
  uint32_t lk[2][4][2];  // [layer][k1 dropU, k2 dropI, k3 noiseU, k4 noiseI][pair]
  for (int l = 0; l < 2; ++l) {
    uint32_t n0, n1;
    ksplit(rk0, rk1, 0u, n0, n1);
    for (int i = 0; i < 4; ++i) ksplit(rk0, rk1, (uint32_t)(i + 1), lk[l][i][0], lk[l][i][1]);
    rk0 = n0; rk1 = n1;
  }
  NceKeys nk;
  {
    uint32_t mk0 = 0u, mk1 = 7u;
    for (int i = 0; i < 16; ++i) {
      uint32_t n0, n1;
      ksplit(mk0, mk1, 0u, n0, n1);
      ksplit(mk0, mk1, 1u, nk.k0[i], nk.k1[i]);
      mk0 = n0; mk1 = n1;
    }
  }
  DropKeys dk;
  dk.a[0] = lk[0][0][0]; dk.a[1] = lk[0][0][1];  // dir0 (->users) layer0
  dk.a[2] = lk[1][0][0]; dk.a[3] = lk[1][0][1];  // dir0 layer1
  dk.a[4] = lk[0][1][0]; dk.a[5] = lk[0][1][1];  // dir1 (->items) layer0
  dk.a[6] = lk[1][1][0]; dk.a[7] = lk[1][1][1];  // dir1 layer1
  WPtrs wp;
  wp.W[0] = W_ng; wp.W[1] = W_ng + 4096;
  wp.W[2] = W_nn;
  wp.W[3] = W_dg; wp.W[4] = W_dg + 4096;
  wp.W[5] = W_dd;
  wp.W[6] = W_nd; wp.W[7] = W_nd + 4096;

  // ---- build per-row CSR buckets (once; shared by both layers) ----
  hipMemsetAsync(hist, 0, 2 * NROW * 4, stream);
  hipMemsetAsync(slots, 0, 16 * 4, stream);
  hist_kernel<<<2048, 256, 0, stream>>>(adj_rows, adj_cols, hist);
  scan1_kernel<<<dim3(NBLK1, 2), 512, 0, stream>>>(hist, starts, bsum);
  scan2_kernel<<<1, 256, 0, stream>>>(bsum, boff, starts);
  scan3_kernel<<<dim3(NBLK1, 2), 512, 0, stream>>>(starts, boff, cursors);
  scatter_kernel<<<(C_NE + 255) / 256, 256, 0, stream>>>(
      adj_rows, adj_cols, adjvals, cursors, edges0, edges1, dk);

  const int gb = (int)(B64 / 256);  // 1024
  const int sb = (NROW + 3) / 4;    // 25000 blocks, 4 waves each

  for (int l = 0; l < 2; ++l) {
    const float* Eu_prev = (l == 0) ? E_u_0 : Eu1;
    const float* Ei_prev = (l == 0) ? E_i_0 : Ei1;
    float* Eu_next = (l == 0) ? Eu1 : Eu2;
    float* Ei_next = (l == 0) ? Ei1 : Ei2;
    hipMemsetAsync(Mu, 0, 1024 * 4, stream);
    svd_reduce<<<1024, 256, 0, stream>>>(vt, Ei_prev, Mu, C_NI);
    svd_reduce<<<1024, 256, 0, stream>>>(ut, Eu_prev, Mi, C_NU);
    // dir0: gather items -> users (noise key k3)
    spmm_row<<<sb, 256, 0, stream>>>(edges0, starts, Ei_prev, Eu_prev,
                                     Eu_next, Zu, Zdu,
                                     lk[l][2][0], lk[l][2][1], l);
    // dir1: gather users -> items (noise key k4)
    spmm_row<<<sb, 256, 0, stream>>>(edges1, starts + (NROW + 1), Eu_prev,
                                     Ei_prev, Ei_next, Zi, Zdi,
                                     lk[l][3][0], lk[l][3][1], l);
    gather_norm<<<dim3(gb, 3), 256, 0, stream>>>(
        uids, Zu, Zdu, u_mul_s, Mu,
        normbuf + (size_t)(0 + l) * B64, normbuf + (size_t)(4 + l) * B64,
        normbuf + (size_t)(8 + l) * B64);
    gather_norm<<<dim3(gb, 3), 256, 0, stream>>>(
        iids, Zi, Zdi, v_mul_s, Mi,
        normbuf + (size_t)(2 + l) * B64, normbuf + (size_t)(6 + l) * B64,
        normbuf + (size_t)(10 + l) * B64);
  }

  hyper_kernel<<<dim3(gb, 16), 256, 0, stream>>>(normbuf, hyper, wp);
  nce_kernel<<<dim3(C_B / 64, 16), 256, 0, stream>>>(normbuf, hyper, slots, nk);
  loss_r_kernel<<<gb, 256, 0, stream>>>(E_u_0, Eu1, Eu2, E_i_0, Ei1, Ei2,
                                        uids, pos, neg, slots);
  final_kernel<<<1, 1, 0, stream>>>(slots, out);
}

// Round 4
// 1603.135 us; speedup vs baseline: 5.3023x; 1.4128x over previous
//
#include <hip/hip_runtime.h>
#include <hip/hip_bf16.h>
#include <cstdint>

#define C_NU 100000
#define C_NI 100000
#define C_DIM 64
#define C_Q 5
#define C_NE 2000000
#define C_B 4096
#define C_P 10
#define NROW 100000
#define NBLK1 196   // ceil(100000/512)

typedef unsigned short u16;
typedef __attribute__((ext_vector_type(8))) short short8;
typedef __attribute__((ext_vector_type(4))) float f32x4;

// ---------------- Threefry-2x32 (JAX-compatible), 20 rounds ----------------
__host__ __device__ static inline void tf2x32(uint32_t k0, uint32_t k1,
                                              uint32_t& x0, uint32_t& x1) {
  uint32_t k2 = k0 ^ k1 ^ 0x1BD11BDAu;
#define TFR(r) { x0 += x1; x1 = (x1 << r) | (x1 >> (32 - r)); x1 ^= x0; }
  x0 += k0; x1 += k1;
  TFR(13) TFR(15) TFR(26) TFR(6)
  x0 += k1; x1 += k2 + 1u;
  TFR(17) TFR(29) TFR(16) TFR(24)
  x0 += k2; x1 += k0 + 2u;
  TFR(13) TFR(15) TFR(26) TFR(6)
  x0 += k0; x1 += k1 + 3u;
  TFR(17) TFR(29) TFR(16) TFR(24)
  x0 += k1; x1 += k2 + 4u;
  TFR(13) TFR(15) TFR(26) TFR(6)
  x0 += k2; x1 += k0 + 5u;
#undef TFR
}

// partitionable-mode random bits at flat index idx (hi counter = 0)
__device__ static inline float tf_uniform(uint32_t k0, uint32_t k1, uint32_t idx) {
  uint32_t x0 = 0u, x1 = idx;
  tf2x32(k0, k1, x0, x1);
  uint32_t bits = x0 ^ x1;
  return __uint_as_float((bits >> 9) | 0x3F800000u) - 1.0f;
}

__device__ static inline float leaky(float x) { return x >= 0.f ? x : 0.5f * x; }

__device__ static inline u16 f2bf(float f) {  // RNE fp32->bf16
  uint32_t x = __float_as_uint(f);
  return (u16)((x + 0x7FFFu + ((x >> 16) & 1u)) >> 16);
}
__device__ static inline float bf2f(u16 u) {
  return __uint_as_float((uint32_t)u << 16);
}

// ---------------- constant maps for the 16 info_nce calls ----------------
// normbuf slots: 0:Zu1 1:Zu2 2:Zi1 3:Zi2 4:Zdu1 5:Zdu2 6:Zdi1 7:Zdi2 8:Gu1 9:Gu2 10:Gi1 11:Gi2
__constant__ int c_gsel[16] = {0,1,2,3, 0,2, 4,5,6,7, 4,6, 0,1,2,3};
__constant__ int c_hsrc[16] = {8,9,10,11, 1,3, 8,9,10,11, 5,7, 4,5,6,7};
// W order: 0:ng0 1:ng1 2:nn 3:dg0 4:dg1 5:dd 6:nd0 7:nd1
__constant__ int c_wsel[16] = {0,1,0,1, 2,2, 3,4,3,4, 5,5, 6,7,6,7};
// slots: 0:n 1:d 2:nn 3:dd 4:nd (5: loss_r sum)
__constant__ int c_slot[16] = {0,0,0,0, 2,2, 1,1,1,1, 3,3, 4,4,4,4};

struct WPtrs { const float* W[8]; };
struct NceKeys { uint32_t k0[16]; uint32_t k1[16]; };
struct DropKeys { uint32_t a[8]; };  // [d0l0, d0l1, d1l0, d1l1] key pairs

// ---------------- per-row bucket build ----------------

__global__ __launch_bounds__(256) void hist_kernel(
    const int* __restrict__ rows, const int* __restrict__ cols,
    uint32_t* __restrict__ hist) {
  for (int e = blockIdx.x * 256 + threadIdx.x; e < C_NE; e += gridDim.x * 256) {
    atomicAdd(&hist[rows[e]], 1u);
    atomicAdd(&hist[NROW + cols[e]], 1u);
  }
}

// block-local exclusive scan of 512-entry chunks; writes block sums
__global__ __launch_bounds__(512) void scan1_kernel(
    const uint32_t* __restrict__ hist, uint32_t* __restrict__ starts,
    uint32_t* __restrict__ bsum) {
  __shared__ uint32_t s[512];
  const int dir = blockIdx.y, b = blockIdx.x, t = threadIdx.x;
  const int idx = b * 512 + t;
  uint32_t v = (idx < NROW) ? hist[dir * NROW + idx] : 0u;
  s[t] = v;
  __syncthreads();
  for (int off = 1; off < 512; off <<= 1) {
    uint32_t a = (t >= off) ? s[t - off] : 0u;
    __syncthreads();
    s[t] += a;
    __syncthreads();
  }
  if (idx < NROW) starts[dir * (NROW + 1) + idx] = s[t] - v;  // local exclusive
  if (t == 511) bsum[dir * NBLK1 + b] = s[511];
}

// scan the per-block sums -> block offsets; set sentinel totals
__global__ __launch_bounds__(256) void scan2_kernel(
    const uint32_t* __restrict__ bsum, uint32_t* __restrict__ boff,
    uint32_t* __restrict__ starts) {
  __shared__ uint32_t s[256];
  const int t = threadIdx.x;
  for (int dir = 0; dir < 2; ++dir) {
    uint32_t v = (t < NBLK1) ? bsum[dir * NBLK1 + t] : 0u;
    s[t] = v;
    __syncthreads();
    for (int off = 1; off < 256; off <<= 1) {
      uint32_t a = (t >= off) ? s[t - off] : 0u;
      __syncthreads();
      s[t] += a;
      __syncthreads();
    }
    if (t < NBLK1) boff[dir * NBLK1 + t] = s[t] - v;  // exclusive
    if (t == 255) starts[dir * (NROW + 1) + NROW] = s[255];  // total
    __syncthreads();
  }
}

// add block offsets; init cursors (cursors aliases hist memory)
__global__ __launch_bounds__(512) void scan3_kernel(
    uint32_t* __restrict__ starts, const uint32_t* __restrict__ boff,
    uint32_t* __restrict__ cursors) {
  const int dir = blockIdx.y, b = blockIdx.x, t = threadIdx.x;
  const int idx = b * 512 + t;
  if (idx >= NROW) return;
  uint32_t st = starts[dir * (NROW + 1) + idx] + boff[dir * NBLK1 + b];
  starts[dir * (NROW + 1) + idx] = st;
  cursors[dir * NROW + idx] = st;
}

// pack edges into per-row CSR order; keep bits from threefry on original edge id
__global__ __launch_bounds__(256) void scatter_kernel(
    const int* __restrict__ rows, const int* __restrict__ cols,
    const float* __restrict__ vals, uint32_t* __restrict__ cursors,
    uint2* __restrict__ edges0, uint2* __restrict__ edges1, DropKeys dk) {
  int e = blockIdx.x * 256 + threadIdx.x;
  if (e >= C_NE) return;
  const int r = rows[e], c = cols[e];
  const uint32_t vb = __float_as_uint(vals[e]);
  const uint32_t ue = (uint32_t)e;
  uint32_t k00 = (tf_uniform(dk.a[0], dk.a[1], ue) < 0.9f) ? 1u : 0u;
  uint32_t k01 = (tf_uniform(dk.a[2], dk.a[3], ue) < 0.9f) ? 1u : 0u;
  uint32_t k10 = (tf_uniform(dk.a[4], dk.a[5], ue) < 0.9f) ? 1u : 0u;
  uint32_t k11 = (tf_uniform(dk.a[6], dk.a[7], ue) < 0.9f) ? 1u : 0u;
  uint32_t s0 = atomicAdd(&cursors[r], 1u);
  edges0[s0] = make_uint2((uint32_t)c | (k00 << 17) | (k01 << 18), vb);
  uint32_t s1 = atomicAdd(&cursors[NROW + c], 1u);
  edges1[s1] = make_uint2((uint32_t)r | (k10 << 17) | (k11 << 18), vb);
}

// ---------------- fused spmm (one wave per dst row) ----------------
__global__ __launch_bounds__(256) void spmm_row(
    const uint2* __restrict__ edges, const uint32_t* __restrict__ starts,
    const float* __restrict__ Ein, const float* __restrict__ Eprev,
    float* __restrict__ Enext, float* __restrict__ Zout,
    float* __restrict__ Zdout, uint32_t nk0, uint32_t nk1, int layer) {
  const int row = blockIdx.x * 4 + (threadIdx.x >> 6);
  const int lane = threadIdx.x & 63;
  if (row >= NROW) return;
  const uint32_t s0 = starts[row], s1 = starts[row + 1];
  const uint32_t kbit = 1u << (17 + layer);
  float z = 0.f, zd = 0.f;
  uint32_t e = s0;
  for (; e + 4 <= s1; e += 4) {
    const uint2 q0 = edges[e], q1 = edges[e + 1], q2 = edges[e + 2], q3 = edges[e + 3];
    const float x0 = Ein[(size_t)(q0.x & 0x1FFFFu) * 64 + lane];
    const float x1 = Ein[(size_t)(q1.x & 0x1FFFFu) * 64 + lane];
    const float x2 = Ein[(size_t)(q2.x & 0x1FFFFu) * 64 + lane];
    const float x3 = Ein[(size_t)(q3.x & 0x1FFFFu) * 64 + lane];
    const float t0 = __uint_as_float(q0.y) * x0;
    const float t1 = __uint_as_float(q1.y) * x1;
    const float t2 = __uint_as_float(q2.y) * x2;
    const float t3 = __uint_as_float(q3.y) * x3;
    z += t0; if (q0.x & kbit) zd += t0;
    z += t1; if (q1.x & kbit) zd += t1;
    z += t2; if (q2.x & kbit) zd += t2;
    z += t3; if (q3.x & kbit) zd += t3;
  }
  for (; e < s1; ++e) {
    const uint2 q = edges[e];
    const float x = Ein[(size_t)(q.x & 0x1FFFFu) * 64 + lane];
    const float t = __uint_as_float(q.y) * x;
    z += t; if (q.x & kbit) zd += t;
  }
  z = leaky(z);
  zd = leaky(zd * (1.0f / 0.9f));
  // noise-augmented view
  const float u = tf_uniform(nk0, nk1, (uint32_t)row * 64u + (uint32_t)lane);
  float ss = u * u;
#pragma unroll
  for (int off = 1; off < 64; off <<= 1) ss += __shfl_xor(ss, off);
  const float nrm = fmaxf(sqrtf(ss), 1e-12f);
  const float sg = (z > 0.f) ? 1.f : (z < 0.f ? -1.f : 0.f);
  z += sg * (u / nrm) * 0.1f;
  const size_t j = (size_t)row * 64 + lane;
  const float en = z + zd + Eprev[j];
  Zout[j] = z;
  Zdout[j] = zd;
  Enext[j] = en;
}

// M[q][d] = sum_n T[q][n] * E[n][d]   (T is [5][n] row-major)
__global__ __launch_bounds__(256) void svd_reduce(
    const float* __restrict__ T, const float* __restrict__ E,
    float* __restrict__ M, int n) {
  int wid = (int)(((long long)blockIdx.x * blockDim.x + threadIdx.x) >> 6);
  int lane = threadIdx.x & 63;
  int nw = (gridDim.x * blockDim.x) >> 6;
  float acc[5] = {0.f, 0.f, 0.f, 0.f, 0.f};
  for (int i = wid; i < n; i += nw) {
    float x = E[(size_t)i * 64 + lane];
#pragma unroll
    for (int q = 0; q < 5; ++q) acc[q] += T[(size_t)q * n + i] * x;
  }
#pragma unroll
  for (int q = 0; q < 5; ++q) atomicAdd(&M[q * 64 + lane], acc[q]);
}

// gather batch rows & L2-normalize -> bf16; blockIdx.y selects {Z, Zd, G}
__global__ __launch_bounds__(256) void gather_norm(
    const int* __restrict__ ids, const float* __restrict__ Z,
    const float* __restrict__ Zd, const float* __restrict__ mul_s,
    const float* __restrict__ M, u16* __restrict__ oZ,
    u16* __restrict__ oZd, u16* __restrict__ oG) {
  long long t = (long long)blockIdx.x * blockDim.x + threadIdx.x;
  int b = (int)(t >> 6);
  int d = (int)(t & 63);
  if (b >= C_B) return;
  int id = ids[b];
  float v;
  u16* out;
  if (blockIdx.y == 0) { v = Z[(size_t)id * 64 + d]; out = oZ; }
  else if (blockIdx.y == 1) { v = Zd[(size_t)id * 64 + d]; out = oZd; }
  else {
    float s = 0.f;
#pragma unroll
    for (int q = 0; q < 5; ++q) s += mul_s[(size_t)id * 5 + q] * M[q * 64 + d];
    v = leaky(s);
    out = oG;
  }
  float ss = v * v;
#pragma unroll
  for (int off = 1; off < 64; off <<= 1) ss += __shfl_xor(ss, off);
  float nrm = fmaxf(sqrtf(ss), 1e-12f);
  out[(size_t)b * 64 + d] = f2bf(v / nrm);
}

// hyper[call] = normbuf[hsrc[call]] @ W[wsel[call]]  (bf16 in, bf16 out)
__global__ __launch_bounds__(256) void hyper_kernel(
    const u16* __restrict__ nb, u16* __restrict__ hy, WPtrs wp) {
  int call = blockIdx.y;
  long long t = (long long)blockIdx.x * blockDim.x + threadIdx.x;
  int b = (int)(t >> 6);
  int d = (int)(t & 63);
  if (b >= C_B) return;
  const u16* xn = nb + (size_t)c_hsrc[call] * C_B * 64 + (size_t)b * 64;
  const float* W = wp.W[c_wsel[call]];
  float x = bf2f(xn[d]);
  float h = 0.f;
  for (int k = 0; k < 64; ++k) {
    float xk = __shfl(x, k);
    h += xk * W[k * 64 + d];
  }
  hy[(size_t)call * C_B * 64 + (size_t)b * 64 + d] = f2bf(h);
}

// ---------------- MFMA info_nce ----------------
// scores^T = mfma(A=H, B=G): D[col=lane&15 -> g][row=(lane>>4)*4+reg -> h]
// -> per-lane row-sum is a single scalar accumulator.
__global__ __launch_bounds__(256) void nce_mfma(
    const u16* __restrict__ nb, const u16* __restrict__ hy,
    float* __restrict__ slots, NceKeys nk) {
  const int call = blockIdx.y;
  const u16* G = nb + (size_t)c_gsel[call] * C_B * 64;
  const u16* H = hy + (size_t)call * C_B * 64;
  const int br = blockIdx.x * 64;
  __shared__ u16 Gs[64 * 64];
  __shared__ u16 Hs[64 * 64];
  const int tid = threadIdx.x;
  const int lane = tid & 63, wid = tid >> 6;
  // stage G tile (rows br..br+63), swizzled: byte ^= (row&7)<<4
  {
    const int r = tid >> 2, seg = tid & 3;
    const uint4* src = (const uint4*)&G[(size_t)(br + r) * 64 + seg * 16];
    uint4 a = src[0], b = src[1];
    const int base = r * 128 + seg * 32, sw = (r & 7) << 4;
    *(uint4*)((char*)Gs + (base ^ sw)) = a;
    *(uint4*)((char*)Gs + ((base + 16) ^ sw)) = b;
  }
  const int gcol = (wid << 4) + (lane & 15);  // g row within the 64-stripe
  const int g_glob = br + gcol;
  float rs = 0.f, ps = 0.f;
  for (int jt = 0; jt < 64; ++jt) {
    __syncthreads();
    {
      const int r = tid >> 2, seg = tid & 3;
      const uint4* src = (const uint4*)&H[(size_t)(jt * 64 + r) * 64 + seg * 16];
      uint4 a = src[0], b = src[1];
      const int base = r * 128 + seg * 32, sw = (r & 7) << 4;
      *(uint4*)((char*)Hs + (base ^ sw)) = a;
      *(uint4*)((char*)Hs + ((base + 16) ^ sw)) = b;
    }
    __syncthreads();
    short8 bf[2];
#pragma unroll
    for (int ks = 0; ks < 2; ++ks) {
      const int off = (gcol * 128 + ks * 64 + ((lane >> 4) << 4)) ^ ((gcol & 7) << 4);
      bf[ks] = *(const short8*)((const char*)Gs + off);
    }
#pragma unroll
    for (int hs = 0; hs < 4; ++hs) {
      const int hr = (hs << 4) + (lane & 15);
      f32x4 acc = {0.f, 0.f, 0.f, 0.f};
#pragma unroll
      for (int ks = 0; ks < 2; ++ks) {
        const int off = (hr * 128 + ks * 64 + ((lane >> 4) << 4)) ^ ((hr & 7) << 4);
        short8 af = *(const short8*)((const char*)Hs + off);
        acc = __builtin_amdgcn_mfma_f32_16x16x32_bf16(af, bf[ks], acc, 0, 0, 0);
      }
      const int hbase = jt * 64 + (hs << 4) + ((lane >> 4) << 2);
#pragma unroll
      for (int j = 0; j < 4; ++j) {
        float e = __expf(acc[j] * 5.0f);  // exp(score/TEMP)
        rs += e;
        if (hbase + j == g_glob) ps = e;
      }
    }
  }
  // combine the 4 lane-groups holding the same g column
  rs += __shfl_xor(rs, 16); rs += __shfl_xor(rs, 32);
  ps += __shfl_xor(ps, 16); ps += __shfl_xor(ps, 32);
  float c = 0.f;
  if ((lane >> 4) == 0) {
    float v = -__logf(ps / (rs + 1e-8f) + 1e-8f);
    float u = tf_uniform(nk.k0[call], nk.k1[call], (uint32_t)g_glob);
    c = (u > 0.5f) ? v : 0.f;
  }
  c += __shfl_xor(c, 1); c += __shfl_xor(c, 2);
  c += __shfl_xor(c, 4); c += __shfl_xor(c, 8);
  if (lane == 0) atomicAdd(&slots[c_slot[call]], c);
}

__global__ __launch_bounds__(256) void loss_r_kernel(
    const float* __restrict__ E0u, const float* __restrict__ Eu1,
    const float* __restrict__ Eu2, const float* __restrict__ E0i,
    const float* __restrict__ Ei1, const float* __restrict__ Ei2,
    const int* __restrict__ uids, const int* __restrict__ pos,
    const int* __restrict__ neg, float* __restrict__ slots) {
  long long t = (long long)blockIdx.x * blockDim.x + threadIdx.x;
  int b = (int)(t >> 6);
  int d = (int)(t & 63);
  if (b >= C_B) return;
  size_t ju = (size_t)uids[b] * 64 + d;
  float u = E0u[ju] + Eu1[ju] + Eu2[ju];
  float bpr = 0.f, pmin = 3.4e38f, nmax = -3.4e38f;
  for (int p = 0; p < C_P; ++p) {
    size_t jp = (size_t)pos[b * C_P + p] * 64 + d;
    size_t jn = (size_t)neg[b * C_P + p] * 64 + d;
    float pe = E0i[jp] + Ei1[jp] + Ei2[jp];
    float ne = E0i[jn] + Ei1[jn] + Ei2[jn];
    float psc = u * pe, nsc = u * ne;
#pragma unroll
    for (int off = 1; off < 64; off <<= 1) {
      psc += __shfl_xor(psc, off);
      nsc += __shfl_xor(nsc, off);
    }
    pmin = fminf(pmin, psc);
    nmax = fmaxf(nmax, nsc);
    bpr += fmaxf(1.f - psc + nsc, 0.f);
  }
  if (d == 0) {
    float hd = (nmax - pmin > 0.005f) ? 10.f * (nmax - pmin) : 0.f;
    atomicAdd(&slots[5], bpr + hd);
  }
}

__global__ void final_kernel(const float* __restrict__ slots, float* __restrict__ out) {
  if (threadIdx.x == 0 && blockIdx.x == 0) {
    float n = slots[0], dl = slots[1], nn = slots[2], dd = slots[3], nd = slots[4];
    float lr = slots[5] / (float)C_B;
    out[0] = lr + 0.2f * (n + dl) + 0.2f * (nn + dd + nd);
    out[1] = lr;
    out[2] = dl;
    out[3] = n;
  }
}

// ---------------- host ----------------
extern "C" void kernel_launch(void* const* d_in, const int* in_sizes, int n_in,
                              void* d_out, int out_size, void* d_ws, size_t ws_size,
                              hipStream_t stream) {
  (void)in_sizes; (void)n_in; (void)out_size;
  const float* E_u_0   = (const float*)d_in[0];
  const float* E_i_0   = (const float*)d_in[1];
  const float* adjvals = (const float*)d_in[2];
  const float* u_mul_s = (const float*)d_in[3];
  const float* v_mul_s = (const float*)d_in[4];
  const float* ut      = (const float*)d_in[5];
  const float* vt      = (const float*)d_in[6];
  const float* W_nn    = (const float*)d_in[7];
  const float* W_dd    = (const float*)d_in[8];
  const float* W_ng    = (const float*)d_in[9];
  const float* W_dg    = (const float*)d_in[10];
  const float* W_nd    = (const float*)d_in[11];
  const int* adj_rows  = (const int*)d_in[12];
  const int* adj_cols  = (const int*)d_in[13];
  const int* uids      = (const int*)d_in[14];
  const int* iids      = (const int*)d_in[15];
  const int* pos       = (const int*)d_in[16];
  const int* neg       = (const int*)d_in[17];
  float* out = (float*)d_out;

  const size_t NU64 = (size_t)C_NU * 64;
  const size_t NI64 = (size_t)C_NI * 64;
  const size_t B64  = (size_t)C_B * 64;

  float* w = (float*)d_ws;
  float* Eu1 = w; w += NU64;
  float* Eu2 = w; w += NU64;
  float* Ei1 = w; w += NI64;
  float* Ei2 = w; w += NI64;
  float* Zu  = w; w += NU64;
  float* Zdu = w; w += NU64;
  float* Zi  = w; w += NI64;
  float* Zdi = w; w += NI64;
  float* Mu = w; w += 512;
  float* Mi = w; w += 512;
  u16* normbuf16 = (u16*)w; w += 6 * B64;     // 12 bf16 buffers of B64
  float* slots = w; w += 16;
  // edges (16B-aligned)
  uint2* edges0 = (uint2*)w; w += 2 * C_NE;
  uint2* edges1 = (uint2*)w; w += 2 * C_NE;
  // hyper bf16 ALIASES the edges region (edges dead before hyper_kernel)
  u16* hyper16 = (u16*)edges0;                // 16*B64 u16 = 8 MB <= 16 MB
  uint32_t* hist = (uint32_t*)w; w += 2 * NROW;
  uint32_t* cursors = hist;                   // alias: hist dead after scan1
  uint32_t* starts = (uint32_t*)w; w += 2 * (NROW + 1);
  uint32_t* bsum = (uint32_t*)w; w += 2 * NBLK1;
  uint32_t* boff = (uint32_t*)w; w += 2 * NBLK1;
  if ((size_t)((char*)w - (char*)d_ws) > ws_size) return;  // ws too small

  // ---- host-side JAX key derivation (partitionable threefry) ----
  auto ksplit = [](uint32_t a, uint32_t b, uint32_t idx, uint32_t& o0, uint32_t& o1) {
    uint32_t x0 = 0u, x1 = idx;
    tf2x32(a, b, x0, x1);
    o0 = x0; o1 = x1;
  };
  uint32_t rk0 = 0u, rk1 = 42u;
  uint32_t lk[2][4][2];  // [layer][k1 dropU, k2 dropI, k3 noiseU, k4 noiseI][pair]
  for (int l = 0; l < 2; ++l) {
    uint32_t n0, n1;
    ksplit(rk0, rk1, 0u, n0, n1);
    for (int i = 0; i < 4; ++i) ksplit(rk0, rk1, (uint32_t)(i + 1), lk[l][i][0], lk[l][i][1]);
    rk0 = n0; rk1 = n1;
  }
  NceKeys nk;
  {
    uint32_t mk0 = 0u, mk1 = 7u;
    for (int i = 0; i < 16; ++i) {
      uint32_t n0, n1;
      ksplit(mk0, mk1, 0u, n0, n1);
      ksplit(mk0, mk1, 1u, nk.k0[i], nk.k1[i]);
      mk0 = n0; mk1 = n1;
    }
  }
  DropKeys dk;
  dk.a[0] = lk[0][0][0]; dk.a[1] = lk[0][0][1];  // dir0 (->users) layer0
  dk.a[2] = lk[1][0][0]; dk.a[3] = lk[1][0][1];  // dir0 layer1
  dk.a[4] = lk[0][1][0]; dk.a[5] = lk[0][1][1];  // dir1 (->items) layer0
  dk.a[6] = lk[1][1][0]; dk.a[7] = lk[1][1][1];  // dir1 layer1
  WPtrs wp;
  wp.W[0] = W_ng; wp.W[1] = W_ng + 4096;
  wp.W[2] = W_nn;
  wp.W[3] = W_dg; wp.W[4] = W_dg + 4096;
  wp.W[5] = W_dd;
  wp.W[6] = W_nd; wp.W[7] = W_nd + 4096;

  // ---- build per-row CSR buckets (once; shared by both layers) ----
  hipMemsetAsync(hist, 0, 2 * NROW * 4, stream);
  hipMemsetAsync(slots, 0, 16 * 4, stream);
  hist_kernel<<<2048, 256, 0, stream>>>(adj_rows, adj_cols, hist);
  scan1_kernel<<<dim3(NBLK1, 2), 512, 0, stream>>>(hist, starts, bsum);
  scan2_kernel<<<1, 256, 0, stream>>>(bsum, boff, starts);
  scan3_kernel<<<dim3(NBLK1, 2), 512, 0, stream>>>(starts, boff, cursors);
  scatter_kernel<<<(C_NE + 255) / 256, 256, 0, stream>>>(
      adj_rows, adj_cols, adjvals, cursors, edges0, edges1, dk);

  const int gb = (int)(B64 / 256);  // 1024
  const int sb = (NROW + 3) / 4;    // 25000 blocks, 4 waves each

  for (int l = 0; l < 2; ++l) {
    const float* Eu_prev = (l == 0) ? E_u_0 : Eu1;
    const float* Ei_prev = (l == 0) ? E_i_0 : Ei1;
    float* Eu_next = (l == 0) ? Eu1 : Eu2;
    float* Ei_next = (l == 0) ? Ei1 : Ei2;
    hipMemsetAsync(Mu, 0, 1024 * 4, stream);
    svd_reduce<<<1024, 256, 0, stream>>>(vt, Ei_prev, Mu, C_NI);
    svd_reduce<<<1024, 256, 0, stream>>>(ut, Eu_prev, Mi, C_NU);
    // dir0: gather items -> users (noise key k3)
    spmm_row<<<sb, 256, 0, stream>>>(edges0, starts, Ei_prev, Eu_prev,
                                     Eu_next, Zu, Zdu,
                                     lk[l][2][0], lk[l][2][1], l);
    // dir1: gather users -> items (noise key k4)
    spmm_row<<<sb, 256, 0, stream>>>(edges1, starts + (NROW + 1), Eu_prev,
                                     Ei_prev, Ei_next, Zi, Zdi,
                                     lk[l][3][0], lk[l][3][1], l);
    gather_norm<<<dim3(gb, 3), 256, 0, stream>>>(
        uids, Zu, Zdu, u_mul_s, Mu,
        normbuf16 + (size_t)(0 + l) * B64, normbuf16 + (size_t)(4 + l) * B64,
        normbuf16 + (size_t)(8 + l) * B64);
    gather_norm<<<dim3(gb, 3), 256, 0, stream>>>(
        iids, Zi, Zdi, v_mul_s, Mi,
        normbuf16 + (size_t)(2 + l) * B64, normbuf16 + (size_t)(6 + l) * B64,
        normbuf16 + (size_t)(10 + l) * B64);
  }

  hyper_kernel<<<dim3(gb, 16), 256, 0, stream>>>(normbuf16, hyper16, wp);
  nce_mfma<<<dim3(C_B / 64, 16), 256, 0, stream>>>(normbuf16, hyper16, slots, nk);
  loss_r_kernel<<<gb, 256, 0, stream>>>(E_u_0, Eu1, Eu2, E_i_0, Ei1, Ei2,
                                        uids, pos, neg, slots);
  final_kernel<<<1, 1, 0, stream>>>(slots, out);
}

// Round 5
// 1215.295 us; speedup vs baseline: 6.9944x; 1.3191x over previous
//
#include <hip/hip_runtime.h>
#include <hip/hip_bf16.h>
#include <cstdint>

#define C_NU 100000
#define C_NI 100000
#define C_DIM 64
#define C_Q 5
#define C_NE 2000000
#define C_B 4096
#define C_P 10
#define NROW 100000
#define NCB 196      // coarse buckets of 512 rows
#define NCHK 256     // chunks in pass A
#define CHUNK 7813   // ceil(2M/256)

typedef unsigned short u16;
typedef __attribute__((ext_vector_type(8))) short short8;
typedef __attribute__((ext_vector_type(4))) float f32x4;

// ---------------- Threefry-2x32 (JAX-compatible), 20 rounds ----------------
__host__ __device__ static inline void tf2x32(uint32_t k0, uint32_t k1,
                                              uint32_t& x0, uint32_t& x1) {
  uint32_t k2 = k0 ^ k1 ^ 0x1BD11BDAu;
#define TFR(r) { x0 += x1; x1 = (x1 << r) | (x1 >> (32 - r)); x1 ^= x0; }
  x0 += k0; x1 += k1;
  TFR(13) TFR(15) TFR(26) TFR(6)
  x0 += k1; x1 += k2 + 1u;
  TFR(17) TFR(29) TFR(16) TFR(24)
  x0 += k2; x1 += k0 + 2u;
  TFR(13) TFR(15) TFR(26) TFR(6)
  x0 += k0; x1 += k1 + 3u;
  TFR(17) TFR(29) TFR(16) TFR(24)
  x0 += k1; x1 += k2 + 4u;
  TFR(13) TFR(15) TFR(26) TFR(6)
  x0 += k2; x1 += k0 + 5u;
#undef TFR
}

// partitionable-mode random bits at flat index idx (hi counter = 0)
__device__ static inline float tf_uniform(uint32_t k0, uint32_t k1, uint32_t idx) {
  uint32_t x0 = 0u, x1 = idx;
  tf2x32(k0, k1, x0, x1);
  uint32_t bits = x0 ^ x1;
  return __uint_as_float((bits >> 9) | 0x3F800000u) - 1.0f;
}

__device__ static inline float leaky(float x) { return x >= 0.f ? x : 0.5f * x; }

__device__ static inline u16 f2bf(float f) {  // RNE fp32->bf16
  uint32_t x = __float_as_uint(f);
  return (u16)((x + 0x7FFFu + ((x >> 16) & 1u)) >> 16);
}
__device__ static inline float bf2f(u16 u) {
  return __uint_as_float((uint32_t)u << 16);
}

// ---------------- constant maps for the 16 info_nce calls ----------------
// normbuf slots: 0:Zu1 1:Zu2 2:Zi1 3:Zi2 4:Zdu1 5:Zdu2 6:Zdi1 7:Zdi2 8:Gu1 9:Gu2 10:Gi1 11:Gi2
__constant__ int c_gsel[16] = {0,1,2,3, 0,2, 4,5,6,7, 4,6, 0,1,2,3};
__constant__ int c_hsrc[16] = {8,9,10,11, 1,3, 8,9,10,11, 5,7, 4,5,6,7};
// W order: 0:ng0 1:ng1 2:nn 3:dg0 4:dg1 5:dd 6:nd0 7:nd1
__constant__ int c_wsel[16] = {0,1,0,1, 2,2, 3,4,3,4, 5,5, 6,7,6,7};
// slots: 0:n 1:d 2:nn 3:dd 4:nd (5: loss_r sum)
__constant__ int c_slot[16] = {0,0,0,0, 2,2, 1,1,1,1, 3,3, 4,4,4,4};

struct WPtrs { const float* W[8]; };
struct NceKeys { uint32_t k0[16]; uint32_t k1[16]; };
struct DropKeys { uint32_t a[8]; };  // [dir0 l0 pair, dir0 l1 pair, dir1 l0 pair, dir1 l1 pair]

// ---------------- two-level counting sort ----------------

// per-(chunk,dir) coarse histogram -> cnt[(dir*NCB + bucket)*NCHK + chunk]
__global__ __launch_bounds__(256) void passA_hist(
    const int* __restrict__ rows, const int* __restrict__ cols,
    uint32_t* __restrict__ cntA) {
  __shared__ uint32_t h[NCB];
  const int dir = blockIdx.y, c = blockIdx.x, t = threadIdx.x;
  for (int i = t; i < NCB; i += 256) h[i] = 0u;
  __syncthreads();
  const int e0 = c * CHUNK, e1 = min(e0 + CHUNK, C_NE);
  const int* ids = dir ? cols : rows;
  for (int e = e0 + t; e < e1; e += 256) atomicAdd(&h[ids[e] >> 9], 1u);
  __syncthreads();
  for (int i = t; i < NCB; i += 256) cntA[(dir * NCB + i) * NCHK + c] = h[i];
}

// exclusive scan of the flat 100352-entry array (196 blocks x 512)
__global__ __launch_bounds__(512) void scanA1(
    const uint32_t* __restrict__ cntA, uint32_t* __restrict__ offs,
    uint32_t* __restrict__ bsum) {
  __shared__ uint32_t s[512];
  const int b = blockIdx.x, t = threadIdx.x;
  const int idx = b * 512 + t;
  uint32_t v = cntA[idx];
  s[t] = v;
  __syncthreads();
  for (int off = 1; off < 512; off <<= 1) {
    uint32_t a = (t >= off) ? s[t - off] : 0u;
    __syncthreads();
    s[t] += a;
    __syncthreads();
  }
  offs[idx] = s[t] - v;
  if (t == 511) bsum[b] = s[511];
}

__global__ __launch_bounds__(256) void scanA2(
    const uint32_t* __restrict__ bsum, uint32_t* __restrict__ boff) {
  __shared__ uint32_t s[256];
  const int t = threadIdx.x;
  uint32_t v = (t < NCB) ? bsum[t] : 0u;
  s[t] = v;
  __syncthreads();
  for (int off = 1; off < 256; off <<= 1) {
    uint32_t a = (t >= off) ? s[t - off] : 0u;
    __syncthreads();
    s[t] += a;
    __syncthreads();
  }
  if (t < NCB) boff[t] = s[t] - v;
}

__global__ __launch_bounds__(512) void scanA3(
    uint32_t* __restrict__ offs, const uint32_t* __restrict__ boff) {
  offs[blockIdx.x * 512 + threadIdx.x] += boff[blockIdx.x];
}

// coarse scatter: block-private contiguous segments per bucket -> dense writes
// record.x = src(17b) | keepL0<<17 | keepL1<<18 | (dst&511)<<19
__global__ __launch_bounds__(256) void passA_scatter(
    const int* __restrict__ rows, const int* __restrict__ cols,
    const float* __restrict__ vals, const uint32_t* __restrict__ offs,
    uint2* __restrict__ edgesA, DropKeys dk) {
  __shared__ uint32_t lofs[NCB];
  const int dir = blockIdx.y, c = blockIdx.x, t = threadIdx.x;
  for (int i = t; i < NCB; i += 256) lofs[i] = offs[(dir * NCB + i) * NCHK + c];
  __syncthreads();
  const int e0 = c * CHUNK, e1 = min(e0 + CHUNK, C_NE);
  const uint32_t kA0 = dk.a[dir * 4 + 0], kA1 = dk.a[dir * 4 + 1];
  const uint32_t kB0 = dk.a[dir * 4 + 2], kB1 = dk.a[dir * 4 + 3];
  for (int e = e0 + t; e < e1; e += 256) {
    const int r = rows[e], cc = cols[e];
    const int dst = dir ? cc : r, src = dir ? r : cc;
    const uint32_t kl0 = (tf_uniform(kA0, kA1, (uint32_t)e) < 0.9f) ? 1u : 0u;
    const uint32_t kl1 = (tf_uniform(kB0, kB1, (uint32_t)e) < 0.9f) ? 1u : 0u;
    const uint32_t x = (uint32_t)src | (kl0 << 17) | (kl1 << 18) |
                       ((uint32_t)(dst & 511) << 19);
    const uint32_t pos = atomicAdd(&lofs[dst >> 9], 1u);
    edgesA[pos] = make_uint2(x, __float_as_uint(vals[e]));
  }
}

// fine sort within each coarse bucket (writes stay in an L2-resident window);
// also emits absolute per-row CSR starts
__global__ __launch_bounds__(512) void passB_kernel(
    const uint2* __restrict__ edgesA, const uint32_t* __restrict__ offs,
    uint2* __restrict__ edgesB, uint32_t* __restrict__ starts) {
  __shared__ uint32_t cnt[512];
  __shared__ uint32_t scn[512];
  const int dir = blockIdx.y, cb = blockIdx.x, t = threadIdx.x;
  const uint32_t segStart = offs[(dir * NCB + cb) * NCHK];
  const uint32_t segEnd = (dir == 1 && cb == NCB - 1)
                              ? (uint32_t)(2 * C_NE)
                              : offs[(dir * NCB + cb + 1) * NCHK];
  cnt[t] = 0u;
  __syncthreads();
  for (uint32_t e = segStart + t; e < segEnd; e += 512)
    atomicAdd(&cnt[(edgesA[e].x >> 19) & 511u], 1u);
  __syncthreads();
  uint32_t v = cnt[t];
  scn[t] = v;
  __syncthreads();
  for (int off = 1; off < 512; off <<= 1) {
    uint32_t a = (t >= off) ? scn[t - off] : 0u;
    __syncthreads();
    scn[t] += a;
    __syncthreads();
  }
  const uint32_t rstart = segStart + scn[t] - v;  // absolute row start
  const int grow = cb * 512 + t;
  if (grow < NROW) starts[dir * (NROW + 1) + grow] = rstart;
  if (cb == NCB - 1 && t == 0) starts[dir * (NROW + 1) + NROW] = segEnd;
  cnt[t] = rstart;  // reuse as running cursor
  __syncthreads();
  for (uint32_t e = segStart + t; e < segEnd; e += 512) {
    const uint2 q = edgesA[e];
    const uint32_t pos = atomicAdd(&cnt[(q.x >> 19) & 511u], 1u);
    edgesB[pos] = q;
  }
}

// ---------------- fused spmm (one wave per dst row) ----------------
__global__ __launch_bounds__(256) void spmm_row(
    const uint2* __restrict__ edges, const uint32_t* __restrict__ starts,
    const float* __restrict__ Ein, const float* __restrict__ Eprev,
    float* __restrict__ Enext, float* __restrict__ Zout,
    float* __restrict__ Zdout, uint32_t nk0, uint32_t nk1, int layer) {
  const int row = blockIdx.x * 4 + (threadIdx.x >> 6);
  const int lane = threadIdx.x & 63;
  if (row >= NROW) return;
  const uint32_t s0 = starts[row], s1 = starts[row + 1];
  const uint32_t kbit = 1u << (17 + layer);
  float z = 0.f, zd = 0.f;
  uint32_t e = s0;
  for (; e + 4 <= s1; e += 4) {
    const uint2 q0 = edges[e], q1 = edges[e + 1], q2 = edges[e + 2], q3 = edges[e + 3];
    const float x0 = Ein[(size_t)(q0.x & 0x1FFFFu) * 64 + lane];
    const float x1 = Ein[(size_t)(q1.x & 0x1FFFFu) * 64 + lane];
    const float x2 = Ein[(size_t)(q2.x & 0x1FFFFu) * 64 + lane];
    const float x3 = Ein[(size_t)(q3.x & 0x1FFFFu) * 64 + lane];
    const float t0 = __uint_as_float(q0.y) * x0;
    const float t1 = __uint_as_float(q1.y) * x1;
    const float t2 = __uint_as_float(q2.y) * x2;
    const float t3 = __uint_as_float(q3.y) * x3;
    z += t0; if (q0.x & kbit) zd += t0;
    z += t1; if (q1.x & kbit) zd += t1;
    z += t2; if (q2.x & kbit) zd += t2;
    z += t3; if (q3.x & kbit) zd += t3;
  }
  for (; e < s1; ++e) {
    const uint2 q = edges[e];
    const float x = Ein[(size_t)(q.x & 0x1FFFFu) * 64 + lane];
    const float t = __uint_as_float(q.y) * x;
    z += t; if (q.x & kbit) zd += t;
  }
  z = leaky(z);
  zd = leaky(zd * (1.0f / 0.9f));
  // noise-augmented view
  const float u = tf_uniform(nk0, nk1, (uint32_t)row * 64u + (uint32_t)lane);
  float ss = u * u;
#pragma unroll
  for (int off = 1; off < 64; off <<= 1) ss += __shfl_xor(ss, off);
  const float nrm = fmaxf(sqrtf(ss), 1e-12f);
  const float sg = (z > 0.f) ? 1.f : (z < 0.f ? -1.f : 0.f);
  z += sg * (u / nrm) * 0.1f;
  const size_t j = (size_t)row * 64 + lane;
  const float en = z + zd + Eprev[j];
  Zout[j] = z;
  Zdout[j] = zd;
  Enext[j] = en;
}

// M[q][d] = sum_n T[q][n] * E[n][d]   (T is [5][n] row-major)
__global__ __launch_bounds__(256) void svd_reduce(
    const float* __restrict__ T, const float* __restrict__ E,
    float* __restrict__ M, int n) {
  int wid = (int)(((long long)blockIdx.x * blockDim.x + threadIdx.x) >> 6);
  int lane = threadIdx.x & 63;
  int nw = (gridDim.x * blockDim.x) >> 6;
  float acc[5] = {0.f, 0.f, 0.f, 0.f, 0.f};
  for (int i = wid; i < n; i += nw) {
    float x = E[(size_t)i * 64 + lane];
#pragma unroll
    for (int q = 0; q < 5; ++q) acc[q] += T[(size_t)q * n + i] * x;
  }
#pragma unroll
  for (int q = 0; q < 5; ++q) atomicAdd(&M[q * 64 + lane], acc[q]);
}

// gather batch rows & L2-normalize -> bf16; blockIdx.y selects {Z, Zd, G}
__global__ __launch_bounds__(256) void gather_norm(
    const int* __restrict__ ids, const float* __restrict__ Z,
    const float* __restrict__ Zd, const float* __restrict__ mul_s,
    const float* __restrict__ M, u16* __restrict__ oZ,
    u16* __restrict__ oZd, u16* __restrict__ oG) {
  long long t = (long long)blockIdx.x * blockDim.x + threadIdx.x;
  int b = (int)(t >> 6);
  int d = (int)(t & 63);
  if (b >= C_B) return;
  int id = ids[b];
  float v;
  u16* out;
  if (blockIdx.y == 0) { v = Z[(size_t)id * 64 + d]; out = oZ; }
  else if (blockIdx.y == 1) { v = Zd[(size_t)id * 64 + d]; out = oZd; }
  else {
    float s = 0.f;
#pragma unroll
    for (int q = 0; q < 5; ++q) s += mul_s[(size_t)id * 5 + q] * M[q * 64 + d];
    v = leaky(s);
    out = oG;
  }
  float ss = v * v;
#pragma unroll
  for (int off = 1; off < 64; off <<= 1) ss += __shfl_xor(ss, off);
  float nrm = fmaxf(sqrtf(ss), 1e-12f);
  out[(size_t)b * 64 + d] = f2bf(v / nrm);
}

// hyper[call] = normbuf[hsrc[call]] @ W[wsel[call]]  (bf16 in, bf16 out)
__global__ __launch_bounds__(256) void hyper_kernel(
    const u16* __restrict__ nb, u16* __restrict__ hy, WPtrs wp) {
  int call = blockIdx.y;
  long long t = (long long)blockIdx.x * blockDim.x + threadIdx.x;
  int b = (int)(t >> 6);
  int d = (int)(t & 63);
  if (b >= C_B) return;
  const u16* xn = nb + (size_t)c_hsrc[call] * C_B * 64 + (size_t)b * 64;
  const float* W = wp.W[c_wsel[call]];
  float x = bf2f(xn[d]);
  float h = 0.f;
  for (int k = 0; k < 64; ++k) {
    float xk = __shfl(x, k);
    h += xk * W[k * 64 + d];
  }
  hy[(size_t)call * C_B * 64 + (size_t)b * 64 + d] = f2bf(h);
}

// ---------------- MFMA info_nce ----------------
// scores^T = mfma(A=H, B=G): D[col=lane&15 -> g][row=(lane>>4)*4+reg -> h]
// -> per-lane row-sum is a single scalar accumulator.
__global__ __launch_bounds__(256) void nce_mfma(
    const u16* __restrict__ nb, const u16* __restrict__ hy,
    float* __restrict__ slots, NceKeys nk) {
  const int call = blockIdx.y;
  const u16* G = nb + (size_t)c_gsel[call] * C_B * 64;
  const u16* H = hy + (size_t)call * C_B * 64;
  const int br = blockIdx.x * 64;
  __shared__ u16 Gs[64 * 64];
  __shared__ u16 Hs[64 * 64];
  const int tid = threadIdx.x;
  const int lane = tid & 63, wid = tid >> 6;
  // stage G tile (rows br..br+63), swizzled: byte ^= (row&7)<<4
  {
    const int r = tid >> 2, seg = tid & 3;
    const uint4* src = (const uint4*)&G[(size_t)(br + r) * 64 + seg * 16];
    uint4 a = src[0], b = src[1];
    const int base = r * 128 + seg * 32, sw = (r & 7) << 4;
    *(uint4*)((char*)Gs + (base ^ sw)) = a;
    *(uint4*)((char*)Gs + ((base + 16) ^ sw)) = b;
  }
  const int gcol = (wid << 4) + (lane & 15);  // g row within the 64-stripe
  const int g_glob = br + gcol;
  float rs = 0.f, ps = 0.f;
  for (int jt = 0; jt < 64; ++jt) {
    __syncthreads();
    {
      const int r = tid >> 2, seg = tid & 3;
      const uint4* src = (const uint4*)&H[(size_t)(jt * 64 + r) * 64 + seg * 16];
      uint4 a = src[0], b = src[1];
      const int base = r * 128 + seg * 32, sw = (r & 7) << 4;
      *(uint4*)((char*)Hs + (base ^ sw)) = a;
      *(uint4*)((char*)Hs + ((base + 16) ^ sw)) = b;
    }
    __syncthreads();
    short8 bf[2];
#pragma unroll
    for (int ks = 0; ks < 2; ++ks) {
      const int off = (gcol * 128 + ks * 64 + ((lane >> 4) << 4)) ^ ((gcol & 7) << 4);
      bf[ks] = *(const short8*)((const char*)Gs + off);
    }
#pragma unroll
    for (int hs = 0; hs < 4; ++hs) {
      const int hr = (hs << 4) + (lane & 15);
      f32x4 acc = {0.f, 0.f, 0.f, 0.f};
#pragma unroll
      for (int ks = 0; ks < 2; ++ks) {
        const int off = (hr * 128 + ks * 64 + ((lane >> 4) << 4)) ^ ((hr & 7) << 4);
        short8 af = *(const short8*)((const char*)Hs + off);
        acc = __builtin_amdgcn_mfma_f32_16x16x32_bf16(af, bf[ks], acc, 0, 0, 0);
      }
      const int hbase = jt * 64 + (hs << 4) + ((lane >> 4) << 2);
#pragma unroll
      for (int j = 0; j < 4; ++j) {
        float e = __expf(acc[j] * 5.0f);  // exp(score/TEMP)
        rs += e;
        if (hbase + j == g_glob) ps = e;
      }
    }
  }
  // combine the 4 lane-groups holding the same g column
  rs += __shfl_xor(rs, 16); rs += __shfl_xor(rs, 32);
  ps += __shfl_xor(ps, 16); ps += __shfl_xor(ps, 32);
  float c = 0.f;
  if ((lane >> 4) == 0) {
    float v = -__logf(ps / (rs + 1e-8f) + 1e-8f);
    float u = tf_uniform(nk.k0[call], nk.k1[call], (uint32_t)g_glob);
    c = (u > 0.5f) ? v : 0.f;
  }
  c += __shfl_xor(c, 1); c += __shfl_xor(c, 2);
  c += __shfl_xor(c, 4); c += __shfl_xor(c, 8);
  if (lane == 0) atomicAdd(&slots[c_slot[call]], c);
}

__global__ __launch_bounds__(256) void loss_r_kernel(
    const float* __restrict__ E0u, const float* __restrict__ Eu1,
    const float* __restrict__ Eu2, const float* __restrict__ E0i,
    const float* __restrict__ Ei1, const float* __restrict__ Ei2,
    const int* __restrict__ uids, const int* __restrict__ pos,
    const int* __restrict__ neg, float* __restrict__ slots) {
  long long t = (long long)blockIdx.x * blockDim.x + threadIdx.x;
  int b = (int)(t >> 6);
  int d = (int)(t & 63);
  if (b >= C_B) return;
  size_t ju = (size_t)uids[b] * 64 + d;
  float u = E0u[ju] + Eu1[ju] + Eu2[ju];
  float bpr = 0.f, pmin = 3.4e38f, nmax = -3.4e38f;
  for (int p = 0; p < C_P; ++p) {
    size_t jp = (size_t)pos[b * C_P + p] * 64 + d;
    size_t jn = (size_t)neg[b * C_P + p] * 64 + d;
    float pe = E0i[jp] + Ei1[jp] + Ei2[jp];
    float ne = E0i[jn] + Ei1[jn] + Ei2[jn];
    float psc = u * pe, nsc = u * ne;
#pragma unroll
    for (int off = 1; off < 64; off <<= 1) {
      psc += __shfl_xor(psc, off);
      nsc += __shfl_xor(nsc, off);
    }
    pmin = fminf(pmin, psc);
    nmax = fmaxf(nmax, nsc);
    bpr += fmaxf(1.f - psc + nsc, 0.f);
  }
  if (d == 0) {
    float hd = (nmax - pmin > 0.005f) ? 10.f * (nmax - pmin) : 0.f;
    atomicAdd(&slots[5], bpr + hd);
  }
}

__global__ void final_kernel(const float* __restrict__ slots, float* __restrict__ out) {
  if (threadIdx.x == 0 && blockIdx.x == 0) {
    float n = slots[0], dl = slots[1], nn = slots[2], dd = slots[3], nd = slots[4];
    float lr = slots[5] / (float)C_B;
    out[0] = lr + 0.2f * (n + dl) + 0.2f * (nn + dd + nd);
    out[1] = lr;
    out[2] = dl;
    out[3] = n;
  }
}

// ---------------- host ----------------
extern "C" void kernel_launch(void* const* d_in, const int* in_sizes, int n_in,
                              void* d_out, int out_size, void* d_ws, size_t ws_size,
                              hipStream_t stream) {
  (void)in_sizes; (void)n_in; (void)out_size;
  const float* E_u_0   = (const float*)d_in[0];
  const float* E_i_0   = (const float*)d_in[1];
  const float* adjvals = (const float*)d_in[2];
  const float* u_mul_s = (const float*)d_in[3];
  const float* v_mul_s = (const float*)d_in[4];
  const float* ut      = (const float*)d_in[5];
  const float* vt      = (const float*)d_in[6];
  const float* W_nn    = (const float*)d_in[7];
  const float* W_dd    = (const float*)d_in[8];
  const float* W_ng    = (const float*)d_in[9];
  const float* W_dg    = (const float*)d_in[10];
  const float* W_nd    = (const float*)d_in[11];
  const int* adj_rows  = (const int*)d_in[12];
  const int* adj_cols  = (const int*)d_in[13];
  const int* uids      = (const int*)d_in[14];
  const int* iids      = (const int*)d_in[15];
  const int* pos       = (const int*)d_in[16];
  const int* neg       = (const int*)d_in[17];
  float* out = (float*)d_out;

  const size_t NU64 = (size_t)C_NU * 64;
  const size_t NI64 = (size_t)C_NI * 64;
  const size_t B64  = (size_t)C_B * 64;

  float* w = (float*)d_ws;
  float* Eu1 = w; w += NU64;
  float* Eu2 = w; w += NU64;
  float* Ei1 = w; w += NI64;
  float* Ei2 = w; w += NI64;
  float* Zu  = w; w += NU64;   // Zu..Zdi contiguous; edgesA aliases this region
  float* Zdu = w; w += NU64;
  float* Zi  = w; w += NI64;
  float* Zdi = w; w += NI64;
  float* Mu = w; w += 512;
  float* Mi = w; w += 512;
  u16* normbuf16 = (u16*)w; w += 6 * B64;     // 12 bf16 buffers of B64
  float* slots = w; w += 16;
  uint2* edgesB = (uint2*)w; w += 4 * C_NE;   // 4M uint2 = 32 MB (final CSR, both dirs)
  u16* hyper16 = (u16*)edgesB;                // alias: edgesB dead before hyper
  uint32_t* cntA = (uint32_t*)w; w += NCB * NCHK * 2;   // 100352
  uint32_t* offs = (uint32_t*)w; w += NCB * NCHK * 2;
  uint32_t* bsumA = (uint32_t*)w; w += NCB;
  uint32_t* boffA = (uint32_t*)w; w += NCB;
  uint32_t* startsAbs = (uint32_t*)w; w += 2 * (NROW + 1);
  uint2* edgesA = (uint2*)Zu;  // alias: 32 MB coarse buffer, dead before spmm
  if ((size_t)((char*)w - (char*)d_ws) > ws_size) return;  // ws too small

  // ---- host-side JAX key derivation (partitionable threefry) ----
  auto ksplit = [](uint32_t a, uint32_t b, uint32_t idx, uint32_t& o0, uint32_t& o1) {
    uint32_t x0 = 0u, x1 = idx;
    tf2x32(a, b, x0, x1);
    o0 = x0; o1 = x1;
  };
  uint32_t rk0 = 0u, rk1 = 42u;
  uint32_t lk[2][4][2];  // [layer][k1 dropU, k2 dropI, k3 noiseU, k4 noiseI][pair]
  for (int l = 0; l < 2; ++l) {
    uint32_t n0, n1;
    ksplit(rk0, rk1, 0u, n0, n1);
    for (int i = 0; i < 4; ++i) ksplit(rk0, rk1, (uint32_t)(i + 1), lk[l][i][0], lk[l][i][1]);
    rk0 = n0; rk1 = n1;
  }
  NceKeys nk;
  {
    uint32_t mk0 = 0u, mk1 = 7u;
    for (int i = 0; i < 16; ++i) {
      uint32_t n0, n1;
      ksplit(mk0, mk1, 0u, n0, n1);
      ksplit(mk0, mk1, 1u, nk.k0[i], nk.k1[i]);
      mk0 = n0; mk1 = n1;
    }
  }
  DropKeys dk;
  dk.a[0] = lk[0][0][0]; dk.a[1] = lk[0][0][1];  // dir0 (->users) layer0
  dk.a[2] = lk[1][0][0]; dk.a[3] = lk[1][0][1];  // dir0 layer1
  dk.a[4] = lk[0][1][0]; dk.a[5] = lk[0][1][1];  // dir1 (->items) layer0
  dk.a[6] = lk[1][1][0]; dk.a[7] = lk[1][1][1];  // dir1 layer1
  WPtrs wp;
  wp.W[0] = W_ng; wp.W[1] = W_ng + 4096;
  wp.W[2] = W_nn;
  wp.W[3] = W_dg; wp.W[4] = W_dg + 4096;
  wp.W[5] = W_dd;
  wp.W[6] = W_nd; wp.W[7] = W_nd + 4096;

  // ---- two-level counting sort into per-row CSR (once; shared by layers) ----
  hipMemsetAsync(slots, 0, 16 * 4, stream);
  passA_hist<<<dim3(NCHK, 2), 256, 0, stream>>>(adj_rows, adj_cols, cntA);
  scanA1<<<NCB, 512, 0, stream>>>(cntA, offs, bsumA);
  scanA2<<<1, 256, 0, stream>>>(bsumA, boffA);
  scanA3<<<NCB, 512, 0, stream>>>(offs, boffA);
  passA_scatter<<<dim3(NCHK, 2), 256, 0, stream>>>(
      adj_rows, adj_cols, adjvals, offs, edgesA, dk);
  passB_kernel<<<dim3(NCB, 2), 512, 0, stream>>>(edgesA, offs, edgesB, startsAbs);

  const int gb = (int)(B64 / 256);  // 1024
  const int sb = (NROW + 3) / 4;    // 25000 blocks, 4 waves each

  for (int l = 0; l < 2; ++l) {
    const float* Eu_prev = (l == 0) ? E_u_0 : Eu1;
    const float* Ei_prev = (l == 0) ? E_i_0 : Ei1;
    float* Eu_next = (l == 0) ? Eu1 : Eu2;
    float* Ei_next = (l == 0) ? Ei1 : Ei2;
    hipMemsetAsync(Mu, 0, 1024 * 4, stream);
    svd_reduce<<<1024, 256, 0, stream>>>(vt, Ei_prev, Mu, C_NI);
    svd_reduce<<<1024, 256, 0, stream>>>(ut, Eu_prev, Mi, C_NU);
    // dir0: gather items -> users (noise key k3)
    spmm_row<<<sb, 256, 0, stream>>>(edgesB, startsAbs, Ei_prev, Eu_prev,
                                     Eu_next, Zu, Zdu,
                                     lk[l][2][0], lk[l][2][1], l);
    // dir1: gather users -> items (noise key k4)
    spmm_row<<<sb, 256, 0, stream>>>(edgesB, startsAbs + (NROW + 1), Eu_prev,
                                     Ei_prev, Ei_next, Zi, Zdi,
                                     lk[l][3][0], lk[l][3][1], l);
    gather_norm<<<dim3(gb, 3), 256, 0, stream>>>(
        uids, Zu, Zdu, u_mul_s, Mu,
        normbuf16 + (size_t)(0 + l) * B64, normbuf16 + (size_t)(4 + l) * B64,
        normbuf16 + (size_t)(8 + l) * B64);
    gather_norm<<<dim3(gb, 3), 256, 0, stream>>>(
        iids, Zi, Zdi, v_mul_s, Mi,
        normbuf16 + (size_t)(2 + l) * B64, normbuf16 + (size_t)(6 + l) * B64,
        normbuf16 + (size_t)(10 + l) * B64);
  }

  hyper_kernel<<<dim3(gb, 16), 256, 0, stream>>>(normbuf16, hyper16, wp);
  nce_mfma<<<dim3(C_B / 64, 16), 256, 0, stream>>>(normbuf16, hyper16, slots, nk);
  loss_r_kernel<<<gb, 256, 0, stream>>>(E_u_0, Eu1, Eu2, E_i_0, Ei1, Ei2,
                                        uids, pos, neg, slots);
  final_kernel<<<1, 1, 0, stream>>>(slots, out);
}

// Round 6
// 1173.146 us; speedup vs baseline: 7.2457x; 1.0359x over previous
//
#include <hip/hip_runtime.h>
#include <hip/hip_bf16.h>
#include <cstdint>

#define C_NU 100000
#define C_NI 100000
#define C_DIM 64
#define C_Q 5
#define C_NE 2000000
#define C_B 4096
#define C_P 10
#define NROW 100000
#define NCB 196      // coarse buckets of 512 rows
#define NCHK 256     // chunks in pass A
#define CHUNK 7813   // ceil(2M/256)

typedef unsigned short u16;
typedef __attribute__((ext_vector_type(8))) short short8;
typedef __attribute__((ext_vector_type(4))) float f32x4;

// ---------------- Threefry-2x32 (JAX-compatible), 20 rounds ----------------
__host__ __device__ static inline void tf2x32(uint32_t k0, uint32_t k1,
                                              uint32_t& x0, uint32_t& x1) {
  uint32_t k2 = k0 ^ k1 ^ 0x1BD11BDAu;
#define TFR(r) { x0 += x1; x1 = (x1 << r) | (x1 >> (32 - r)); x1 ^= x0; }
  x0 += k0; x1 += k1;
  TFR(13) TFR(15) TFR(26) TFR(6)
  x0 += k1; x1 += k2 + 1u;
  TFR(17) TFR(29) TFR(16) TFR(24)
  x0 += k2; x1 += k0 + 2u;
  TFR(13) TFR(15) TFR(26) TFR(6)
  x0 += k0; x1 += k1 + 3u;
  TFR(17) TFR(29) TFR(16) TFR(24)
  x0 += k1; x1 += k2 + 4u;
  TFR(13) TFR(15) TFR(26) TFR(6)
  x0 += k2; x1 += k0 + 5u;
#undef TFR
}

// partitionable-mode random bits at flat index idx (hi counter = 0)
__device__ static inline float tf_uniform(uint32_t k0, uint32_t k1, uint32_t idx) {
  uint32_t x0 = 0u, x1 = idx;
  tf2x32(k0, k1, x0, x1);
  uint32_t bits = x0 ^ x1;
  return __uint_as_float((bits >> 9) | 0x3F800000u) - 1.0f;
}

__device__ static inline float leaky(float x) { return x >= 0.f ? x : 0.5f * x; }

__device__ static inline u16 f2bf(float f) {  // RNE fp32->bf16
  uint32_t x = __float_as_uint(f);
  return (u16)((x + 0x7FFFu + ((x >> 16) & 1u)) >> 16);
}
__device__ static inline float bf2f(u16 u) {
  return __uint_as_float((uint32_t)u << 16);
}

// ---------------- constant maps for the 16 info_nce calls ----------------
// normbuf slots: 0:Zu1 1:Zu2 2:Zi1 3:Zi2 4:Zdu1 5:Zdu2 6:Zdi1 7:Zdi2 8:Gu1 9:Gu2 10:Gi1 11:Gi2
__constant__ int c_gsel[16] = {0,1,2,3, 0,2, 4,5,6,7, 4,6, 0,1,2,3};
__constant__ int c_hsrc[16] = {8,9,10,11, 1,3, 8,9,10,11, 5,7, 4,5,6,7};
// W order: 0:ng0 1:ng1 2:nn 3:dg0 4:dg1 5:dd 6:nd0 7:nd1
__constant__ int c_wsel[16] = {0,1,0,1, 2,2, 3,4,3,4, 5,5, 6,7,6,7};
// slots: 0:n 1:d 2:nn 3:dd 4:nd (5: loss_r sum)
__constant__ int c_slot[16] = {0,0,0,0, 2,2, 1,1,1,1, 3,3, 4,4,4,4};

struct WPtrs { const float* W[8]; };
struct NceKeys { uint32_t k0[16]; uint32_t k1[16]; };
struct DropKeys { uint32_t a[8]; };  // [dir0 l0 pair, dir0 l1 pair, dir1 l0 pair, dir1 l1 pair]

// ---------------- two-level counting sort ----------------

__global__ __launch_bounds__(256) void passA_hist(
    const int* __restrict__ rows, const int* __restrict__ cols,
    uint32_t* __restrict__ cntA) {
  __shared__ uint32_t h[NCB];
  const int dir = blockIdx.y, c = blockIdx.x, t = threadIdx.x;
  for (int i = t; i < NCB; i += 256) h[i] = 0u;
  __syncthreads();
  const int e0 = c * CHUNK, e1 = min(e0 + CHUNK, C_NE);
  const int* ids = dir ? cols : rows;
  for (int e = e0 + t; e < e1; e += 256) atomicAdd(&h[ids[e] >> 9], 1u);
  __syncthreads();
  for (int i = t; i < NCB; i += 256) cntA[(dir * NCB + i) * NCHK + c] = h[i];
}

__global__ __launch_bounds__(512) void scanA1(
    const uint32_t* __restrict__ cntA, uint32_t* __restrict__ offs,
    uint32_t* __restrict__ bsum) {
  __shared__ uint32_t s[512];
  const int b = blockIdx.x, t = threadIdx.x;
  const int idx = b * 512 + t;
  uint32_t v = cntA[idx];
  s[t] = v;
  __syncthreads();
  for (int off = 1; off < 512; off <<= 1) {
    uint32_t a = (t >= off) ? s[t - off] : 0u;
    __syncthreads();
    s[t] += a;
    __syncthreads();
  }
  offs[idx] = s[t] - v;
  if (t == 511) bsum[b] = s[511];
}

__global__ __launch_bounds__(256) void scanA2(
    const uint32_t* __restrict__ bsum, uint32_t* __restrict__ boff) {
  __shared__ uint32_t s[256];
  const int t = threadIdx.x;
  uint32_t v = (t < NCB) ? bsum[t] : 0u;
  s[t] = v;
  __syncthreads();
  for (int off = 1; off < 256; off <<= 1) {
    uint32_t a = (t >= off) ? s[t - off] : 0u;
    __syncthreads();
    s[t] += a;
    __syncthreads();
  }
  if (t < NCB) boff[t] = s[t] - v;
}

__global__ __launch_bounds__(512) void scanA3(
    uint32_t* __restrict__ offs, const uint32_t* __restrict__ boff) {
  offs[blockIdx.x * 512 + threadIdx.x] += boff[blockIdx.x];
}

// record.x = src(17b) | keepL0<<17 | keepL1<<18 | (dst&511)<<19
__global__ __launch_bounds__(256) void passA_scatter(
    const int* __restrict__ rows, const int* __restrict__ cols,
    const float* __restrict__ vals, const uint32_t* __restrict__ offs,
    uint2* __restrict__ edgesA, DropKeys dk) {
  __shared__ uint32_t lofs[NCB];
  const int dir = blockIdx.y, c = blockIdx.x, t = threadIdx.x;
  for (int i = t; i < NCB; i += 256) lofs[i] = offs[(dir * NCB + i) * NCHK + c];
  __syncthreads();
  const int e0 = c * CHUNK, e1 = min(e0 + CHUNK, C_NE);
  const uint32_t kA0 = dk.a[dir * 4 + 0], kA1 = dk.a[dir * 4 + 1];
  const uint32_t kB0 = dk.a[dir * 4 + 2], kB1 = dk.a[dir * 4 + 3];
  for (int e = e0 + t; e < e1; e += 256) {
    const int r = rows[e], cc = cols[e];
    const int dst = dir ? cc : r, src = dir ? r : cc;
    const uint32_t kl0 = (tf_uniform(kA0, kA1, (uint32_t)e) < 0.9f) ? 1u : 0u;
    const uint32_t kl1 = (tf_uniform(kB0, kB1, (uint32_t)e) < 0.9f) ? 1u : 0u;
    const uint32_t x = (uint32_t)src | (kl0 << 17) | (kl1 << 18) |
                       ((uint32_t)(dst & 511) << 19);
    const uint32_t pos = atomicAdd(&lofs[dst >> 9], 1u);
    edgesA[pos] = make_uint2(x, __float_as_uint(vals[e]));
  }
}

__global__ __launch_bounds__(512) void passB_kernel(
    const uint2* __restrict__ edgesA, const uint32_t* __restrict__ offs,
    uint2* __restrict__ edgesB, uint32_t* __restrict__ starts) {
  __shared__ uint32_t cnt[512];
  __shared__ uint32_t scn[512];
  const int dir = blockIdx.y, cb = blockIdx.x, t = threadIdx.x;
  const uint32_t segStart = offs[(dir * NCB + cb) * NCHK];
  const uint32_t segEnd = (dir == 1 && cb == NCB - 1)
                              ? (uint32_t)(2 * C_NE)
                              : offs[(dir * NCB + cb + 1) * NCHK];
  cnt[t] = 0u;
  __syncthreads();
  for (uint32_t e = segStart + t; e < segEnd; e += 512)
    atomicAdd(&cnt[(edgesA[e].x >> 19) & 511u], 1u);
  __syncthreads();
  uint32_t v = cnt[t];
  scn[t] = v;
  __syncthreads();
  for (int off = 1; off < 512; off <<= 1) {
    uint32_t a = (t >= off) ? scn[t - off] : 0u;
    __syncthreads();
    scn[t] += a;
    __syncthreads();
  }
  const uint32_t rstart = segStart + scn[t] - v;
  const int grow = cb * 512 + t;
  if (grow < NROW) starts[dir * (NROW + 1) + grow] = rstart;
  if (cb == NCB - 1 && t == 0) starts[dir * (NROW + 1) + NROW] = segEnd;
  cnt[t] = rstart;
  __syncthreads();
  for (uint32_t e = segStart + t; e < segEnd; e += 512) {
    const uint2 q = edgesA[e];
    const uint32_t pos = atomicAdd(&cnt[(q.x >> 19) & 511u], 1u);
    edgesB[pos] = q;
  }
}

// ---------------- fp32 -> bf16 convert (float4 -> ushort4) ----------------
__global__ __launch_bounds__(256) void bf16_convert(
    const float* __restrict__ src, u16* __restrict__ dst, int n4) {
  int i = blockIdx.x * 256 + threadIdx.x;
  if (i >= n4) return;
  float4 v = ((const float4*)src)[i];
  ushort4 o;
  o.x = f2bf(v.x); o.y = f2bf(v.y); o.z = f2bf(v.z); o.w = f2bf(v.w);
  ((ushort4*)dst)[i] = o;
}

// Wt16[w][d][k] = bf16(W[w][k][d])  (pre-transposed for MFMA B-operand)
__global__ __launch_bounds__(256) void w16_prep(WPtrs wp, u16* __restrict__ Wt16) {
  int i = blockIdx.x * 256 + threadIdx.x;
  if (i >= 8 * 4096) return;
  int w = i >> 12, kd = i & 4095, k = kd >> 6, d = kd & 63;
  Wt16[w * 4096 + d * 64 + k] = f2bf(wp.W[w][k * 64 + d]);
}

// ---------------- fused spmm (one wave per dst row, bf16 gathers) ----------------
__global__ __launch_bounds__(256) void spmm_row(
    const uint2* __restrict__ edges, const uint32_t* __restrict__ starts,
    const u16* __restrict__ Einb, const float* __restrict__ Eprev,
    float* __restrict__ Enext, u16* __restrict__ Enb16,
    float* __restrict__ Zout, float* __restrict__ Zdout,
    uint32_t nk0, uint32_t nk1, int layer) {
  const int row = blockIdx.x * 4 + (threadIdx.x >> 6);
  const int lane = threadIdx.x & 63;
  if (row >= NROW) return;
  const uint32_t s0 = starts[row], s1 = starts[row + 1];
  const uint32_t kbit = 1u << (17 + layer);
  float z = 0.f, zd = 0.f;
  uint32_t e = s0;
  for (; e + 4 <= s1; e += 4) {
    const uint2 q0 = edges[e], q1 = edges[e + 1], q2 = edges[e + 2], q3 = edges[e + 3];
    const float x0 = bf2f(Einb[(size_t)(q0.x & 0x1FFFFu) * 64 + lane]);
    const float x1 = bf2f(Einb[(size_t)(q1.x & 0x1FFFFu) * 64 + lane]);
    const float x2 = bf2f(Einb[(size_t)(q2.x & 0x1FFFFu) * 64 + lane]);
    const float x3 = bf2f(Einb[(size_t)(q3.x & 0x1FFFFu) * 64 + lane]);
    const float t0 = __uint_as_float(q0.y) * x0;
    const float t1 = __uint_as_float(q1.y) * x1;
    const float t2 = __uint_as_float(q2.y) * x2;
    const float t3 = __uint_as_float(q3.y) * x3;
    z += t0; if (q0.x & kbit) zd += t0;
    z += t1; if (q1.x & kbit) zd += t1;
    z += t2; if (q2.x & kbit) zd += t2;
    z += t3; if (q3.x & kbit) zd += t3;
  }
  for (; e < s1; ++e) {
    const uint2 q = edges[e];
    const float x = bf2f(Einb[(size_t)(q.x & 0x1FFFFu) * 64 + lane]);
    const float t = __uint_as_float(q.y) * x;
    z += t; if (q.x & kbit) zd += t;
  }
  z = leaky(z);
  zd = leaky(zd * (1.0f / 0.9f));
  // noise-augmented view
  const float u = tf_uniform(nk0, nk1, (uint32_t)row * 64u + (uint32_t)lane);
  float ss = u * u;
#pragma unroll
  for (int off = 1; off < 64; off <<= 1) ss += __shfl_xor(ss, off);
  const float nrm = fmaxf(sqrtf(ss), 1e-12f);
  const float sg = (z > 0.f) ? 1.f : (z < 0.f ? -1.f : 0.f);
  z += sg * (u / nrm) * 0.1f;
  const size_t j = (size_t)row * 64 + lane;
  Zout[j] = z;
  Zdout[j] = zd;
  if (Enext) {  // layer 0 only: materialize E1 (fp32 + bf16 for next-layer gathers)
    const float en = z + zd + Eprev[j];
    Enext[j] = en;
    Enb16[j] = f2bf(en);
  }
}

// M[q][d] = sum_n T[q][n] * E[n][d]
__global__ __launch_bounds__(256) void svd_reduce(
    const float* __restrict__ T, const float* __restrict__ E,
    float* __restrict__ M, int n) {
  int wid = (int)(((long long)blockIdx.x * blockDim.x + threadIdx.x) >> 6);
  int lane = threadIdx.x & 63;
  int nw = (gridDim.x * blockDim.x) >> 6;
  float acc[5] = {0.f, 0.f, 0.f, 0.f, 0.f};
  for (int i = wid; i < n; i += nw) {
    float x = E[(size_t)i * 64 + lane];
#pragma unroll
    for (int q = 0; q < 5; ++q) acc[q] += T[(size_t)q * n + i] * x;
  }
#pragma unroll
  for (int q = 0; q < 5; ++q) atomicAdd(&M[q * 64 + lane], acc[q]);
}

// gather batch rows & L2-normalize -> bf16; blockIdx.y selects {Z, Zd, G}
__global__ __launch_bounds__(256) void gather_norm(
    const int* __restrict__ ids, const float* __restrict__ Z,
    const float* __restrict__ Zd, const float* __restrict__ mul_s,
    const float* __restrict__ M, u16* __restrict__ oZ,
    u16* __restrict__ oZd, u16* __restrict__ oG) {
  long long t = (long long)blockIdx.x * blockDim.x + threadIdx.x;
  int b = (int)(t >> 6);
  int d = (int)(t & 63);
  if (b >= C_B) return;
  int id = ids[b];
  float v;
  u16* out;
  if (blockIdx.y == 0) { v = Z[(size_t)id * 64 + d]; out = oZ; }
  else if (blockIdx.y == 1) { v = Zd[(size_t)id * 64 + d]; out = oZd; }
  else {
    float s = 0.f;
#pragma unroll
    for (int q = 0; q < 5; ++q) s += mul_s[(size_t)id * 5 + q] * M[q * 64 + d];
    v = leaky(s);
    out = oG;
  }
  float ss = v * v;
#pragma unroll
  for (int off = 1; off < 64; off <<= 1) ss += __shfl_xor(ss, off);
  float nrm = fmaxf(sqrtf(ss), 1e-12f);
  out[(size_t)b * 64 + d] = f2bf(v / nrm);
}

// ---------------- MFMA hyper: hy[call] = normbuf[hsrc] @ W[wsel] ----------------
__global__ __launch_bounds__(256) void hyper_mfma(
    const u16* __restrict__ nb, const u16* __restrict__ Wt16,
    u16* __restrict__ hy) {
  const int call = blockIdx.y;
  const int b0 = blockIdx.x * 64;
  __shared__ u16 Xs[64 * 64];
  __shared__ u16 Ws[64 * 64];
  const int tid = threadIdx.x, lane = tid & 63, wid = tid >> 6;
  const u16* X = nb + (size_t)c_hsrc[call] * C_B * 64;
  const u16* Wt = Wt16 + (size_t)c_wsel[call] * 4096;
  {
    const int r = tid >> 2, seg = tid & 3;
    const int base = r * 128 + seg * 32, sw = (r & 7) << 4;
    const uint4* sx = (const uint4*)&X[(size_t)(b0 + r) * 64 + seg * 16];
    uint4 a = sx[0], b = sx[1];
    *(uint4*)((char*)Xs + (base ^ sw)) = a;
    *(uint4*)((char*)Xs + ((base + 16) ^ sw)) = b;
    const uint4* sv = (const uint4*)&Wt[r * 64 + seg * 16];
    uint4 c = sv[0], d = sv[1];
    *(uint4*)((char*)Ws + (base ^ sw)) = c;
    *(uint4*)((char*)Ws + ((base + 16) ^ sw)) = d;
  }
  __syncthreads();
  const int am = (wid << 4) + (lane & 15);  // A (X) row within tile
  short8 af[2];
#pragma unroll
  for (int ks = 0; ks < 2; ++ks) {
    const int off = (am * 128 + ks * 64 + ((lane >> 4) << 4)) ^ ((am & 7) << 4);
    af[ks] = *(const short8*)((const char*)Xs + off);
  }
  const int ob = b0 + (wid << 4) + ((lane >> 4) << 2);
#pragma unroll
  for (int n = 0; n < 4; ++n) {
    const int bn = (n << 4) + (lane & 15);  // B (Wt) row = output col d
    f32x4 acc = {0.f, 0.f, 0.f, 0.f};
#pragma unroll
    for (int ks = 0; ks < 2; ++ks) {
      const int off = (bn * 128 + ks * 64 + ((lane >> 4) << 4)) ^ ((bn & 7) << 4);
      short8 bf = *(const short8*)((const char*)Ws + off);
      acc = __builtin_amdgcn_mfma_f32_16x16x32_bf16(af[ks], bf, acc, 0, 0, 0);
    }
    const int d = (n << 4) + (lane & 15);
#pragma unroll
    for (int j = 0; j < 4; ++j)
      hy[(size_t)call * C_B * 64 + (size_t)(ob + j) * 64 + d] = f2bf(acc[j]);
  }
}

// ---------------- MFMA info_nce (double-buffered H staging) ----------------
__global__ __launch_bounds__(256) void nce_mfma(
    const u16* __restrict__ nb, const u16* __restrict__ hy,
    float* __restrict__ slots, NceKeys nk) {
  const int call = blockIdx.y;
  const u16* G = nb + (size_t)c_gsel[call] * C_B * 64;
  const u16* H = hy + (size_t)call * C_B * 64;
  const int br = blockIdx.x * 64;
  __shared__ u16 Gs[64 * 64];
  __shared__ u16 Hs[2][64 * 64];
  const int tid = threadIdx.x, lane = tid & 63, wid = tid >> 6;
  const int r = tid >> 2, seg = tid & 3;
  const int base = r * 128 + seg * 32, sw = (r & 7) << 4;
  {
    const uint4* src = (const uint4*)&G[(size_t)(br + r) * 64 + seg * 16];
    uint4 a = src[0], b = src[1];
    *(uint4*)((char*)Gs + (base ^ sw)) = a;
    *(uint4*)((char*)Gs + ((base + 16) ^ sw)) = b;
  }
  {
    const uint4* src = (const uint4*)&H[(size_t)r * 64 + seg * 16];
    uint4 a = src[0], b = src[1];
    *(uint4*)((char*)Hs[0] + (base ^ sw)) = a;
    *(uint4*)((char*)Hs[0] + ((base + 16) ^ sw)) = b;
  }
  const int gcol = (wid << 4) + (lane & 15);
  const int g_glob = br + gcol;
  float rs = 0.f, ps = 0.f;
  short8 bfG[2];
  int cur = 0;
  for (int jt = 0; jt < 64; ++jt) {
    __syncthreads();  // Hs[cur] (and Gs on first iter) ready
    if (jt == 0) {
#pragma unroll
      for (int ks = 0; ks < 2; ++ks) {
        const int off = (gcol * 128 + ks * 64 + ((lane >> 4) << 4)) ^ ((gcol & 7) << 4);
        bfG[ks] = *(const short8*)((const char*)Gs + off);
      }
    }
    uint4 na, nb_;
    if (jt + 1 < 64) {  // prefetch next H tile (latency hidden under compute)
      const uint4* src = (const uint4*)&H[(size_t)((jt + 1) * 64 + r) * 64 + seg * 16];
      na = src[0]; nb_ = src[1];
    }
    const char* Hb = (const char*)(Hs[cur]);
#pragma unroll
    for (int hs = 0; hs < 4; ++hs) {
      const int hr = (hs << 4) + (lane & 15);
      f32x4 acc = {0.f, 0.f, 0.f, 0.f};
#pragma unroll
      for (int ks = 0; ks < 2; ++ks) {
        const int off = (hr * 128 + ks * 64 + ((lane >> 4) << 4)) ^ ((hr & 7) << 4);
        short8 af = *(const short8*)(Hb + off);
        acc = __builtin_amdgcn_mfma_f32_16x16x32_bf16(af, bfG[ks], acc, 0, 0, 0);
      }
      const int hbase = jt * 64 + (hs << 4) + ((lane >> 4) << 2);
#pragma unroll
      for (int j = 0; j < 4; ++j) {
        float e = __expf(acc[j] * 5.0f);  // exp(score/TEMP)
        rs += e;
        if (hbase + j == g_glob) ps = e;
      }
    }
    if (jt + 1 < 64) {
      *(uint4*)((char*)Hs[cur ^ 1] + (base ^ sw)) = na;
      *(uint4*)((char*)Hs[cur ^ 1] + ((base + 16) ^ sw)) = nb_;
    }
    cur ^= 1;
  }
  rs += __shfl_xor(rs, 16); rs += __shfl_xor(rs, 32);
  ps += __shfl_xor(ps, 16); ps += __shfl_xor(ps, 32);
  float c = 0.f;
  if ((lane >> 4) == 0) {
    float v = -__logf(ps / (rs + 1e-8f) + 1e-8f);
    float u = tf_uniform(nk.k0[call], nk.k1[call], (uint32_t)g_glob);
    c = (u > 0.5f) ? v : 0.f;
  }
  c += __shfl_xor(c, 1); c += __shfl_xor(c, 2);
  c += __shfl_xor(c, 4); c += __shfl_xor(c, 8);
  if (lane == 0) atomicAdd(&slots[c_slot[call]], c);
}

// E_sum = E0 + 2*E1 + Z2 + Zd2  (E2 never materialized)
__global__ __launch_bounds__(256) void loss_r_kernel(
    const float* __restrict__ E0u, const float* __restrict__ Eu1,
    const float* __restrict__ Zu, const float* __restrict__ Zdu,
    const float* __restrict__ E0i, const float* __restrict__ Ei1,
    const float* __restrict__ Zi, const float* __restrict__ Zdi,
    const int* __restrict__ uids, const int* __restrict__ pos,
    const int* __restrict__ neg, float* __restrict__ slots) {
  long long t = (long long)blockIdx.x * blockDim.x + threadIdx.x;
  int b = (int)(t >> 6);
  int d = (int)(t & 63);
  if (b >= C_B) return;
  size_t ju = (size_t)uids[b] * 64 + d;
  float u = E0u[ju] + 2.f * Eu1[ju] + Zu[ju] + Zdu[ju];
  float bpr = 0.f, pmin = 3.4e38f, nmax = -3.4e38f;
  for (int p = 0; p < C_P; ++p) {
    size_t jp = (size_t)pos[b * C_P + p] * 64 + d;
    size_t jn = (size_t)neg[b * C_P + p] * 64 + d;
    float pe = E0i[jp] + 2.f * Ei1[jp] + Zi[jp] + Zdi[jp];
    float ne = E0i[jn] + 2.f * Ei1[jn] + Zi[jn] + Zdi[jn];
    float psc = u * pe, nsc = u * ne;
#pragma unroll
    for (int off = 1; off < 64; off <<= 1) {
      psc += __shfl_xor(psc, off);
      nsc += __shfl_xor(nsc, off);
    }
    pmin = fminf(pmin, psc);
    nmax = fmaxf(nmax, nsc);
    bpr += fmaxf(1.f - psc + nsc, 0.f);
  }
  if (d == 0) {
    float hd = (nmax - pmin > 0.005f) ? 10.f * (nmax - pmin) : 0.f;
    atomicAdd(&slots[5], bpr + hd);
  }
}

__global__ void final_kernel(const float* __restrict__ slots, float* __restrict__ out) {
  if (threadIdx.x == 0 && blockIdx.x == 0) {
    float n = slots[0], dl = slots[1], nn = slots[2], dd = slots[3], nd = slots[4];
    float lr = slots[5] / (float)C_B;
    out[0] = lr + 0.2f * (n + dl) + 0.2f * (nn + dd + nd);
    out[1] = lr;
    out[2] = dl;
    out[3] = n;
  }
}

// ---------------- host ----------------
extern "C" void kernel_launch(void* const* d_in, const int* in_sizes, int n_in,
                              void* d_out, int out_size, void* d_ws, size_t ws_size,
                              hipStream_t stream) {
  (void)in_sizes; (void)n_in; (void)out_size;
  const float* E_u_0   = (const float*)d_in[0];
  const float* E_i_0   = (const float*)d_in[1];
  const float* adjvals = (const float*)d_in[2];
  const float* u_mul_s = (const float*)d_in[3];
  const float* v_mul_s = (const float*)d_in[4];
  const float* ut      = (const float*)d_in[5];
  const float* vt      = (const float*)d_in[6];
  const float* W_nn    = (const float*)d_in[7];
  const float* W_dd    = (const float*)d_in[8];
  const float* W_ng    = (const float*)d_in[9];
  const float* W_dg    = (const float*)d_in[10];
  const float* W_nd    = (const float*)d_in[11];
  const int* adj_rows  = (const int*)d_in[12];
  const int* adj_cols  = (const int*)d_in[13];
  const int* uids      = (const int*)d_in[14];
  const int* iids      = (const int*)d_in[15];
  const int* pos       = (const int*)d_in[16];
  const int* neg       = (const int*)d_in[17];
  float* out = (float*)d_out;

  const size_t NU64 = (size_t)C_NU * 64;
  const size_t NI64 = (size_t)C_NI * 64;
  const size_t B64  = (size_t)C_B * 64;

  float* w = (float*)d_ws;
  float* Eu1 = w; w += NU64;
  float* Ei1 = w; w += NI64;
  float* Zu  = w; w += NU64;   // edgesA aliases Zu..Zdu
  float* Zdu = w; w += NU64;
  float* Zi  = w; w += NI64;
  float* Zdi = w; w += NI64;
  float* Mu = w; w += 512;
  float* Mi = w; w += 512;
  u16* normbuf16 = (u16*)w; w += 6 * B64;     // 12 bf16 buffers of B64
  float* slots = w; w += 16;
  uint2* edgesB = (uint2*)w; w += 4 * C_NE;   // 32 MB final CSR (both dirs)
  u16* hyper16 = (u16*)edgesB;                // alias: edgesB dead before hyper
  u16* Wt16 = (u16*)w; w += 16384;            // 8 x 64x64 bf16 (transposed)
  uint32_t* cntA = (uint32_t*)w; w += NCB * NCHK * 2;
  uint32_t* offs = (uint32_t*)w; w += NCB * NCHK * 2;
  uint32_t* bsumA = (uint32_t*)w; w += NCB;
  uint32_t* boffA = (uint32_t*)w; w += NCB;
  uint32_t* startsAbs = (uint32_t*)w; w += 2 * (NROW + 1);
  u16* Eu0b = (u16*)w; w += NU64 / 2;         // bf16 copies for gathers
  u16* Ei0b = (u16*)w; w += NI64 / 2;         // (Ei1b aliases Ei0b)
  u16* Eu1b = (u16*)w; w += NU64 / 2;
  u16* Ei1b = Ei0b;                           // Ei0b dead once dir1-l0 runs
  uint2* edgesA = (uint2*)Zu;                 // 32 MB coarse buffer, dead before spmm
  if ((size_t)((char*)w - (char*)d_ws) > ws_size) return;

  // ---- host-side JAX key derivation (partitionable threefry) ----
  auto ksplit = [](uint32_t a, uint32_t b, uint32_t idx, uint32_t& o0, uint32_t& o1) {
    uint32_t x0 = 0u, x1 = idx;
    tf2x32(a, b, x0, x1);
    o0 = x0; o1 = x1;
  };
  uint32_t rk0 = 0u, rk1 = 42u;
  uint32_t lk[2][4][2];
  for (int l = 0; l < 2; ++l) {
    uint32_t n0, n1;
    ksplit(rk0, rk1, 0u, n0, n1);
    for (int i = 0; i < 4; ++i) ksplit(rk0, rk1, (uint32_t)(i + 1), lk[l][i][0], lk[l][i][1]);
    rk0 = n0; rk1 = n1;
  }
  NceKeys nk;
  {
    uint32_t mk0 = 0u, mk1 = 7u;
    for (int i = 0; i < 16; ++i) {
      uint32_t n0, n1;
      ksplit(mk0, mk1, 0u, n0, n1);
      ksplit(mk0, mk1, 1u, nk.k0[i], nk.k1[i]);
      mk0 = n0; mk1 = n1;
    }
  }
  DropKeys dk;
  dk.a[0] = lk[0][0][0]; dk.a[1] = lk[0][0][1];
  dk.a[2] = lk[1][0][0]; dk.a[3] = lk[1][0][1];
  dk.a[4] = lk[0][1][0]; dk.a[5] = lk[0][1][1];
  dk.a[6] = lk[1][1][0]; dk.a[7] = lk[1][1][1];
  WPtrs wp;
  wp.W[0] = W_ng; wp.W[1] = W_ng + 4096;
  wp.W[2] = W_nn;
  wp.W[3] = W_dg; wp.W[4] = W_dg + 4096;
  wp.W[5] = W_dd;
  wp.W[6] = W_nd; wp.W[7] = W_nd + 4096;

  // ---- sort + preps ----
  hipMemsetAsync(slots, 0, 16 * 4, stream);
  passA_hist<<<dim3(NCHK, 2), 256, 0, stream>>>(adj_rows, adj_cols, cntA);
  scanA1<<<NCB, 512, 0, stream>>>(cntA, offs, bsumA);
  scanA2<<<1, 256, 0, stream>>>(bsumA, boffA);
  scanA3<<<NCB, 512, 0, stream>>>(offs, boffA);
  passA_scatter<<<dim3(NCHK, 2), 256, 0, stream>>>(
      adj_rows, adj_cols, adjvals, offs, edgesA, dk);
  passB_kernel<<<dim3(NCB, 2), 512, 0, stream>>>(edgesA, offs, edgesB, startsAbs);
  bf16_convert<<<(int)(NU64 / 4 + 255) / 256, 256, 0, stream>>>(E_u_0, Eu0b, (int)(NU64 / 4));
  bf16_convert<<<(int)(NI64 / 4 + 255) / 256, 256, 0, stream>>>(E_i_0, Ei0b, (int)(NI64 / 4));
  w16_prep<<<(8 * 4096 + 255) / 256, 256, 0, stream>>>(wp, Wt16);

  const int gb = (int)(B64 / 256);  // 1024
  const int sb = (NROW + 3) / 4;    // 25000 blocks, 4 waves each

  for (int l = 0; l < 2; ++l) {
    hipMemsetAsync(Mu, 0, 1024 * 4, stream);
    svd_reduce<<<1024, 256, 0, stream>>>(vt, (l == 0) ? E_i_0 : Ei1, Mu, C_NI);
    svd_reduce<<<1024, 256, 0, stream>>>(ut, (l == 0) ? E_u_0 : Eu1, Mi, C_NU);
    // dir0: items -> users (noise key k3)
    spmm_row<<<sb, 256, 0, stream>>>(
        edgesB, startsAbs, (l == 0) ? Ei0b : Ei1b,
        (l == 0) ? E_u_0 : nullptr, (l == 0) ? Eu1 : nullptr,
        (l == 0) ? Eu1b : nullptr, Zu, Zdu, lk[l][2][0], lk[l][2][1], l);
    // dir1: users -> items (noise key k4)
    spmm_row<<<sb, 256, 0, stream>>>(
        edgesB, startsAbs + (NROW + 1), (l == 0) ? Eu0b : Eu1b,
        (l == 0) ? E_i_0 : nullptr, (l == 0) ? Ei1 : nullptr,
        (l == 0) ? Ei1b : nullptr, Zi, Zdi, lk[l][3][0], lk[l][3][1], l);
    gather_norm<<<dim3(gb, 3), 256, 0, stream>>>(
        uids, Zu, Zdu, u_mul_s, Mu,
        normbuf16 + (size_t)(0 + l) * B64, normbuf16 + (size_t)(4 + l) * B64,
        normbuf16 + (size_t)(8 + l) * B64);
    gather_norm<<<dim3(gb, 3), 256, 0, stream>>>(
        iids, Zi, Zdi, v_mul_s, Mi,
        normbuf16 + (size_t)(2 + l) * B64, normbuf16 + (size_t)(6 + l) * B64,
        normbuf16 + (size_t)(10 + l) * B64);
  }

  hyper_mfma<<<dim3(C_B / 64, 16), 256, 0, stream>>>(normbuf16, Wt16, hyper16);
  nce_mfma<<<dim3(C_B / 64, 16), 256, 0, stream>>>(normbuf16, hyper16, slots, nk);
  loss_r_kernel<<<gb, 256, 0, stream>>>(E_u_0, Eu1, Zu, Zdu, E_i_0, Ei1, Zi, Zdi,
                                        uids, pos, neg, slots);
  final_kernel<<<1, 1, 0, stream>>>(slots, out);
}

// Round 7
// 1079.243 us; speedup vs baseline: 7.8761x; 1.0870x over previous
//
#include <hip/hip_runtime.h>
#include <hip/hip_bf16.h>
#include <cstdint>

#define C_NU 100000
#define C_NI 100000
#define C_DIM 64
#define C_Q 5
#define C_NE 2000000
#define C_B 4096
#define C_P 10
#define NROW 100000
#define NCB 196      // coarse buckets of 512 rows
#define NCHK 256     // chunks in pass A
#define CHUNK 7813   // ceil(2M/256)

typedef unsigned short u16;
typedef __attribute__((ext_vector_type(8))) short short8;
typedef __attribute__((ext_vector_type(4))) float f32x4;

__device__ static inline int rfl(int v) { return __builtin_amdgcn_readfirstlane(v); }
__device__ static inline uint32_t rflu(uint32_t v) {
  return (uint32_t)__builtin_amdgcn_readfirstlane((int)v);
}

// ---------------- Threefry-2x32 (JAX-compatible), 20 rounds ----------------
__host__ __device__ static inline void tf2x32(uint32_t k0, uint32_t k1,
                                              uint32_t& x0, uint32_t& x1) {
  uint32_t k2 = k0 ^ k1 ^ 0x1BD11BDAu;
#define TFR(r) { x0 += x1; x1 = (x1 << r) | (x1 >> (32 - r)); x1 ^= x0; }
  x0 += k0; x1 += k1;
  TFR(13) TFR(15) TFR(26) TFR(6)
  x0 += k1; x1 += k2 + 1u;
  TFR(17) TFR(29) TFR(16) TFR(24)
  x0 += k2; x1 += k0 + 2u;
  TFR(13) TFR(15) TFR(26) TFR(6)
  x0 += k0; x1 += k1 + 3u;
  TFR(17) TFR(29) TFR(16) TFR(24)
  x0 += k1; x1 += k2 + 4u;
  TFR(13) TFR(15) TFR(26) TFR(6)
  x0 += k2; x1 += k0 + 5u;
#undef TFR
}

// partitionable-mode random bits at flat index idx (hi counter = 0)
__device__ static inline float tf_uniform(uint32_t k0, uint32_t k1, uint32_t idx) {
  uint32_t x0 = 0u, x1 = idx;
  tf2x32(k0, k1, x0, x1);
  uint32_t bits = x0 ^ x1;
  return __uint_as_float((bits >> 9) | 0x3F800000u) - 1.0f;
}

__device__ static inline float leaky(float x) { return x >= 0.f ? x : 0.5f * x; }

__device__ static inline u16 f2bf(float f) {  // RNE fp32->bf16
  uint32_t x = __float_as_uint(f);
  return (u16)((x + 0x7FFFu + ((x >> 16) & 1u)) >> 16);
}
__device__ static inline float bf2f(u16 u) {
  return __uint_as_float((uint32_t)u << 16);
}

// ---------------- constant maps for the 16 info_nce calls ----------------
// normbuf slots: 0:Zu1 1:Zu2 2:Zi1 3:Zi2 4:Zdu1 5:Zdu2 6:Zdi1 7:Zdi2 8:Gu1 9:Gu2 10:Gi1 11:Gi2
__constant__ int c_gsel[16] = {0,1,2,3, 0,2, 4,5,6,7, 4,6, 0,1,2,3};
__constant__ int c_hsrc[16] = {8,9,10,11, 1,3, 8,9,10,11, 5,7, 4,5,6,7};
// W order: 0:ng0 1:ng1 2:nn 3:dg0 4:dg1 5:dd 6:nd0 7:nd1
__constant__ int c_wsel[16] = {0,1,0,1, 2,2, 3,4,3,4, 5,5, 6,7,6,7};
// slots: 0:n 1:d 2:nn 3:dd 4:nd (5: loss_r sum)
__constant__ int c_slot[16] = {0,0,0,0, 2,2, 1,1,1,1, 3,3, 4,4,4,4};

struct WPtrs { const float* W[8]; };
struct NceKeys { uint32_t k0[16]; uint32_t k1[16]; };
struct DropKeys { uint32_t a[8]; };  // [dir0 l0 pair, dir0 l1 pair, dir1 l0 pair, dir1 l1 pair]

// ---------------- two-level counting sort ----------------

__global__ __launch_bounds__(256) void passA_hist(
    const int* __restrict__ rows, const int* __restrict__ cols,
    uint32_t* __restrict__ cntA) {
  __shared__ uint32_t h[NCB];
  const int dir = blockIdx.y, c = blockIdx.x, t = threadIdx.x;
  for (int i = t; i < NCB; i += 256) h[i] = 0u;
  __syncthreads();
  const int e0 = c * CHUNK, e1 = min(e0 + CHUNK, C_NE);
  const int* ids = dir ? cols : rows;
  for (int e = e0 + t; e < e1; e += 256) atomicAdd(&h[ids[e] >> 9], 1u);
  __syncthreads();
  for (int i = t; i < NCB; i += 256) cntA[(dir * NCB + i) * NCHK + c] = h[i];
}

__global__ __launch_bounds__(512) void scanA1(
    const uint32_t* __restrict__ cntA, uint32_t* __restrict__ offs,
    uint32_t* __restrict__ bsum) {
  __shared__ uint32_t s[512];
  const int b = blockIdx.x, t = threadIdx.x;
  const int idx = b * 512 + t;
  uint32_t v = cntA[idx];
  s[t] = v;
  __syncthreads();
  for (int off = 1; off < 512; off <<= 1) {
    uint32_t a = (t >= off) ? s[t - off] : 0u;
    __syncthreads();
    s[t] += a;
    __syncthreads();
  }
  offs[idx] = s[t] - v;
  if (t == 511) bsum[b] = s[511];
}

__global__ __launch_bounds__(256) void scanA2(
    const uint32_t* __restrict__ bsum, uint32_t* __restrict__ boff) {
  __shared__ uint32_t s[256];
  const int t = threadIdx.x;
  uint32_t v = (t < NCB) ? bsum[t] : 0u;
  s[t] = v;
  __syncthreads();
  for (int off = 1; off < 256; off <<= 1) {
    uint32_t a = (t >= off) ? s[t - off] : 0u;
    __syncthreads();
    s[t] += a;
    __syncthreads();
  }
  if (t < NCB) boff[t] = s[t] - v;
}

__global__ __launch_bounds__(512) void scanA3(
    uint32_t* __restrict__ offs, const uint32_t* __restrict__ boff) {
  offs[blockIdx.x * 512 + threadIdx.x] += boff[blockIdx.x];
}

// record.x = src(17b) | keepL0<<17 | keepL1<<18 | (dst&511)<<19
__global__ __launch_bounds__(256) void passA_scatter(
    const int* __restrict__ rows, const int* __restrict__ cols,
    const float* __restrict__ vals, const uint32_t* __restrict__ offs,
    uint2* __restrict__ edgesA, DropKeys dk) {
  __shared__ uint32_t lofs[NCB];
  const int dir = blockIdx.y, c = blockIdx.x, t = threadIdx.x;
  for (int i = t; i < NCB; i += 256) lofs[i] = offs[(dir * NCB + i) * NCHK + c];
  __syncthreads();
  const int e0 = c * CHUNK, e1 = min(e0 + CHUNK, C_NE);
  const uint32_t kA0 = dk.a[dir * 4 + 0], kA1 = dk.a[dir * 4 + 1];
  const uint32_t kB0 = dk.a[dir * 4 + 2], kB1 = dk.a[dir * 4 + 3];
  for (int e = e0 + t; e < e1; e += 256) {
    const int r = rows[e], cc = cols[e];
    const int dst = dir ? cc : r, src = dir ? r : cc;
    const uint32_t kl0 = (tf_uniform(kA0, kA1, (uint32_t)e) < 0.9f) ? 1u : 0u;
    const uint32_t kl1 = (tf_uniform(kB0, kB1, (uint32_t)e) < 0.9f) ? 1u : 0u;
    const uint32_t x = (uint32_t)src | (kl0 << 17) | (kl1 << 18) |
                       ((uint32_t)(dst & 511) << 19);
    const uint32_t pos = atomicAdd(&lofs[dst >> 9], 1u);
    edgesA[pos] = make_uint2(x, __float_as_uint(vals[e]));
  }
}

__global__ __launch_bounds__(512) void passB_kernel(
    const uint2* __restrict__ edgesA, const uint32_t* __restrict__ offs,
    uint2* __restrict__ edgesB, uint32_t* __restrict__ starts) {
  __shared__ uint32_t cnt[512];
  __shared__ uint32_t scn[512];
  const int dir = blockIdx.y, cb = blockIdx.x, t = threadIdx.x;
  const uint32_t segStart = offs[(dir * NCB + cb) * NCHK];
  const uint32_t segEnd = (dir == 1 && cb == NCB - 1)
                              ? (uint32_t)(2 * C_NE)
                              : offs[(dir * NCB + cb + 1) * NCHK];
  cnt[t] = 0u;
  __syncthreads();
  for (uint32_t e = segStart + t; e < segEnd; e += 512)
    atomicAdd(&cnt[(edgesA[e].x >> 19) & 511u], 1u);
  __syncthreads();
  uint32_t v = cnt[t];
  scn[t] = v;
  __syncthreads();
  for (int off = 1; off < 512; off <<= 1) {
    uint32_t a = (t >= off) ? scn[t - off] : 0u;
    __syncthreads();
    scn[t] += a;
    __syncthreads();
  }
  const uint32_t rstart = segStart + scn[t] - v;
  const int grow = cb * 512 + t;
  if (grow < NROW) starts[dir * (NROW + 1) + grow] = rstart;
  if (cb == NCB - 1 && t == 0) starts[dir * (NROW + 1) + NROW] = segEnd;
  cnt[t] = rstart;
  __syncthreads();
  for (uint32_t e = segStart + t; e < segEnd; e += 512) {
    const uint2 q = edgesA[e];
    const uint32_t pos = atomicAdd(&cnt[(q.x >> 19) & 511u], 1u);
    edgesB[pos] = q;
  }
}

// ---------------- fp32 -> bf16 convert (float4 -> ushort4) ----------------
__global__ __launch_bounds__(256) void bf16_convert(
    const float* __restrict__ src, u16* __restrict__ dst, int n4) {
  int i = blockIdx.x * 256 + threadIdx.x;
  if (i >= n4) return;
  float4 v = ((const float4*)src)[i];
  ushort4 o;
  o.x = f2bf(v.x); o.y = f2bf(v.y); o.z = f2bf(v.z); o.w = f2bf(v.w);
  ((ushort4*)dst)[i] = o;
}

// Wt16[w][d][k] = bf16(W[w][k][d])  (pre-transposed for MFMA B-operand)
__global__ __launch_bounds__(256) void w16_prep(WPtrs wp, u16* __restrict__ Wt16) {
  int i = blockIdx.x * 256 + threadIdx.x;
  if (i >= 8 * 4096) return;
  int w = i >> 12, kd = i & 4095, k = kd >> 6, d = kd & 63;
  Wt16[w * 4096 + d * 64 + k] = f2bf(wp.W[w][k * 64 + d]);
}

// ---------------- fused spmm (one wave per dst row, scalarized) ----------------
__global__ __launch_bounds__(256) void spmm_row(
    const uint2* __restrict__ edges, const uint32_t* __restrict__ starts,
    const u16* __restrict__ Einb, const float* __restrict__ Eprev,
    float* __restrict__ Enext, u16* __restrict__ Enb16,
    float* __restrict__ Zout, float* __restrict__ Zdout,
    uint32_t nk0, uint32_t nk1, int layer) {
  const int row = rfl(blockIdx.x * 4 + (threadIdx.x >> 6));
  const int lane = threadIdx.x & 63;
  if (row >= NROW) return;
  const uint32_t s0 = rflu(starts[row]);
  const uint32_t s1 = rflu(starts[row + 1]);
  const uint32_t kbit = 1u << (17 + layer);
  float z = 0.f, zd = 0.f;
  uint32_t e = s0;
  for (; e + 4 <= s1; e += 4) {
    const uint32_t p0 = rflu(edges[e].x),     w0 = rflu(edges[e].y);
    const uint32_t p1 = rflu(edges[e + 1].x), w1 = rflu(edges[e + 1].y);
    const uint32_t p2 = rflu(edges[e + 2].x), w2 = rflu(edges[e + 2].y);
    const uint32_t p3 = rflu(edges[e + 3].x), w3 = rflu(edges[e + 3].y);
    const float x0 = bf2f(Einb[(size_t)(p0 & 0x1FFFFu) * 64 + lane]);
    const float x1 = bf2f(Einb[(size_t)(p1 & 0x1FFFFu) * 64 + lane]);
    const float x2 = bf2f(Einb[(size_t)(p2 & 0x1FFFFu) * 64 + lane]);
    const float x3 = bf2f(Einb[(size_t)(p3 & 0x1FFFFu) * 64 + lane]);
    const float v0 = __uint_as_float(w0), v1 = __uint_as_float(w1);
    const float v2 = __uint_as_float(w2), v3 = __uint_as_float(w3);
    const float d0 = (p0 & kbit) ? v0 : 0.f;  // scalar select
    const float d1 = (p1 & kbit) ? v1 : 0.f;
    const float d2 = (p2 & kbit) ? v2 : 0.f;
    const float d3 = (p3 & kbit) ? v3 : 0.f;
    z += v0 * x0; zd += d0 * x0;
    z += v1 * x1; zd += d1 * x1;
    z += v2 * x2; zd += d2 * x2;
    z += v3 * x3; zd += d3 * x3;
  }
  for (; e < s1; ++e) {
    const uint32_t p = rflu(edges[e].x), wv = rflu(edges[e].y);
    const float x = bf2f(Einb[(size_t)(p & 0x1FFFFu) * 64 + lane]);
    const float v = __uint_as_float(wv);
    z += v * x;
    zd += ((p & kbit) ? v : 0.f) * x;
  }
  z = leaky(z);
  zd = leaky(zd * (1.0f / 0.9f));
  // noise-augmented view
  const float u = tf_uniform(nk0, nk1, (uint32_t)row * 64u + (uint32_t)lane);
  float ss = u * u;
#pragma unroll
  for (int off = 1; off < 64; off <<= 1) ss += __shfl_xor(ss, off);
  const float nrm = fmaxf(sqrtf(ss), 1e-12f);
  const float sg = (z > 0.f) ? 1.f : (z < 0.f ? -1.f : 0.f);
  z += sg * (u / nrm) * 0.1f;
  const size_t j = (size_t)row * 64 + lane;
  Zout[j] = z;
  Zdout[j] = zd;
  if (Enext) {  // layer 0 only: materialize E1 (fp32 + bf16 for next-layer gathers)
    const float en = z + zd + Eprev[j];
    Enext[j] = en;
    Enb16[j] = f2bf(en);
  }
}

// M[q][d] = sum_n T[q][n] * E[n][d]
__global__ __launch_bounds__(256) void svd_reduce(
    const float* __restrict__ T, const float* __restrict__ E,
    float* __restrict__ M, int n) {
  int wid = rfl((int)(((long long)blockIdx.x * blockDim.x + threadIdx.x) >> 6));
  int lane = threadIdx.x & 63;
  int nw = (gridDim.x * blockDim.x) >> 6;
  float acc[5] = {0.f, 0.f, 0.f, 0.f, 0.f};
  for (int i = wid; i < n; i += nw) {
    float x = E[(size_t)i * 64 + lane];
#pragma unroll
    for (int q = 0; q < 5; ++q) acc[q] += T[(size_t)q * n + i] * x;
  }
#pragma unroll
  for (int q = 0; q < 5; ++q) atomicAdd(&M[q * 64 + lane], acc[q]);
}

// gather batch rows & L2-normalize -> bf16; blockIdx.y selects {Z, Zd, G}
__global__ __launch_bounds__(256) void gather_norm(
    const int* __restrict__ ids, const float* __restrict__ Z,
    const float* __restrict__ Zd, const float* __restrict__ mul_s,
    const float* __restrict__ M, u16* __restrict__ oZ,
    u16* __restrict__ oZd, u16* __restrict__ oG) {
  long long t = (long long)blockIdx.x * blockDim.x + threadIdx.x;
  int b = (int)(t >> 6);
  int d = (int)(t & 63);
  if (b >= C_B) return;
  int id = rfl(ids[b]);
  float v;
  u16* out;
  if (blockIdx.y == 0) { v = Z[(size_t)id * 64 + d]; out = oZ; }
  else if (blockIdx.y == 1) { v = Zd[(size_t)id * 64 + d]; out = oZd; }
  else {
    float s = 0.f;
#pragma unroll
    for (int q = 0; q < 5; ++q) s += mul_s[(size_t)id * 5 + q] * M[q * 64 + d];
    v = leaky(s);
    out = oG;
  }
  float ss = v * v;
#pragma unroll
  for (int off = 1; off < 64; off <<= 1) ss += __shfl_xor(ss, off);
  float nrm = fmaxf(sqrtf(ss), 1e-12f);
  out[(size_t)b * 64 + d] = f2bf(v / nrm);
}

// ---------------- MFMA hyper: hy[call] = normbuf[hsrc] @ W[wsel] ----------------
__global__ __launch_bounds__(256) void hyper_mfma(
    const u16* __restrict__ nb, const u16* __restrict__ Wt16,
    u16* __restrict__ hy) {
  const int call = blockIdx.y;
  const int b0 = blockIdx.x * 64;
  __shared__ u16 Xs[64 * 64];
  __shared__ u16 Ws[64 * 64];
  const int tid = threadIdx.x, lane = tid & 63, wid = tid >> 6;
  const u16* X = nb + (size_t)c_hsrc[call] * C_B * 64;
  const u16* Wt = Wt16 + (size_t)c_wsel[call] * 4096;
  {
    const int r = tid >> 2, seg = tid & 3;
    const int base = r * 128 + seg * 32, sw = (r & 7) << 4;
    const uint4* sx = (const uint4*)&X[(size_t)(b0 + r) * 64 + seg * 16];
    uint4 a = sx[0], b = sx[1];
    *(uint4*)((char*)Xs + (base ^ sw)) = a;
    *(uint4*)((char*)Xs + ((base + 16) ^ sw)) = b;
    const uint4* sv = (const uint4*)&Wt[r * 64 + seg * 16];
    uint4 c = sv[0], d = sv[1];
    *(uint4*)((char*)Ws + (base ^ sw)) = c;
    *(uint4*)((char*)Ws + ((base + 16) ^ sw)) = d;
  }
  __syncthreads();
  const int am = (wid << 4) + (lane & 15);  // A (X) row within tile
  short8 af[2];
#pragma unroll
  for (int ks = 0; ks < 2; ++ks) {
    const int off = (am * 128 + ks * 64 + ((lane >> 4) << 4)) ^ ((am & 7) << 4);
    af[ks] = *(const short8*)((const char*)Xs + off);
  }
  const int ob = b0 + (wid << 4) + ((lane >> 4) << 2);
#pragma unroll
  for (int n = 0; n < 4; ++n) {
    const int bn = (n << 4) + (lane & 15);  // B (Wt) row = output col d
    f32x4 acc = {0.f, 0.f, 0.f, 0.f};
#pragma unroll
    for (int ks = 0; ks < 2; ++ks) {
      const int off = (bn * 128 + ks * 64 + ((lane >> 4) << 4)) ^ ((bn & 7) << 4);
      short8 bf = *(const short8*)((const char*)Ws + off);
      acc = __builtin_amdgcn_mfma_f32_16x16x32_bf16(af[ks], bf, acc, 0, 0, 0);
    }
    const int d = (n << 4) + (lane & 15);
#pragma unroll
    for (int j = 0; j < 4; ++j)
      hy[(size_t)call * C_B * 64 + (size_t)(ob + j) * 64 + d] = f2bf(acc[j]);
  }
}

// ---------------- MFMA info_nce (double-buffered H staging) ----------------
__global__ __launch_bounds__(256) void nce_mfma(
    const u16* __restrict__ nb, const u16* __restrict__ hy,
    float* __restrict__ slots, NceKeys nk) {
  const int call = blockIdx.y;
  const u16* G = nb + (size_t)c_gsel[call] * C_B * 64;
  const u16* H = hy + (size_t)call * C_B * 64;
  const int br = blockIdx.x * 64;
  __shared__ u16 Gs[64 * 64];
  __shared__ u16 Hs[2][64 * 64];
  const int tid = threadIdx.x, lane = tid & 63, wid = tid >> 6;
  const int r = tid >> 2, seg = tid & 3;
  const int base = r * 128 + seg * 32, sw = (r & 7) << 4;
  {
    const uint4* src = (const uint4*)&G[(size_t)(br + r) * 64 + seg * 16];
    uint4 a = src[0], b = src[1];
    *(uint4*)((char*)Gs + (base ^ sw)) = a;
    *(uint4*)((char*)Gs + ((base + 16) ^ sw)) = b;
  }
  {
    const uint4* src = (const uint4*)&H[(size_t)r * 64 + seg * 16];
    uint4 a = src[0], b = src[1];
    *(uint4*)((char*)Hs[0] + (base ^ sw)) = a;
    *(uint4*)((char*)Hs[0] + ((base + 16) ^ sw)) = b;
  }
  const int gcol = (wid << 4) + (lane & 15);
  const int g_glob = br + gcol;
  float rs = 0.f, ps = 0.f;
  short8 bfG[2];
  int cur = 0;
  for (int jt = 0; jt < 64; ++jt) {
    __syncthreads();  // Hs[cur] (and Gs on first iter) ready
    if (jt == 0) {
#pragma unroll
      for (int ks = 0; ks < 2; ++ks) {
        const int off = (gcol * 128 + ks * 64 + ((lane >> 4) << 4)) ^ ((gcol & 7) << 4);
        bfG[ks] = *(const short8*)((const char*)Gs + off);
      }
    }
    uint4 na, nb_;
    if (jt + 1 < 64) {  // prefetch next H tile (latency hidden under compute)
      const uint4* src = (const uint4*)&H[(size_t)((jt + 1) * 64 + r) * 64 + seg * 16];
      na = src[0]; nb_ = src[1];
    }
    const char* Hb = (const char*)(Hs[cur]);
#pragma unroll
    for (int hs = 0; hs < 4; ++hs) {
      const int hr = (hs << 4) + (lane & 15);
      f32x4 acc = {0.f, 0.f, 0.f, 0.f};
#pragma unroll
      for (int ks = 0; ks < 2; ++ks) {
        const int off = (hr * 128 + ks * 64 + ((lane >> 4) << 4)) ^ ((hr & 7) << 4);
        short8 af = *(const short8*)(Hb + off);
        acc = __builtin_amdgcn_mfma_f32_16x16x32_bf16(af, bfG[ks], acc, 0, 0, 0);
      }
      const int hbase = jt * 64 + (hs << 4) + ((lane >> 4) << 2);
#pragma unroll
      for (int j = 0; j < 4; ++j) {
        float e = __expf(acc[j] * 5.0f);  // exp(score/TEMP)
        rs += e;
        if (hbase + j == g_glob) ps = e;
      }
    }
    if (jt + 1 < 64) {
      *(uint4*)((char*)Hs[cur ^ 1] + (base ^ sw)) = na;
      *(uint4*)((char*)Hs[cur ^ 1] + ((base + 16) ^ sw)) = nb_;
    }
    cur ^= 1;
  }
  rs += __shfl_xor(rs, 16); rs += __shfl_xor(rs, 32);
  ps += __shfl_xor(ps, 16); ps += __shfl_xor(ps, 32);
  float c = 0.f;
  if ((lane >> 4) == 0) {
    float v = -__logf(ps / (rs + 1e-8f) + 1e-8f);
    float u = tf_uniform(nk.k0[call], nk.k1[call], (uint32_t)g_glob);
    c = (u > 0.5f) ? v : 0.f;
  }
  c += __shfl_xor(c, 1); c += __shfl_xor(c, 2);
  c += __shfl_xor(c, 4); c += __shfl_xor(c, 8);
  if (lane == 0) atomicAdd(&slots[c_slot[call]], c);
}

// E_sum = E0 + 2*E1 + Z2 + Zd2  (E2 never materialized)
__global__ __launch_bounds__(256) void loss_r_kernel(
    const float* __restrict__ E0u, const float* __restrict__ Eu1,
    const float* __restrict__ Zu, const float* __restrict__ Zdu,
    const float* __restrict__ E0i, const float* __restrict__ Ei1,
    const float* __restrict__ Zi, const float* __restrict__ Zdi,
    const int* __restrict__ uids, const int* __restrict__ pos,
    const int* __restrict__ neg, float* __restrict__ slots) {
  long long t = (long long)blockIdx.x * blockDim.x + threadIdx.x;
  int b = (int)(t >> 6);
  int d = (int)(t & 63);
  if (b >= C_B) return;
  size_t ju = (size_t)rfl(uids[b]) * 64 + d;
  float u = E0u[ju] + 2.f * Eu1[ju] + Zu[ju] + Zdu[ju];
  float bpr = 0.f, pmin = 3.4e38f, nmax = -3.4e38f;
  for (int p = 0; p < C_P; ++p) {
    size_t jp = (size_t)rfl(pos[b * C_P + p]) * 64 + d;
    size_t jn = (size_t)rfl(neg[b * C_P + p]) * 64 + d;
    float pe = E0i[jp] + 2.f * Ei1[jp] + Zi[jp] + Zdi[jp];
    float ne = E0i[jn] + 2.f * Ei1[jn] + Zi[jn] + Zdi[jn];
    float psc = u * pe, nsc = u * ne;
#pragma unroll
    for (int off = 1; off < 64; off <<= 1) {
      psc += __shfl_xor(psc, off);
      nsc += __shfl_xor(nsc, off);
    }
    pmin = fminf(pmin, psc);
    nmax = fmaxf(nmax, nsc);
    bpr += fmaxf(1.f - psc + nsc, 0.f);
  }
  if (d == 0) {
    float hd = (nmax - pmin > 0.005f) ? 10.f * (nmax - pmin) : 0.f;
    atomicAdd(&slots[5], bpr + hd);
  }
}

__global__ void final_kernel(const float* __restrict__ slots, float* __restrict__ out) {
  if (threadIdx.x == 0 && blockIdx.x == 0) {
    float n = slots[0], dl = slots[1], nn = slots[2], dd = slots[3], nd = slots[4];
    float lr = slots[5] / (float)C_B;
    out[0] = lr + 0.2f * (n + dl) + 0.2f * (nn + dd + nd);
    out[1] = lr;
    out[2] = dl;
    out[3] = n;
  }
}

// ---------------- host ----------------
extern "C" void kernel_launch(void* const* d_in, const int* in_sizes, int n_in,
                              void* d_out, int out_size, void* d_ws, size_t ws_size,
                              hipStream_t stream) {
  (void)in_sizes; (void)n_in; (void)out_size;
  const float* E_u_0   = (const float*)d_in[0];
  const float* E_i_0   = (const float*)d_in[1];
  const float* adjvals = (const float*)d_in[2];
  const float* u_mul_s = (const float*)d_in[3];
  const float* v_mul_s = (const float*)d_in[4];
  const float* ut      = (const float*)d_in[5];
  const float* vt      = (const float*)d_in[6];
  const float* W_nn    = (const float*)d_in[7];
  const float* W_dd    = (const float*)d_in[8];
  const float* W_ng    = (const float*)d_in[9];
  const float* W_dg    = (const float*)d_in[10];
  const float* W_nd    = (const float*)d_in[11];
  const int* adj_rows  = (const int*)d_in[12];
  const int* adj_cols  = (const int*)d_in[13];
  const int* uids      = (const int*)d_in[14];
  const int* iids      = (const int*)d_in[15];
  const int* pos       = (const int*)d_in[16];
  const int* neg       = (const int*)d_in[17];
  float* out = (float*)d_out;

  const size_t NU64 = (size_t)C_NU * 64;
  const size_t NI64 = (size_t)C_NI * 64;
  const size_t B64  = (size_t)C_B * 64;

  float* w = (float*)d_ws;
  float* Eu1 = w; w += NU64;
  float* Ei1 = w; w += NI64;
  float* Zu  = w; w += NU64;   // edgesA aliases Zu..Zdu
  float* Zdu = w; w += NU64;
  float* Zi  = w; w += NI64;
  float* Zdi = w; w += NI64;
  float* Mu = w; w += 512;
  float* Mi = w; w += 512;
  u16* normbuf16 = (u16*)w; w += 6 * B64;     // 12 bf16 buffers of B64
  float* slots = w; w += 16;
  uint2* edgesB = (uint2*)w; w += 4 * C_NE;   // 32 MB final CSR (both dirs)
  u16* hyper16 = (u16*)edgesB;                // alias: edgesB dead before hyper
  u16* Wt16 = (u16*)w; w += 16384;            // 8 x 64x64 bf16 (transposed)
  uint32_t* cntA = (uint32_t*)w; w += NCB * NCHK * 2;
  uint32_t* offs = (uint32_t*)w; w += NCB * NCHK * 2;
  uint32_t* bsumA = (uint32_t*)w; w += NCB;
  uint32_t* boffA = (uint32_t*)w; w += NCB;
  uint32_t* startsAbs = (uint32_t*)w; w += 2 * (NROW + 1);
  u16* Eu0b = (u16*)w; w += NU64 / 2;         // bf16 copies for gathers
  u16* Ei0b = (u16*)w; w += NI64 / 2;         // (Ei1b aliases Ei0b)
  u16* Eu1b = (u16*)w; w += NU64 / 2;
  u16* Ei1b = Ei0b;                           // Ei0b dead once dir1-l0 runs
  uint2* edgesA = (uint2*)Zu;                 // 32 MB coarse buffer, dead before spmm
  if ((size_t)((char*)w - (char*)d_ws) > ws_size) return;

  // ---- host-side JAX key derivation (partitionable threefry) ----
  auto ksplit = [](uint32_t a, uint32_t b, uint32_t idx, uint32_t& o0, uint32_t& o1) {
    uint32_t x0 = 0u, x1 = idx;
    tf2x32(a, b, x0, x1);
    o0 = x0; o1 = x1;
  };
  uint32_t rk0 = 0u, rk1 = 42u;
  uint32_t lk[2][4][2];
  for (int l = 0; l < 2; ++l) {
    uint32_t n0, n1;
    ksplit(rk0, rk1, 0u, n0, n1);
    for (int i = 0; i < 4; ++i) ksplit(rk0, rk1, (uint32_t)(i + 1), lk[l][i][0], lk[l][i][1]);
    rk0 = n0; rk1 = n1;
  }
  NceKeys nk;
  {
    uint32_t mk0 = 0u, mk1 = 7u;
    for (int i = 0; i < 16; ++i) {
      uint32_t n0, n1;
      ksplit(mk0, mk1, 0u, n0, n1);
      ksplit(mk0, mk1, 1u, nk.k0[i], nk.k1[i]);
      mk0 = n0; mk1 = n1;
    }
  }
  DropKeys dk;
  dk.a[0] = lk[0][0][0]; dk.a[1] = lk[0][0][1];
  dk.a[2] = lk[1][0][0]; dk.a[3] = lk[1][0][1];
  dk.a[4] = lk[0][1][0]; dk.a[5] = lk[0][1][1];
  dk.a[6] = lk[1][1][0]; dk.a[7] = lk[1][1][1];
  WPtrs wp;
  wp.W[0] = W_ng; wp.W[1] = W_ng + 4096;
  wp.W[2] = W_nn;
  wp.W[3] = W_dg; wp.W[4] = W_dg + 4096;
  wp.W[5] = W_dd;
  wp.W[6] = W_nd; wp.W[7] = W_nd + 4096;

  // ---- sort + preps ----
  hipMemsetAsync(slots, 0, 16 * 4, stream);
  passA_hist<<<dim3(NCHK, 2), 256, 0, stream>>>(adj_rows, adj_cols, cntA);
  scanA1<<<NCB, 512, 0, stream>>>(cntA, offs, bsumA);
  scanA2<<<1, 256, 0, stream>>>(bsumA, boffA);
  scanA3<<<NCB, 512, 0, stream>>>(offs, boffA);
  passA_scatter<<<dim3(NCHK, 2), 256, 0, stream>>>(
      adj_rows, adj_cols, adjvals, offs, edgesA, dk);
  passB_kernel<<<dim3(NCB, 2), 512, 0, stream>>>(edgesA, offs, edgesB, startsAbs);
  bf16_convert<<<(int)(NU64 / 4 + 255) / 256, 256, 0, stream>>>(E_u_0, Eu0b, (int)(NU64 / 4));
  bf16_convert<<<(int)(NI64 / 4 + 255) / 256, 256, 0, stream>>>(E_i_0, Ei0b, (int)(NI64 / 4));
  w16_prep<<<(8 * 4096 + 255) / 256, 256, 0, stream>>>(wp, Wt16);

  const int gb = (int)(B64 / 256);  // 1024
  const int sb = (NROW + 3) / 4;    // 25000 blocks, 4 waves each

  for (int l = 0; l < 2; ++l) {
    hipMemsetAsync(Mu, 0, 1024 * 4, stream);
    svd_reduce<<<1024, 256, 0, stream>>>(vt, (l == 0) ? E_i_0 : Ei1, Mu, C_NI);
    svd_reduce<<<1024, 256, 0, stream>>>(ut, (l == 0) ? E_u_0 : Eu1, Mi, C_NU);
    // dir0: items -> users (noise key k3)
    spmm_row<<<sb, 256, 0, stream>>>(
        edgesB, startsAbs, (l == 0) ? Ei0b : Ei1b,
        (l == 0) ? E_u_0 : nullptr, (l == 0) ? Eu1 : nullptr,
        (l == 0) ? Eu1b : nullptr, Zu, Zdu, lk[l][2][0], lk[l][2][1], l);
    // dir1: users -> items (noise key k4)
    spmm_row<<<sb, 256, 0, stream>>>(
        edgesB, startsAbs + (NROW + 1), (l == 0) ? Eu0b : Eu1b,
        (l == 0) ? E_i_0 : nullptr, (l == 0) ? Ei1 : nullptr,
        (l == 0) ? Ei1b : nullptr, Zi, Zdi, lk[l][3][0], lk[l][3][1], l);
    gather_norm<<<dim3(gb, 3), 256, 0, stream>>>(
        uids, Zu, Zdu, u_mul_s, Mu,
        normbuf16 + (size_t)(0 + l) * B64, normbuf16 + (size_t)(4 + l) * B64,
        normbuf16 + (size_t)(8 + l) * B64);
    gather_norm<<<dim3(gb, 3), 256, 0, stream>>>(
        iids, Zi, Zdi, v_mul_s, Mi,
        normbuf16 + (size_t)(2 + l) * B64, normbuf16 + (size_t)(6 + l) * B64,
        normbuf16 + (size_t)(10 + l) * B64);
  }

  hyper_mfma<<<dim3(C_B / 64, 16), 256, 0, stream>>>(normbuf16, Wt16, hyper16);
  nce_mfma<<<dim3(C_B / 64, 16), 256, 0, stream>>>(normbuf16, hyper16, slots, nk);
  loss_r_kernel<<<gb, 256, 0, stream>>>(E_u_0, Eu1, Zu, Zdu, E_i_0, Ei1, Zi, Zdi,
                                        uids, pos, neg, slots);
  final_kernel<<<1, 1, 0, stream>>>(slots, out);
}

// Round 8
// 731.987 us; speedup vs baseline: 11.6126x; 1.4744x over previous
//
#include <hip/hip_runtime.h>
#include <hip/hip_bf16.h>
#include <cstdint>

#define C_NU 100000
#define C_NI 100000
#define C_DIM 64
#define C_Q 5
#define C_NE 2000000
#define C_B 4096
#define C_P 10
#define NROW 100000
#define NCB 196      // coarse buckets of 512 rows
#define NCHK 256     // chunks in pass A
#define CHUNK 7813   // ceil(2M/256)

typedef unsigned short u16;
typedef __attribute__((ext_vector_type(8))) short short8;
typedef __attribute__((ext_vector_type(4))) float f32x4;

__device__ static inline int rfl(int v) { return __builtin_amdgcn_readfirstlane(v); }
__device__ static inline uint32_t rflu(uint32_t v) {
  return (uint32_t)__builtin_amdgcn_readfirstlane((int)v);
}

// ---------------- Threefry-2x32 (JAX-compatible), 20 rounds ----------------
__host__ __device__ static inline void tf2x32(uint32_t k0, uint32_t k1,
                                              uint32_t& x0, uint32_t& x1) {
  uint32_t k2 = k0 ^ k1 ^ 0x1BD11BDAu;
#define TFR(r) { x0 += x1; x1 = (x1 << r) | (x1 >> (32 - r)); x1 ^= x0; }
  x0 += k0; x1 += k1;
  TFR(13) TFR(15) TFR(26) TFR(6)
  x0 += k1; x1 += k2 + 1u;
  TFR(17) TFR(29) TFR(16) TFR(24)
  x0 += k2; x1 += k0 + 2u;
  TFR(13) TFR(15) TFR(26) TFR(6)
  x0 += k0; x1 += k1 + 3u;
  TFR(17) TFR(29) TFR(16) TFR(24)
  x0 += k1; x1 += k2 + 4u;
  TFR(13) TFR(15) TFR(26) TFR(6)
  x0 += k2; x1 += k0 + 5u;
#undef TFR
}

// partitionable-mode random bits at flat index idx (hi counter = 0)
__device__ static inline float tf_uniform(uint32_t k0, uint32_t k1, uint32_t idx) {
  uint32_t x0 = 0u, x1 = idx;
  tf2x32(k0, k1, x0, x1);
  uint32_t bits = x0 ^ x1;
  return __uint_as_float((bits >> 9) | 0x3F800000u) - 1.0f;
}

__device__ static inline float leaky(float x) { return x >= 0.f ? x : 0.5f * x; }

__device__ static inline u16 f2bf(float f) {  // RNE fp32->bf16
  uint32_t x = __float_as_uint(f);
  return (u16)((x + 0x7FFFu + ((x >> 16) & 1u)) >> 16);
}
__device__ static inline float bf2f(u16 u) {
  return __uint_as_float((uint32_t)u << 16);
}

// ---------------- constant maps for the 16 info_nce calls ----------------
// normbuf slots: 0:Zu1 1:Zu2 2:Zi1 3:Zi2 4:Zdu1 5:Zdu2 6:Zdi1 7:Zdi2 8:Gu1 9:Gu2 10:Gi1 11:Gi2
__constant__ int c_gsel[16] = {0,1,2,3, 0,2, 4,5,6,7, 4,6, 0,1,2,3};
__constant__ int c_hsrc[16] = {8,9,10,11, 1,3, 8,9,10,11, 5,7, 4,5,6,7};
// W order: 0:ng0 1:ng1 2:nn 3:dg0 4:dg1 5:dd 6:nd0 7:nd1
__constant__ int c_wsel[16] = {0,1,0,1, 2,2, 3,4,3,4, 5,5, 6,7,6,7};
// slots: 0:n 1:d 2:nn 3:dd 4:nd (5: loss_r sum)
__constant__ int c_slot[16] = {0,0,0,0, 2,2, 1,1,1,1, 3,3, 4,4,4,4};

struct WPtrs { const float* W[8]; };
struct NceKeys { uint32_t k0[16]; uint32_t k1[16]; };
struct DropKeys { uint32_t a[8]; };  // [dir0 l0 pair, dir0 l1 pair, dir1 l0 pair, dir1 l1 pair]

// ---------------- two-level counting sort ----------------

__global__ __launch_bounds__(256) void passA_hist(
    const int* __restrict__ rows, const int* __restrict__ cols,
    uint32_t* __restrict__ cntA) {
  __shared__ uint32_t h[NCB];
  const int dir = blockIdx.y, c = blockIdx.x, t = threadIdx.x;
  for (int i = t; i < NCB; i += 256) h[i] = 0u;
  __syncthreads();
  const int e0 = c * CHUNK, e1 = min(e0 + CHUNK, C_NE);
  const int* ids = dir ? cols : rows;
  for (int e = e0 + t; e < e1; e += 256) atomicAdd(&h[ids[e] >> 9], 1u);
  __syncthreads();
  for (int i = t; i < NCB; i += 256) cntA[(dir * NCB + i) * NCHK + c] = h[i];
}

__global__ __launch_bounds__(512) void scanA1(
    const uint32_t* __restrict__ cntA, uint32_t* __restrict__ offs,
    uint32_t* __restrict__ bsum) {
  __shared__ uint32_t s[512];
  const int b = blockIdx.x, t = threadIdx.x;
  const int idx = b * 512 + t;
  uint32_t v = cntA[idx];
  s[t] = v;
  __syncthreads();
  for (int off = 1; off < 512; off <<= 1) {
    uint32_t a = (t >= off) ? s[t - off] : 0u;
    __syncthreads();
    s[t] += a;
    __syncthreads();
  }
  offs[idx] = s[t] - v;
  if (t == 511) bsum[b] = s[511];
}

__global__ __launch_bounds__(256) void scanA2(
    const uint32_t* __restrict__ bsum, uint32_t* __restrict__ boff) {
  __shared__ uint32_t s[256];
  const int t = threadIdx.x;
  uint32_t v = (t < NCB) ? bsum[t] : 0u;
  s[t] = v;
  __syncthreads();
  for (int off = 1; off < 256; off <<= 1) {
    uint32_t a = (t >= off) ? s[t - off] : 0u;
    __syncthreads();
    s[t] += a;
    __syncthreads();
  }
  if (t < NCB) boff[t] = s[t] - v;
}

__global__ __launch_bounds__(512) void scanA3(
    uint32_t* __restrict__ offs, const uint32_t* __restrict__ boff) {
  offs[blockIdx.x * 512 + threadIdx.x] += boff[blockIdx.x];
}

// record.x = src(17b) | keepL0<<17 | keepL1<<18 | (dst&511)<<19
__global__ __launch_bounds__(256) void passA_scatter(
    const int* __restrict__ rows, const int* __restrict__ cols,
    const float* __restrict__ vals, const uint32_t* __restrict__ offs,
    uint2* __restrict__ edgesA, DropKeys dk) {
  __shared__ uint32_t lofs[NCB];
  const int dir = blockIdx.y, c = blockIdx.x, t = threadIdx.x;
  for (int i = t; i < NCB; i += 256) lofs[i] = offs[(dir * NCB + i) * NCHK + c];
  __syncthreads();
  const int e0 = c * CHUNK, e1 = min(e0 + CHUNK, C_NE);
  const uint32_t kA0 = dk.a[dir * 4 + 0], kA1 = dk.a[dir * 4 + 1];
  const uint32_t kB0 = dk.a[dir * 4 + 2], kB1 = dk.a[dir * 4 + 3];
  for (int e = e0 + t; e < e1; e += 256) {
    const int r = rows[e], cc = cols[e];
    const int dst = dir ? cc : r, src = dir ? r : cc;
    const uint32_t kl0 = (tf_uniform(kA0, kA1, (uint32_t)e) < 0.9f) ? 1u : 0u;
    const uint32_t kl1 = (tf_uniform(kB0, kB1, (uint32_t)e) < 0.9f) ? 1u : 0u;
    const uint32_t x = (uint32_t)src | (kl0 << 17) | (kl1 << 18) |
                       ((uint32_t)(dst & 511) << 19);
    const uint32_t pos = atomicAdd(&lofs[dst >> 9], 1u);
    edgesA[pos] = make_uint2(x, __float_as_uint(vals[e]));
  }
}

__global__ __launch_bounds__(512) void passB_kernel(
    const uint2* __restrict__ edgesA, const uint32_t* __restrict__ offs,
    uint2* __restrict__ edgesB, uint32_t* __restrict__ starts) {
  __shared__ uint32_t cnt[512];
  __shared__ uint32_t scn[512];
  const int dir = blockIdx.y, cb = blockIdx.x, t = threadIdx.x;
  const uint32_t segStart = offs[(dir * NCB + cb) * NCHK];
  const uint32_t segEnd = (dir == 1 && cb == NCB - 1)
                              ? (uint32_t)(2 * C_NE)
                              : offs[(dir * NCB + cb + 1) * NCHK];
  cnt[t] = 0u;
  __syncthreads();
  for (uint32_t e = segStart + t; e < segEnd; e += 512)
    atomicAdd(&cnt[(edgesA[e].x >> 19) & 511u], 1u);
  __syncthreads();
  uint32_t v = cnt[t];
  scn[t] = v;
  __syncthreads();
  for (int off = 1; off < 512; off <<= 1) {
    uint32_t a = (t >= off) ? scn[t - off] : 0u;
    __syncthreads();
    scn[t] += a;
    __syncthreads();
  }
  const uint32_t rstart = segStart + scn[t] - v;
  const int grow = cb * 512 + t;
  if (grow < NROW) starts[dir * (NROW + 1) + grow] = rstart;
  if (cb == NCB - 1 && t == 0) starts[dir * (NROW + 1) + NROW] = segEnd;
  cnt[t] = rstart;
  __syncthreads();
  for (uint32_t e = segStart + t; e < segEnd; e += 512) {
    const uint2 q = edgesA[e];
    const uint32_t pos = atomicAdd(&cnt[(q.x >> 19) & 511u], 1u);
    edgesB[pos] = q;
  }
}

// ---------------- fp32 -> bf16 convert (float4 -> ushort4) ----------------
__global__ __launch_bounds__(256) void bf16_convert(
    const float* __restrict__ src, u16* __restrict__ dst, int n4) {
  int i = blockIdx.x * 256 + threadIdx.x;
  if (i >= n4) return;
  float4 v = ((const float4*)src)[i];
  ushort4 o;
  o.x = f2bf(v.x); o.y = f2bf(v.y); o.z = f2bf(v.z); o.w = f2bf(v.w);
  ((ushort4*)dst)[i] = o;
}

// Wt16[w][d][k] = bf16(W[w][k][d])  (pre-transposed for MFMA B-operand)
__global__ __launch_bounds__(256) void w16_prep(WPtrs wp, u16* __restrict__ Wt16) {
  int i = blockIdx.x * 256 + threadIdx.x;
  if (i >= 8 * 4096) return;
  int w = i >> 12, kd = i & 4095, k = kd >> 6, d = kd & 63;
  Wt16[w * 4096 + d * 64 + k] = f2bf(wp.W[w][k * 64 + d]);
}

// ---------------- fused spmm (one wave per dst row, scalarized) ----------------
__global__ __launch_bounds__(256) void spmm_row(
    const uint2* __restrict__ edges, const uint32_t* __restrict__ starts,
    const u16* __restrict__ Einb, const float* __restrict__ Eprev,
    float* __restrict__ Enext, u16* __restrict__ Enb16,
    float* __restrict__ Zout, float* __restrict__ Zdout,
    uint32_t nk0, uint32_t nk1, int layer) {
  const int row = rfl(blockIdx.x * 4 + (threadIdx.x >> 6));
  const int lane = threadIdx.x & 63;
  if (row >= NROW) return;
  const uint32_t s0 = rflu(starts[row]);
  const uint32_t s1 = rflu(starts[row + 1]);
  const uint32_t kbit = 1u << (17 + layer);
  float z = 0.f, zd = 0.f;
  uint32_t e = s0;
  for (; e + 4 <= s1; e += 4) {
    const uint32_t p0 = rflu(edges[e].x),     w0 = rflu(edges[e].y);
    const uint32_t p1 = rflu(edges[e + 1].x), w1 = rflu(edges[e + 1].y);
    const uint32_t p2 = rflu(edges[e + 2].x), w2 = rflu(edges[e + 2].y);
    const uint32_t p3 = rflu(edges[e + 3].x), w3 = rflu(edges[e + 3].y);
    const float x0 = bf2f(Einb[(size_t)(p0 & 0x1FFFFu) * 64 + lane]);
    const float x1 = bf2f(Einb[(size_t)(p1 & 0x1FFFFu) * 64 + lane]);
    const float x2 = bf2f(Einb[(size_t)(p2 & 0x1FFFFu) * 64 + lane]);
    const float x3 = bf2f(Einb[(size_t)(p3 & 0x1FFFFu) * 64 + lane]);
    const float v0 = __uint_as_float(w0), v1 = __uint_as_float(w1);
    const float v2 = __uint_as_float(w2), v3 = __uint_as_float(w3);
    const float d0 = (p0 & kbit) ? v0 : 0.f;  // scalar select
    const float d1 = (p1 & kbit) ? v1 : 0.f;
    const float d2 = (p2 & kbit) ? v2 : 0.f;
    const float d3 = (p3 & kbit) ? v3 : 0.f;
    z += v0 * x0; zd += d0 * x0;
    z += v1 * x1; zd += d1 * x1;
    z += v2 * x2; zd += d2 * x2;
    z += v3 * x3; zd += d3 * x3;
  }
  for (; e < s1; ++e) {
    const uint32_t p = rflu(edges[e].x), wv = rflu(edges[e].y);
    const float x = bf2f(Einb[(size_t)(p & 0x1FFFFu) * 64 + lane]);
    const float v = __uint_as_float(wv);
    z += v * x;
    zd += ((p & kbit) ? v : 0.f) * x;
  }
  z = leaky(z);
  zd = leaky(zd * (1.0f / 0.9f));
  // noise-augmented view
  const float u = tf_uniform(nk0, nk1, (uint32_t)row * 64u + (uint32_t)lane);
  float ss = u * u;
#pragma unroll
  for (int off = 1; off < 64; off <<= 1) ss += __shfl_xor(ss, off);
  const float nrm = fmaxf(sqrtf(ss), 1e-12f);
  const float sg = (z > 0.f) ? 1.f : (z < 0.f ? -1.f : 0.f);
  z += sg * (u / nrm) * 0.1f;
  const size_t j = (size_t)row * 64 + lane;
  Zout[j] = z;
  Zdout[j] = zd;
  if (Enext) {  // layer 0 only: materialize E1 (fp32 + bf16 for next-layer gathers)
    const float en = z + zd + Eprev[j];
    Enext[j] = en;
    Enb16[j] = f2bf(en);
  }
}

// ---------------- dual-dir SVD middle matrix, block-reduced atomics ----------------
// M[q][d] = sum_i T[q][i] * E[i][d]; dir0: (vt, Ei)->Mu, dir1: (ut, Eu)->Mi
__global__ __launch_bounds__(256) void svd_reduce2(
    const float* __restrict__ T0, const float* __restrict__ E0,
    const float* __restrict__ T1, const float* __restrict__ E1,
    float* __restrict__ Mu, float* __restrict__ Mi) {
  const int dir = blockIdx.y;
  const float* __restrict__ T = dir ? T1 : T0;
  const float* __restrict__ E = dir ? E1 : E0;
  float* __restrict__ M = dir ? Mi : Mu;
  const int lane = threadIdx.x & 63;
  const int wl = threadIdx.x >> 6;
  const int gw = blockIdx.x * 4 + wl;  // 0..4095
  float a0 = 0.f, a1 = 0.f, a2 = 0.f, a3 = 0.f, a4 = 0.f;
  for (int i = gw; i < NROW; i += 4096) {
    const float x = E[(size_t)i * 64 + lane];
    a0 += T[i] * x;
    a1 += T[NROW + i] * x;
    a2 += T[2 * NROW + i] * x;
    a3 += T[3 * NROW + i] * x;
    a4 += T[4 * NROW + i] * x;
  }
  __shared__ float red[4][5][64];
  red[wl][0][lane] = a0; red[wl][1][lane] = a1; red[wl][2][lane] = a2;
  red[wl][3][lane] = a3; red[wl][4][lane] = a4;
  __syncthreads();
  for (int o = threadIdx.x; o < 320; o += 256) {
    const int q = o >> 6, d = o & 63;
    const float s = red[0][q][d] + red[1][q][d] + red[2][q][d] + red[3][q][d];
    atomicAdd(&M[o], s);
  }
}

// gather batch rows & L2-normalize -> bf16; blockIdx.y selects {Z, Zd, G}
__global__ __launch_bounds__(256) void gather_norm(
    const int* __restrict__ ids, const float* __restrict__ Z,
    const float* __restrict__ Zd, const float* __restrict__ mul_s,
    const float* __restrict__ M, u16* __restrict__ oZ,
    u16* __restrict__ oZd, u16* __restrict__ oG) {
  long long t = (long long)blockIdx.x * blockDim.x + threadIdx.x;
  int b = (int)(t >> 6);
  int d = (int)(t & 63);
  if (b >= C_B) return;
  int id = rfl(ids[b]);
  float v;
  u16* out;
  if (blockIdx.y == 0) { v = Z[(size_t)id * 64 + d]; out = oZ; }
  else if (blockIdx.y == 1) { v = Zd[(size_t)id * 64 + d]; out = oZd; }
  else {
    float s = 0.f;
#pragma unroll
    for (int q = 0; q < 5; ++q) s += mul_s[(size_t)id * 5 + q] * M[q * 64 + d];
    v = leaky(s);
    out = oG;
  }
  float ss = v * v;
#pragma unroll
  for (int off = 1; off < 64; off <<= 1) ss += __shfl_xor(ss, off);
  float nrm = fmaxf(sqrtf(ss), 1e-12f);
  out[(size_t)b * 64 + d] = f2bf(v / nrm);
}

// ---------------- MFMA hyper: hy[call] = normbuf[hsrc] @ W[wsel] ----------------
__global__ __launch_bounds__(256) void hyper_mfma(
    const u16* __restrict__ nb, const u16* __restrict__ Wt16,
    u16* __restrict__ hy) {
  const int call = blockIdx.y;
  const int b0 = blockIdx.x * 64;
  __shared__ u16 Xs[64 * 64];
  __shared__ u16 Ws[64 * 64];
  const int tid = threadIdx.x, lane = tid & 63, wid = tid >> 6;
  const u16* X = nb + (size_t)c_hsrc[call] * C_B * 64;
  const u16* Wt = Wt16 + (size_t)c_wsel[call] * 4096;
  {
    const int r = tid >> 2, seg = tid & 3;
    const int base = r * 128 + seg * 32, sw = (r & 7) << 4;
    const uint4* sx = (const uint4*)&X[(size_t)(b0 + r) * 64 + seg * 16];
    uint4 a = sx[0], b = sx[1];
    *(uint4*)((char*)Xs + (base ^ sw)) = a;
    *(uint4*)((char*)Xs + ((base + 16) ^ sw)) = b;
    const uint4* sv = (const uint4*)&Wt[r * 64 + seg * 16];
    uint4 c = sv[0], d = sv[1];
    *(uint4*)((char*)Ws + (base ^ sw)) = c;
    *(uint4*)((char*)Ws + ((base + 16) ^ sw)) = d;
  }
  __syncthreads();
  const int am = (wid << 4) + (lane & 15);  // A (X) row within tile
  short8 af[2];
#pragma unroll
  for (int ks = 0; ks < 2; ++ks) {
    const int off = (am * 128 + ks * 64 + ((lane >> 4) << 4)) ^ ((am & 7) << 4);
    af[ks] = *(const short8*)((const char*)Xs + off);
  }
  const int ob = b0 + (wid << 4) + ((lane >> 4) << 2);
#pragma unroll
  for (int n = 0; n < 4; ++n) {
    const int bn = (n << 4) + (lane & 15);  // B (Wt) row = output col d
    f32x4 acc = {0.f, 0.f, 0.f, 0.f};
#pragma unroll
    for (int ks = 0; ks < 2; ++ks) {
      const int off = (bn * 128 + ks * 64 + ((lane >> 4) << 4)) ^ ((bn & 7) << 4);
      short8 bf = *(const short8*)((const char*)Ws + off);
      acc = __builtin_amdgcn_mfma_f32_16x16x32_bf16(af[ks], bf, acc, 0, 0, 0);
    }
    const int d = (n << 4) + (lane & 15);
#pragma unroll
    for (int j = 0; j < 4; ++j)
      hy[(size_t)call * C_B * 64 + (size_t)(ob + j) * 64 + d] = f2bf(acc[j]);
  }
}

// ---------------- MFMA info_nce (dbuf H staging, hoisted diag, exp2) ----------------
__global__ __launch_bounds__(256) void nce_mfma(
    const u16* __restrict__ nb, const u16* __restrict__ hy,
    float* __restrict__ slots, NceKeys nk) {
  const int call = blockIdx.y;
  const u16* G = nb + (size_t)c_gsel[call] * C_B * 64;
  const u16* H = hy + (size_t)call * C_B * 64;
  const int br = blockIdx.x * 64;
  __shared__ u16 Gs[64 * 64];
  __shared__ u16 Hs[2][64 * 64];
  const int tid = threadIdx.x, lane = tid & 63, wid = tid >> 6;
  const int r = tid >> 2, seg = tid & 3;
  const int base = r * 128 + seg * 32, sw = (r & 7) << 4;
  {
    const uint4* src = (const uint4*)&G[(size_t)(br + r) * 64 + seg * 16];
    uint4 a = src[0], b = src[1];
    *(uint4*)((char*)Gs + (base ^ sw)) = a;
    *(uint4*)((char*)Gs + ((base + 16) ^ sw)) = b;
  }
  {
    const uint4* src = (const uint4*)&H[(size_t)r * 64 + seg * 16];
    uint4 a = src[0], b = src[1];
    *(uint4*)((char*)Hs[0] + (base ^ sw)) = a;
    *(uint4*)((char*)Hs[0] + ((base + 16) ^ sw)) = b;
  }
  const int gcol = (wid << 4) + (lane & 15);
  const int g_glob = br + gcol;
  float rs0 = 0.f, rs1 = 0.f, ps = 0.f;
  short8 bfG[2];
  int cur = 0;
  for (int jt = 0; jt < 64; ++jt) {
    __syncthreads();  // Hs[cur] (and Gs on first iter) ready
    if (jt == 0) {
#pragma unroll
      for (int ks = 0; ks < 2; ++ks) {
        const int off = (gcol * 128 + ks * 64 + ((lane >> 4) << 4)) ^ ((gcol & 7) << 4);
        bfG[ks] = *(const short8*)((const char*)Gs + off);
      }
    }
    uint4 na, nb_;
    if (jt + 1 < 64) {  // prefetch next H tile (latency hidden under compute)
      const uint4* src = (const uint4*)&H[(size_t)((jt + 1) * 64 + r) * 64 + seg * 16];
      na = src[0]; nb_ = src[1];
    }
    const bool diag_jt = (jt == blockIdx.x);
    const char* Hb = (const char*)(Hs[cur]);
#pragma unroll
    for (int hs = 0; hs < 4; ++hs) {
      const int hr = (hs << 4) + (lane & 15);
      f32x4 acc = {0.f, 0.f, 0.f, 0.f};
      __builtin_amdgcn_s_setprio(1);
#pragma unroll
      for (int ks = 0; ks < 2; ++ks) {
        const int off = (hr * 128 + ks * 64 + ((lane >> 4) << 4)) ^ ((hr & 7) << 4);
        short8 af = *(const short8*)(Hb + off);
        acc = __builtin_amdgcn_mfma_f32_16x16x32_bf16(af, bfG[ks], acc, 0, 0, 0);
      }
      __builtin_amdgcn_s_setprio(0);
      float ev[4];
#pragma unroll
      for (int j = 0; j < 4; ++j) ev[j] = exp2f(acc[j] * 7.2134752f);  // exp(s/T)
      rs0 += ev[0] + ev[1];
      rs1 += ev[2] + ev[3];
      if (diag_jt && hs == wid) {  // wave-uniform: only tile jt==bx, stripe hs==wid
        const int jb = (hs << 4) + ((lane >> 4) << 2);
#pragma unroll
        for (int j = 0; j < 4; ++j)
          if (jb + j == gcol) ps = ev[j];
      }
    }
    if (jt + 1 < 64) {
      *(uint4*)((char*)Hs[cur ^ 1] + (base ^ sw)) = na;
      *(uint4*)((char*)Hs[cur ^ 1] + ((base + 16) ^ sw)) = nb_;
    }
    cur ^= 1;
  }
  float rs = rs0 + rs1;
  rs += __shfl_xor(rs, 16); rs += __shfl_xor(rs, 32);
  ps += __shfl_xor(ps, 16); ps += __shfl_xor(ps, 32);
  float c = 0.f;
  if ((lane >> 4) == 0) {
    float v = -__logf(ps / (rs + 1e-8f) + 1e-8f);
    float u = tf_uniform(nk.k0[call], nk.k1[call], (uint32_t)g_glob);
    c = (u > 0.5f) ? v : 0.f;
  }
  c += __shfl_xor(c, 1); c += __shfl_xor(c, 2);
  c += __shfl_xor(c, 4); c += __shfl_xor(c, 8);
  if (lane == 0) atomicAdd(&slots[c_slot[call]], c);
}

// E_sum = E0 + 2*E1 + Z2 + Zd2  (E2 never materialized)
__global__ __launch_bounds__(256) void loss_r_kernel(
    const float* __restrict__ E0u, const float* __restrict__ Eu1,
    const float* __restrict__ Zu, const float* __restrict__ Zdu,
    const float* __restrict__ E0i, const float* __restrict__ Ei1,
    const float* __restrict__ Zi, const float* __restrict__ Zdi,
    const int* __restrict__ uids, const int* __restrict__ pos,
    const int* __restrict__ neg, float* __restrict__ slots) {
  long long t = (long long)blockIdx.x * blockDim.x + threadIdx.x;
  int b = (int)(t >> 6);
  int d = (int)(t & 63);
  if (b >= C_B) return;
  size_t ju = (size_t)rfl(uids[b]) * 64 + d;
  float u = E0u[ju] + 2.f * Eu1[ju] + Zu[ju] + Zdu[ju];
  float bpr = 0.f, pmin = 3.4e38f, nmax = -3.4e38f;
  for (int p = 0; p < C_P; ++p) {
    size_t jp = (size_t)rfl(pos[b * C_P + p]) * 64 + d;
    size_t jn = (size_t)rfl(neg[b * C_P + p]) * 64 + d;
    float pe = E0i[jp] + 2.f * Ei1[jp] + Zi[jp] + Zdi[jp];
    float ne = E0i[jn] + 2.f * Ei1[jn] + Zi[jn] + Zdi[jn];
    float psc = u * pe, nsc = u * ne;
#pragma unroll
    for (int off = 1; off < 64; off <<= 1) {
      psc += __shfl_xor(psc, off);
      nsc += __shfl_xor(nsc, off);
    }
    pmin = fminf(pmin, psc);
    nmax = fmaxf(nmax, nsc);
    bpr += fmaxf(1.f - psc + nsc, 0.f);
  }
  if (d == 0) {
    float hd = (nmax - pmin > 0.005f) ? 10.f * (nmax - pmin) : 0.f;
    atomicAdd(&slots[5], bpr + hd);
  }
}

__global__ void final_kernel(const float* __restrict__ slots, float* __restrict__ out) {
  if (threadIdx.x == 0 && blockIdx.x == 0) {
    float n = slots[0], dl = slots[1], nn = slots[2], dd = slots[3], nd = slots[4];
    float lr = slots[5] / (float)C_B;
    out[0] = lr + 0.2f * (n + dl) + 0.2f * (nn + dd + nd);
    out[1] = lr;
    out[2] = dl;
    out[3] = n;
  }
}

// ---------------- host ----------------
extern "C" void kernel_launch(void* const* d_in, const int* in_sizes, int n_in,
                              void* d_out, int out_size, void* d_ws, size_t ws_size,
                              hipStream_t stream) {
  (void)in_sizes; (void)n_in; (void)out_size;
  const float* E_u_0   = (const float*)d_in[0];
  const float* E_i_0   = (const float*)d_in[1];
  const float* adjvals = (const float*)d_in[2];
  const float* u_mul_s = (const float*)d_in[3];
  const float* v_mul_s = (const float*)d_in[4];
  const float* ut      = (const float*)d_in[5];
  const float* vt      = (const float*)d_in[6];
  const float* W_nn    = (const float*)d_in[7];
  const float* W_dd    = (const float*)d_in[8];
  const float* W_ng    = (const float*)d_in[9];
  const float* W_dg    = (const float*)d_in[10];
  const float* W_nd    = (const float*)d_in[11];
  const int* adj_rows  = (const int*)d_in[12];
  const int* adj_cols  = (const int*)d_in[13];
  const int* uids      = (const int*)d_in[14];
  const int* iids      = (const int*)d_in[15];
  const int* pos       = (const int*)d_in[16];
  const int* neg       = (const int*)d_in[17];
  float* out = (float*)d_out;

  const size_t NU64 = (size_t)C_NU * 64;
  const size_t NI64 = (size_t)C_NI * 64;
  const size_t B64  = (size_t)C_B * 64;

  float* w = (float*)d_ws;
  float* Eu1 = w; w += NU64;
  float* Ei1 = w; w += NI64;
  float* Zu  = w; w += NU64;   // edgesA aliases Zu..Zdu
  float* Zdu = w; w += NU64;
  float* Zi  = w; w += NI64;
  float* Zdi = w; w += NI64;
  float* Mu = w; w += 512;
  float* Mi = w; w += 512;
  u16* normbuf16 = (u16*)w; w += 6 * B64;     // 12 bf16 buffers of B64
  float* slots = w; w += 16;
  uint2* edgesB = (uint2*)w; w += 4 * C_NE;   // 32 MB final CSR (both dirs)
  u16* hyper16 = (u16*)edgesB;                // alias: edgesB dead before hyper
  u16* Wt16 = (u16*)w; w += 16384;            // 8 x 64x64 bf16 (transposed)
  uint32_t* cntA = (uint32_t*)w; w += NCB * NCHK * 2;
  uint32_t* offs = (uint32_t*)w; w += NCB * NCHK * 2;
  uint32_t* bsumA = (uint32_t*)w; w += NCB;
  uint32_t* boffA = (uint32_t*)w; w += NCB;
  uint32_t* startsAbs = (uint32_t*)w; w += 2 * (NROW + 1);
  u16* Eu0b = (u16*)w; w += NU64 / 2;         // bf16 copies for gathers
  u16* Ei0b = (u16*)w; w += NI64 / 2;         // (Ei1b aliases Ei0b)
  u16* Eu1b = (u16*)w; w += NU64 / 2;
  u16* Ei1b = Ei0b;                           // Ei0b dead once dir1-l0 runs
  uint2* edgesA = (uint2*)Zu;                 // 32 MB coarse buffer, dead before spmm
  if ((size_t)((char*)w - (char*)d_ws) > ws_size) return;

  // ---- host-side JAX key derivation (partitionable threefry) ----
  auto ksplit = [](uint32_t a, uint32_t b, uint32_t idx, uint32_t& o0, uint32_t& o1) {
    uint32_t x0 = 0u, x1 = idx;
    tf2x32(a, b, x0, x1);
    o0 = x0; o1 = x1;
  };
  uint32_t rk0 = 0u, rk1 = 42u;
  uint32_t lk[2][4][2];
  for (int l = 0; l < 2; ++l) {
    uint32_t n0, n1;
    ksplit(rk0, rk1, 0u, n0, n1);
    for (int i = 0; i < 4; ++i) ksplit(rk0, rk1, (uint32_t)(i + 1), lk[l][i][0], lk[l][i][1]);
    rk0 = n0; rk1 = n1;
  }
  NceKeys nk;
  {
    uint32_t mk0 = 0u, mk1 = 7u;
    for (int i = 0; i < 16; ++i) {
      uint32_t n0, n1;
      ksplit(mk0, mk1, 0u, n0, n1);
      ksplit(mk0, mk1, 1u, nk.k0[i], nk.k1[i]);
      mk0 = n0; mk1 = n1;
    }
  }
  DropKeys dk;
  dk.a[0] = lk[0][0][0]; dk.a[1] = lk[0][0][1];
  dk.a[2] = lk[1][0][0]; dk.a[3] = lk[1][0][1];
  dk.a[4] = lk[0][1][0]; dk.a[5] = lk[0][1][1];
  dk.a[6] = lk[1][1][0]; dk.a[7] = lk[1][1][1];
  WPtrs wp;
  wp.W[0] = W_ng; wp.W[1] = W_ng + 4096;
  wp.W[2] = W_nn;
  wp.W[3] = W_dg; wp.W[4] = W_dg + 4096;
  wp.W[5] = W_dd;
  wp.W[6] = W_nd; wp.W[7] = W_nd + 4096;

  // ---- sort + preps ----
  hipMemsetAsync(slots, 0, 16 * 4, stream);
  passA_hist<<<dim3(NCHK, 2), 256, 0, stream>>>(adj_rows, adj_cols, cntA);
  scanA1<<<NCB, 512, 0, stream>>>(cntA, offs, bsumA);
  scanA2<<<1, 256, 0, stream>>>(bsumA, boffA);
  scanA3<<<NCB, 512, 0, stream>>>(offs, boffA);
  passA_scatter<<<dim3(NCHK, 2), 256, 0, stream>>>(
      adj_rows, adj_cols, adjvals, offs, edgesA, dk);
  passB_kernel<<<dim3(NCB, 2), 512, 0, stream>>>(edgesA, offs, edgesB, startsAbs);
  bf16_convert<<<(int)(NU64 / 4 + 255) / 256, 256, 0, stream>>>(E_u_0, Eu0b, (int)(NU64 / 4));
  bf16_convert<<<(int)(NI64 / 4 + 255) / 256, 256, 0, stream>>>(E_i_0, Ei0b, (int)(NI64 / 4));
  w16_prep<<<(8 * 4096 + 255) / 256, 256, 0, stream>>>(wp, Wt16);

  const int gb = (int)(B64 / 256);  // 1024
  const int sb = (NROW + 3) / 4;    // 25000 blocks, 4 waves each

  for (int l = 0; l < 2; ++l) {
    hipMemsetAsync(Mu, 0, 1024 * 4, stream);  // Mu+Mi contiguous
    svd_reduce2<<<dim3(1024, 2), 256, 0, stream>>>(
        vt, (l == 0) ? E_i_0 : Ei1, ut, (l == 0) ? E_u_0 : Eu1, Mu, Mi);
    // dir0: items -> users (noise key k3)
    spmm_row<<<sb, 256, 0, stream>>>(
        edgesB, startsAbs, (l == 0) ? Ei0b : Ei1b,
        (l == 0) ? E_u_0 : nullptr, (l == 0) ? Eu1 : nullptr,
        (l == 0) ? Eu1b : nullptr, Zu, Zdu, lk[l][2][0], lk[l][2][1], l);
    // dir1: users -> items (noise key k4)
    spmm_row<<<sb, 256, 0, stream>>>(
        edgesB, startsAbs + (NROW + 1), (l == 0) ? Eu0b : Eu1b,
        (l == 0) ? E_i_0 : nullptr, (l == 0) ? Ei1 : nullptr,
        (l == 0) ? Ei1b : nullptr, Zi, Zdi, lk[l][3][0], lk[l][3][1], l);
    gather_norm<<<dim3(gb, 3), 256, 0, stream>>>(
        uids, Zu, Zdu, u_mul_s, Mu,
        normbuf16 + (size_t)(0 + l) * B64, normbuf16 + (size_t)(4 + l) * B64,
        normbuf16 + (size_t)(8 + l) * B64);
    gather_norm<<<dim3(gb, 3), 256, 0, stream>>>(
        iids, Zi, Zdi, v_mul_s, Mi,
        normbuf16 + (size_t)(2 + l) * B64, normbuf16 + (size_t)(6 + l) * B64,
        normbuf16 + (size_t)(10 + l) * B64);
  }

  hyper_mfma<<<dim3(C_B / 64, 16), 256, 0, stream>>>(normbuf16, Wt16, hyper16);
  nce_mfma<<<dim3(C_B / 64, 16), 256, 0, stream>>>(normbuf16, hyper16, slots, nk);
  loss_r_kernel<<<gb, 256, 0, stream>>>(E_u_0, Eu1, Zu, Zdu, E_i_0, Ei1, Zi, Zdi,
                                        uids, pos, neg, slots);
  final_kernel<<<1, 1, 0, stream>>>(slots, out);
}

// Round 9
// 687.112 us; speedup vs baseline: 12.3710x; 1.0653x over previous
//
#include <hip/hip_runtime.h>
#include <hip/hip_bf16.h>
#include <cstdint>

#define C_NU 100000
#define C_NI 100000
#define C_DIM 64
#define C_Q 5
#define C_NE 2000000
#define C_B 4096
#define C_P 10
#define NROW 100000
#define NCB 196      // coarse buckets of 512 rows
#define NCHK 256     // chunks in pass A
#define CHUNK 7813   // ceil(2M/256)

typedef unsigned short u16;
typedef unsigned char u8;
typedef __attribute__((ext_vector_type(8))) short short8;
typedef __attribute__((ext_vector_type(4))) float f32x4;

__device__ static inline int rfl(int v) { return __builtin_amdgcn_readfirstlane(v); }
__device__ static inline uint32_t rflu(uint32_t v) {
  return (uint32_t)__builtin_amdgcn_readfirstlane((int)v);
}

// ---------------- Threefry-2x32 (JAX-compatible), 20 rounds ----------------
__host__ __device__ static inline void tf2x32(uint32_t k0, uint32_t k1,
                                              uint32_t& x0, uint32_t& x1) {
  uint32_t k2 = k0 ^ k1 ^ 0x1BD11BDAu;
#define TFR(r) { x0 += x1; x1 = (x1 << r) | (x1 >> (32 - r)); x1 ^= x0; }
  x0 += k0; x1 += k1;
  TFR(13) TFR(15) TFR(26) TFR(6)
  x0 += k1; x1 += k2 + 1u;
  TFR(17) TFR(29) TFR(16) TFR(24)
  x0 += k2; x1 += k0 + 2u;
  TFR(13) TFR(15) TFR(26) TFR(6)
  x0 += k0; x1 += k1 + 3u;
  TFR(17) TFR(29) TFR(16) TFR(24)
  x0 += k1; x1 += k2 + 4u;
  TFR(13) TFR(15) TFR(26) TFR(6)
  x0 += k2; x1 += k0 + 5u;
#undef TFR
}

// partitionable-mode random bits at flat index idx (hi counter = 0)
__device__ static inline float tf_uniform(uint32_t k0, uint32_t k1, uint32_t idx) {
  uint32_t x0 = 0u, x1 = idx;
  tf2x32(k0, k1, x0, x1);
  uint32_t bits = x0 ^ x1;
  return __uint_as_float((bits >> 9) | 0x3F800000u) - 1.0f;
}

__device__ static inline float leaky(float x) { return x >= 0.f ? x : 0.5f * x; }

__device__ static inline u16 f2bf(float f) {  // RNE fp32->bf16
  uint32_t x = __float_as_uint(f);
  return (u16)((x + 0x7FFFu + ((x >> 16) & 1u)) >> 16);
}
__device__ static inline float bf2f(u16 u) {
  return __uint_as_float((uint32_t)u << 16);
}

// fp8 store: byte = sign | 7-bit (4-exp,3-mant) of (x*256), RNE, underflow->0.
// decode: val = as_float(((b&0x80)<<24)|((b&0x7F)<<20)) * 2^120; x = val*2^-8.
__device__ static inline u8 f2fp8(float x) {
  float t = x * 256.f;
  uint32_t sgn = (__float_as_uint(t) >> 24) & 0x80u;
  float a = fabsf(t) * 0x1p-120f;
  uint32_t u = __float_as_uint(a);
  u += 0x7FFFFu + ((u >> 20) & 1u);
  uint32_t mag = u >> 20;
  if (mag > 0x7Fu) mag = 0x7Fu;
  return (u8)(sgn | mag);
}

// ---------------- constant maps for the 16 info_nce calls ----------------
// normbuf slots: 0:Zu1 1:Zu2 2:Zi1 3:Zi2 4:Zdu1 5:Zdu2 6:Zdi1 7:Zdi2 8:Gu1 9:Gu2 10:Gi1 11:Gi2
__constant__ int c_gsel[16] = {0,1,2,3, 0,2, 4,5,6,7, 4,6, 0,1,2,3};
__constant__ int c_hsrc[16] = {8,9,10,11, 1,3, 8,9,10,11, 5,7, 4,5,6,7};
// W order: 0:ng0 1:ng1 2:nn 3:dg0 4:dg1 5:dd 6:nd0 7:nd1
__constant__ int c_wsel[16] = {0,1,0,1, 2,2, 3,4,3,4, 5,5, 6,7,6,7};
// slots: 0:n 1:d 2:nn 3:dd 4:nd (5: loss_r sum)
__constant__ int c_slot[16] = {0,0,0,0, 2,2, 1,1,1,1, 3,3, 4,4,4,4};

struct WPtrs { const float* W[8]; };
struct NceKeys { uint32_t k0[16]; uint32_t k1[16]; };
struct DropKeys { uint32_t a[8]; };

// ---------------- two-level counting sort ----------------

__global__ __launch_bounds__(256) void passA_hist(
    const int* __restrict__ rows, const int* __restrict__ cols,
    uint32_t* __restrict__ cntA) {
  __shared__ uint32_t h[NCB];
  const int dir = blockIdx.y, c = blockIdx.x, t = threadIdx.x;
  for (int i = t; i < NCB; i += 256) h[i] = 0u;
  __syncthreads();
  const int e0 = c * CHUNK, e1 = min(e0 + CHUNK, C_NE);
  const int* ids = dir ? cols : rows;
  for (int e = e0 + t; e < e1; e += 256) atomicAdd(&h[ids[e] >> 9], 1u);
  __syncthreads();
  for (int i = t; i < NCB; i += 256) cntA[(dir * NCB + i) * NCHK + c] = h[i];
}

__global__ __launch_bounds__(512) void scanA1(
    const uint32_t* __restrict__ cntA, uint32_t* __restrict__ offs,
    uint32_t* __restrict__ bsum) {
  __shared__ uint32_t s[512];
  const int b = blockIdx.x, t = threadIdx.x;
  const int idx = b * 512 + t;
  uint32_t v = cntA[idx];
  s[t] = v;
  __syncthreads();
  for (int off = 1; off < 512; off <<= 1) {
    uint32_t a = (t >= off) ? s[t - off] : 0u;
    __syncthreads();
    s[t] += a;
    __syncthreads();
  }
  offs[idx] = s[t] - v;
  if (t == 511) bsum[b] = s[511];
}

__global__ __launch_bounds__(256) void scanA2(
    const uint32_t* __restrict__ bsum, uint32_t* __restrict__ boff) {
  __shared__ uint32_t s[256];
  const int t = threadIdx.x;
  uint32_t v = (t < NCB) ? bsum[t] : 0u;
  s[t] = v;
  __syncthreads();
  for (int off = 1; off < 256; off <<= 1) {
    uint32_t a = (t >= off) ? s[t - off] : 0u;
    __syncthreads();
    s[t] += a;
    __syncthreads();
  }
  if (t < NCB) boff[t] = s[t] - v;
}

__global__ __launch_bounds__(512) void scanA3(
    uint32_t* __restrict__ offs, const uint32_t* __restrict__ boff) {
  offs[blockIdx.x * 512 + threadIdx.x] += boff[blockIdx.x];
}

// record.x = src(17b) | keepL0<<17 | keepL1<<18 | (dst&511)<<19
__global__ __launch_bounds__(256) void passA_scatter(
    const int* __restrict__ rows, const int* __restrict__ cols,
    const float* __restrict__ vals, const uint32_t* __restrict__ offs,
    uint2* __restrict__ edgesA, DropKeys dk) {
  __shared__ uint32_t lofs[NCB];
  const int dir = blockIdx.y, c = blockIdx.x, t = threadIdx.x;
  for (int i = t; i < NCB; i += 256) lofs[i] = offs[(dir * NCB + i) * NCHK + c];
  __syncthreads();
  const int e0 = c * CHUNK, e1 = min(e0 + CHUNK, C_NE);
  const uint32_t kA0 = dk.a[dir * 4 + 0], kA1 = dk.a[dir * 4 + 1];
  const uint32_t kB0 = dk.a[dir * 4 + 2], kB1 = dk.a[dir * 4 + 3];
  for (int e = e0 + t; e < e1; e += 256) {
    const int r = rows[e], cc = cols[e];
    const int dst = dir ? cc : r, src = dir ? r : cc;
    const uint32_t kl0 = (tf_uniform(kA0, kA1, (uint32_t)e) < 0.9f) ? 1u : 0u;
    const uint32_t kl1 = (tf_uniform(kB0, kB1, (uint32_t)e) < 0.9f) ? 1u : 0u;
    const uint32_t x = (uint32_t)src | (kl0 << 17) | (kl1 << 18) |
                       ((uint32_t)(dst & 511) << 19);
    const uint32_t pos = atomicAdd(&lofs[dst >> 9], 1u);
    edgesA[pos] = make_uint2(x, __float_as_uint(vals[e]));
  }
}

__global__ __launch_bounds__(512) void passB_kernel(
    const uint2* __restrict__ edgesA, const uint32_t* __restrict__ offs,
    uint2* __restrict__ edgesB, uint32_t* __restrict__ starts) {
  __shared__ uint32_t cnt[512];
  __shared__ uint32_t scn[512];
  const int dir = blockIdx.y, cb = blockIdx.x, t = threadIdx.x;
  const uint32_t segStart = offs[(dir * NCB + cb) * NCHK];
  const uint32_t segEnd = (dir == 1 && cb == NCB - 1)
                              ? (uint32_t)(2 * C_NE)
                              : offs[(dir * NCB + cb + 1) * NCHK];
  cnt[t] = 0u;
  __syncthreads();
  for (uint32_t e = segStart + t; e < segEnd; e += 512)
    atomicAdd(&cnt[(edgesA[e].x >> 19) & 511u], 1u);
  __syncthreads();
  uint32_t v = cnt[t];
  scn[t] = v;
  __syncthreads();
  for (int off = 1; off < 512; off <<= 1) {
    uint32_t a = (t >= off) ? scn[t - off] : 0u;
    __syncthreads();
    scn[t] += a;
    __syncthreads();
  }
  const uint32_t rstart = segStart + scn[t] - v;
  const int grow = cb * 512 + t;
  if (grow < NROW) starts[dir * (NROW + 1) + grow] = rstart;
  if (cb == NCB - 1 && t == 0) starts[dir * (NROW + 1) + NROW] = segEnd;
  cnt[t] = rstart;
  __syncthreads();
  for (uint32_t e = segStart + t; e < segEnd; e += 512) {
    const uint2 q = edgesA[e];
    const uint32_t pos = atomicAdd(&cnt[(q.x >> 19) & 511u], 1u);
    edgesB[pos] = q;
  }
}

// ---------------- fp32 -> fp8 table convert ----------------
__global__ __launch_bounds__(256) void fp8_convert(
    const float* __restrict__ src, u8* __restrict__ dst, int n4) {
  int i = blockIdx.x * 256 + threadIdx.x;
  if (i >= n4) return;
  float4 v = ((const float4*)src)[i];
  uint32_t o = (uint32_t)f2fp8(v.x) | ((uint32_t)f2fp8(v.y) << 8) |
               ((uint32_t)f2fp8(v.z) << 16) | ((uint32_t)f2fp8(v.w) << 24);
  ((uint32_t*)dst)[i] = o;
}

// Wt16[w][d][k] = bf16(W[w][k][d])  (pre-transposed for MFMA B-operand)
__global__ __launch_bounds__(256) void w16_prep(WPtrs wp, u16* __restrict__ Wt16) {
  int i = blockIdx.x * 256 + threadIdx.x;
  if (i >= 8 * 4096) return;
  int w = i >> 12, kd = i & 4095, k = kd >> 6, d = kd & 63;
  Wt16[w * 4096 + d * 64 + k] = f2bf(wp.W[w][k * 64 + d]);
}

// ---------------- fused spmm (wave/row, scalarized, fp8 gathers) ----------------
__global__ __launch_bounds__(256) void spmm_row(
    const uint2* __restrict__ edges, const uint32_t* __restrict__ starts,
    const u8* __restrict__ Einf, const float* __restrict__ Eprev,
    float* __restrict__ Enext, u8* __restrict__ Enf8,
    u16* __restrict__ Zout, u16* __restrict__ Zdout,
    uint32_t nk0, uint32_t nk1, int layer) {
  const int row = rfl(blockIdx.x * 4 + (threadIdx.x >> 6));
  const int lane = threadIdx.x & 63;
  if (row >= NROW) return;
  const uint32_t s0 = rflu(starts[row]);
  const uint32_t s1 = rflu(starts[row + 1]);
  const uint32_t kbit = 1u << (17 + layer);
  const float VS = 0x1p112f;  // fp8 decode scale (2^120) * table scale (2^-8)
  float z = 0.f, zd = 0.f;
  uint32_t e = s0;
  for (; e + 4 <= s1; e += 4) {
    const uint32_t p0 = rflu(edges[e].x),     w0 = rflu(edges[e].y);
    const uint32_t p1 = rflu(edges[e + 1].x), w1 = rflu(edges[e + 1].y);
    const uint32_t p2 = rflu(edges[e + 2].x), w2 = rflu(edges[e + 2].y);
    const uint32_t p3 = rflu(edges[e + 3].x), w3 = rflu(edges[e + 3].y);
    const uint32_t b0 = Einf[(size_t)(p0 & 0x1FFFFu) * 64 + lane];
    const uint32_t b1 = Einf[(size_t)(p1 & 0x1FFFFu) * 64 + lane];
    const uint32_t b2 = Einf[(size_t)(p2 & 0x1FFFFu) * 64 + lane];
    const uint32_t b3 = Einf[(size_t)(p3 & 0x1FFFFu) * 64 + lane];
    const float x0 = __uint_as_float(((b0 & 0x80u) << 24) | ((b0 & 0x7Fu) << 20));
    const float x1 = __uint_as_float(((b1 & 0x80u) << 24) | ((b1 & 0x7Fu) << 20));
    const float x2 = __uint_as_float(((b2 & 0x80u) << 24) | ((b2 & 0x7Fu) << 20));
    const float x3 = __uint_as_float(((b3 & 0x80u) << 24) | ((b3 & 0x7Fu) << 20));
    const float v0 = __uint_as_float(w0) * VS, v1 = __uint_as_float(w1) * VS;
    const float v2 = __uint_as_float(w2) * VS, v3 = __uint_as_float(w3) * VS;
    const float d0 = (p0 & kbit) ? v0 : 0.f;
    const float d1 = (p1 & kbit) ? v1 : 0.f;
    const float d2 = (p2 & kbit) ? v2 : 0.f;
    const float d3 = (p3 & kbit) ? v3 : 0.f;
    z += v0 * x0; zd += d0 * x0;
    z += v1 * x1; zd += d1 * x1;
    z += v2 * x2; zd += d2 * x2;
    z += v3 * x3; zd += d3 * x3;
  }
  for (; e < s1; ++e) {
    const uint32_t p = rflu(edges[e].x), wv = rflu(edges[e].y);
    const uint32_t b = Einf[(size_t)(p & 0x1FFFFu) * 64 + lane];
    const float x = __uint_as_float(((b & 0x80u) << 24) | ((b & 0x7Fu) << 20));
    const float v = __uint_as_float(wv) * VS;
    z += v * x;
    zd += ((p & kbit) ? v : 0.f) * x;
  }
  z = leaky(z);
  zd = leaky(zd * (1.0f / 0.9f));
  // noise-augmented view
  const float u = tf_uniform(nk0, nk1, (uint32_t)row * 64u + (uint32_t)lane);
  float ss = u * u;
#pragma unroll
  for (int off = 1; off < 64; off <<= 1) ss += __shfl_xor(ss, off);
  const float nrm = fmaxf(sqrtf(ss), 1e-12f);
  const float sg = (z > 0.f) ? 1.f : (z < 0.f ? -1.f : 0.f);
  z += sg * (u / nrm) * 0.1f;
  const size_t j = (size_t)row * 64 + lane;
  Zout[j] = f2bf(z);
  Zdout[j] = f2bf(zd);
  if (Enext) {  // layer 0 only: materialize E1 (fp32 + fp8 for next-layer gathers)
    const float en = z + zd + Eprev[j];
    Enext[j] = en;
    Enf8[j] = f2fp8(en);
  }
}

// ---------------- dual-dir SVD middle matrix, block-reduced atomics ----------------
__global__ __launch_bounds__(256) void svd_reduce2(
    const float* __restrict__ T0, const float* __restrict__ E0,
    const float* __restrict__ T1, const float* __restrict__ E1,
    float* __restrict__ Mu, float* __restrict__ Mi) {
  const int dir = blockIdx.y;
  const float* __restrict__ T = dir ? T1 : T0;
  const float* __restrict__ E = dir ? E1 : E0;
  float* __restrict__ M = dir ? Mi : Mu;
  const int lane = threadIdx.x & 63;
  const int wl = threadIdx.x >> 6;
  const int gw = blockIdx.x * 4 + wl;
  float a0 = 0.f, a1 = 0.f, a2 = 0.f, a3 = 0.f, a4 = 0.f;
  for (int i = gw; i < NROW; i += 4096) {
    const float x = E[(size_t)i * 64 + lane];
    a0 += T[i] * x;
    a1 += T[NROW + i] * x;
    a2 += T[2 * NROW + i] * x;
    a3 += T[3 * NROW + i] * x;
    a4 += T[4 * NROW + i] * x;
  }
  __shared__ float red[4][5][64];
  red[wl][0][lane] = a0; red[wl][1][lane] = a1; red[wl][2][lane] = a2;
  red[wl][3][lane] = a3; red[wl][4][lane] = a4;
  __syncthreads();
  for (int o = threadIdx.x; o < 320; o += 256) {
    const int q = o >> 6, d = o & 63;
    const float s = red[0][q][d] + red[1][q][d] + red[2][q][d] + red[3][q][d];
    atomicAdd(&M[o], s);
  }
}

// gather batch rows & L2-normalize -> bf16; blockIdx.y selects {Z, Zd, G}
__global__ __launch_bounds__(256) void gather_norm(
    const int* __restrict__ ids, const u16* __restrict__ Z,
    const u16* __restrict__ Zd, const float* __restrict__ mul_s,
    const float* __restrict__ M, u16* __restrict__ oZ,
    u16* __restrict__ oZd, u16* __restrict__ oG) {
  long long t = (long long)blockIdx.x * blockDim.x + threadIdx.x;
  int b = (int)(t >> 6);
  int d = (int)(t & 63);
  if (b >= C_B) return;
  int id = rfl(ids[b]);
  float v;
  u16* out;
  if (blockIdx.y == 0) { v = bf2f(Z[(size_t)id * 64 + d]); out = oZ; }
  else if (blockIdx.y == 1) { v = bf2f(Zd[(size_t)id * 64 + d]); out = oZd; }
  else {
    float s = 0.f;
#pragma unroll
    for (int q = 0; q < 5; ++q) s += mul_s[(size_t)id * 5 + q] * M[q * 64 + d];
    v = leaky(s);
    out = oG;
  }
  float ss = v * v;
#pragma unroll
  for (int off = 1; off < 64; off <<= 1) ss += __shfl_xor(ss, off);
  float nrm = fmaxf(sqrtf(ss), 1e-12f);
  out[(size_t)b * 64 + d] = f2bf(v / nrm);
}

// ---------------- MFMA hyper: hy[call] = normbuf[hsrc] @ W[wsel] ----------------
__global__ __launch_bounds__(256) void hyper_mfma(
    const u16* __restrict__ nb, const u16* __restrict__ Wt16,
    u16* __restrict__ hy) {
  const int call = blockIdx.y;
  const int b0 = blockIdx.x * 64;
  __shared__ u16 Xs[64 * 64];
  __shared__ u16 Ws[64 * 64];
  const int tid = threadIdx.x, lane = tid & 63, wid = tid >> 6;
  const u16* X = nb + (size_t)c_hsrc[call] * C_B * 64;
  const u16* Wt = Wt16 + (size_t)c_wsel[call] * 4096;
  {
    const int r = tid >> 2, seg = tid & 3;
    const int base = r * 128 + seg * 32, sw = (r & 7) << 4;
    const uint4* sx = (const uint4*)&X[(size_t)(b0 + r) * 64 + seg * 16];
    uint4 a = sx[0], b = sx[1];
    *(uint4*)((char*)Xs + (base ^ sw)) = a;
    *(uint4*)((char*)Xs + ((base + 16) ^ sw)) = b;
    const uint4* sv = (const uint4*)&Wt[r * 64 + seg * 16];
    uint4 c = sv[0], d = sv[1];
    *(uint4*)((char*)Ws + (base ^ sw)) = c;
    *(uint4*)((char*)Ws + ((base + 16) ^ sw)) = d;
  }
  __syncthreads();
  const int am = (wid << 4) + (lane & 15);
  short8 af[2];
#pragma unroll
  for (int ks = 0; ks < 2; ++ks) {
    const int off = (am * 128 + ks * 64 + ((lane >> 4) << 4)) ^ ((am & 7) << 4);
    af[ks] = *(const short8*)((const char*)Xs + off);
  }
  const int ob = b0 + (wid << 4) + ((lane >> 4) << 2);
#pragma unroll
  for (int n = 0; n < 4; ++n) {
    const int bn = (n << 4) + (lane & 15);
    f32x4 acc = {0.f, 0.f, 0.f, 0.f};
#pragma unroll
    for (int ks = 0; ks < 2; ++ks) {
      const int off = (bn * 128 + ks * 64 + ((lane >> 4) << 4)) ^ ((bn & 7) << 4);
      short8 bf = *(const short8*)((const char*)Ws + off);
      acc = __builtin_amdgcn_mfma_f32_16x16x32_bf16(af[ks], bf, acc, 0, 0, 0);
    }
    const int d = (n << 4) + (lane & 15);
#pragma unroll
    for (int j = 0; j < 4; ++j)
      hy[(size_t)call * C_B * 64 + (size_t)(ob + j) * 64 + d] = f2bf(acc[j]);
  }
}

// ---------------- MFMA info_nce: 128-row G tiles, 2 stripes/wave ----------------
__global__ __launch_bounds__(256) void nce_mfma(
    const u16* __restrict__ nb, const u16* __restrict__ hy,
    float* __restrict__ slots, NceKeys nk) {
  const int call = blockIdx.y;
  const u16* G = nb + (size_t)c_gsel[call] * C_B * 64;
  const u16* H = hy + (size_t)call * C_B * 64;
  const int br = blockIdx.x * 128;
  __shared__ u16 Gs[128 * 64];
  __shared__ u16 Hs[2][64 * 64];
  const int tid = threadIdx.x, lane = tid & 63, wid = tid >> 6;
  // stage G tile (128 rows), swizzled
  {
    const int r2 = tid >> 1;
    const int sw2 = (r2 & 7) << 4;
#pragma unroll
    for (int p = 0; p < 2; ++p) {
      const int sg = (tid & 1) + p * 2;
      const uint4* src = (const uint4*)&G[(size_t)(br + r2) * 64 + sg * 16];
      uint4 a = src[0], b = src[1];
      const int bse = r2 * 128 + sg * 32;
      *(uint4*)((char*)Gs + (bse ^ sw2)) = a;
      *(uint4*)((char*)Gs + ((bse + 16) ^ sw2)) = b;
    }
  }
  const int r = tid >> 2, seg = tid & 3;
  const int base = r * 128 + seg * 32, sw = (r & 7) << 4;
  {
    const uint4* src = (const uint4*)&H[(size_t)r * 64 + seg * 16];
    uint4 a = src[0], b = src[1];
    *(uint4*)((char*)Hs[0] + (base ^ sw)) = a;
    *(uint4*)((char*)Hs[0] + ((base + 16) ^ sw)) = b;
  }
  float rs[2] = {0.f, 0.f}, ps[2] = {0.f, 0.f};
  short8 bfG[2][2];
  const int jt_diag = (blockIdx.x << 1) + (wid >> 1);
  const int hsd0 = (wid & 1) << 1;  // stripe0 diag hs; stripe1 = hsd0+1
  int cur = 0;
  for (int jt = 0; jt < 64; ++jt) {
    __syncthreads();  // Hs[cur] (and Gs on first iter) ready
    if (jt == 0) {
#pragma unroll
      for (int s = 0; s < 2; ++s)
#pragma unroll
        for (int ks = 0; ks < 2; ++ks) {
          const int gc = (wid << 5) + (s << 4) + (lane & 15);
          const int off = (gc * 128 + ks * 64 + ((lane >> 4) << 4)) ^ ((gc & 7) << 4);
          bfG[s][ks] = *(const short8*)((const char*)Gs + off);
        }
    }
    uint4 na, nb_;
    if (jt + 1 < 64) {  // prefetch next H tile
      const uint4* src = (const uint4*)&H[(size_t)((jt + 1) * 64 + r) * 64 + seg * 16];
      na = src[0]; nb_ = src[1];
    }
    const bool dj = (jt == jt_diag);
    const char* Hb = (const char*)(Hs[cur]);
#pragma unroll
    for (int hs = 0; hs < 4; ++hs) {
      const int hr = (hs << 4) + (lane & 15);
      const int offA0 = (hr * 128 + ((lane >> 4) << 4)) ^ ((hr & 7) << 4);
      const int offA1 = (hr * 128 + 64 + ((lane >> 4) << 4)) ^ ((hr & 7) << 4);
      const short8 af0 = *(const short8*)(Hb + offA0);
      const short8 af1 = *(const short8*)(Hb + offA1);
      f32x4 acc0 = {0.f, 0.f, 0.f, 0.f}, acc1 = {0.f, 0.f, 0.f, 0.f};
      __builtin_amdgcn_s_setprio(1);
      acc0 = __builtin_amdgcn_mfma_f32_16x16x32_bf16(af0, bfG[0][0], acc0, 0, 0, 0);
      acc0 = __builtin_amdgcn_mfma_f32_16x16x32_bf16(af1, bfG[0][1], acc0, 0, 0, 0);
      acc1 = __builtin_amdgcn_mfma_f32_16x16x32_bf16(af0, bfG[1][0], acc1, 0, 0, 0);
      acc1 = __builtin_amdgcn_mfma_f32_16x16x32_bf16(af1, bfG[1][1], acc1, 0, 0, 0);
      __builtin_amdgcn_s_setprio(0);
      float e0[4], e1[4];
#pragma unroll
      for (int j = 0; j < 4; ++j) {
        e0[j] = exp2f(acc0[j] * 7.2134752f);
        e1[j] = exp2f(acc1[j] * 7.2134752f);
      }
      rs[0] += (e0[0] + e0[1]) + (e0[2] + e0[3]);
      rs[1] += (e1[0] + e1[1]) + (e1[2] + e1[3]);
      if (dj) {
        const int jm = (lane & 15) - ((lane >> 4) << 2);
        if (hs == hsd0) {
#pragma unroll
          for (int j = 0; j < 4; ++j)
            if (jm == j) ps[0] = e0[j];
        }
        if (hs == hsd0 + 1) {
#pragma unroll
          for (int j = 0; j < 4; ++j)
            if (jm == j) ps[1] = e1[j];
        }
      }
    }
    if (jt + 1 < 64) {
      *(uint4*)((char*)Hs[cur ^ 1] + (base ^ sw)) = na;
      *(uint4*)((char*)Hs[cur ^ 1] + ((base + 16) ^ sw)) = nb_;
    }
    cur ^= 1;
  }
#pragma unroll
  for (int s = 0; s < 2; ++s) {
    rs[s] += __shfl_xor(rs[s], 16); rs[s] += __shfl_xor(rs[s], 32);
    ps[s] += __shfl_xor(ps[s], 16); ps[s] += __shfl_xor(ps[s], 32);
  }
  float c = 0.f;
  if ((lane >> 4) == 0) {
#pragma unroll
    for (int s = 0; s < 2; ++s) {
      const float v = -__logf(ps[s] / (rs[s] + 1e-8f) + 1e-8f);
      const int gg = br + (wid << 5) + (s << 4) + (lane & 15);
      const float u = tf_uniform(nk.k0[call], nk.k1[call], (uint32_t)gg);
      c += (u > 0.5f) ? v : 0.f;
    }
  }
  c += __shfl_xor(c, 1); c += __shfl_xor(c, 2);
  c += __shfl_xor(c, 4); c += __shfl_xor(c, 8);
  if (lane == 0) atomicAdd(&slots[c_slot[call]], c);
}

// E_sum = E0 + 2*E1 + Z2 + Zd2  (E2 never materialized; Z in bf16)
__global__ __launch_bounds__(256) void loss_r_kernel(
    const float* __restrict__ E0u, const float* __restrict__ Eu1,
    const u16* __restrict__ Zu, const u16* __restrict__ Zdu,
    const float* __restrict__ E0i, const float* __restrict__ Ei1,
    const u16* __restrict__ Zi, const u16* __restrict__ Zdi,
    const int* __restrict__ uids, const int* __restrict__ pos,
    const int* __restrict__ neg, float* __restrict__ slots) {
  long long t = (long long)blockIdx.x * blockDim.x + threadIdx.x;
  int b = (int)(t >> 6);
  int d = (int)(t & 63);
  if (b >= C_B) return;
  size_t ju = (size_t)rfl(uids[b]) * 64 + d;
  float u = E0u[ju] + 2.f * Eu1[ju] + bf2f(Zu[ju]) + bf2f(Zdu[ju]);
  float bpr = 0.f, pmin = 3.4e38f, nmax = -3.4e38f;
  for (int p = 0; p < C_P; ++p) {
    size_t jp = (size_t)rfl(pos[b * C_P + p]) * 64 + d;
    size_t jn = (size_t)rfl(neg[b * C_P + p]) * 64 + d;
    float pe = E0i[jp] + 2.f * Ei1[jp] + bf2f(Zi[jp]) + bf2f(Zdi[jp]);
    float ne = E0i[jn] + 2.f * Ei1[jn] + bf2f(Zi[jn]) + bf2f(Zdi[jn]);
    float psc = u * pe, nsc = u * ne;
#pragma unroll
    for (int off = 1; off < 64; off <<= 1) {
      psc += __shfl_xor(psc, off);
      nsc += __shfl_xor(nsc, off);
    }
    pmin = fminf(pmin, psc);
    nmax = fmaxf(nmax, nsc);
    bpr += fmaxf(1.f - psc + nsc, 0.f);
  }
  if (d == 0) {
    float hd = (nmax - pmin > 0.005f) ? 10.f * (nmax - pmin) : 0.f;
    atomicAdd(&slots[5], bpr + hd);
  }
}

__global__ void final_kernel(const float* __restrict__ slots, float* __restrict__ out) {
  if (threadIdx.x == 0 && blockIdx.x == 0) {
    float n = slots[0], dl = slots[1], nn = slots[2], dd = slots[3], nd = slots[4];
    float lr = slots[5] / (float)C_B;
    out[0] = lr + 0.2f * (n + dl) + 0.2f * (nn + dd + nd);
    out[1] = lr;
    out[2] = dl;
    out[3] = n;
  }
}

// ---------------- host ----------------
extern "C" void kernel_launch(void* const* d_in, const int* in_sizes, int n_in,
                              void* d_out, int out_size, void* d_ws, size_t ws_size,
                              hipStream_t stream) {
  (void)in_sizes; (void)n_in; (void)out_size;
  const float* E_u_0   = (const float*)d_in[0];
  const float* E_i_0   = (const float*)d_in[1];
  const float* adjvals = (const float*)d_in[2];
  const float* u_mul_s = (const float*)d_in[3];
  const float* v_mul_s = (const float*)d_in[4];
  const float* ut      = (const float*)d_in[5];
  const float* vt      = (const float*)d_in[6];
  const float* W_nn    = (const float*)d_in[7];
  const float* W_dd    = (const float*)d_in[8];
  const float* W_ng    = (const float*)d_in[9];
  const float* W_dg    = (const float*)d_in[10];
  const float* W_nd    = (const float*)d_in[11];
  const int* adj_rows  = (const int*)d_in[12];
  const int* adj_cols  = (const int*)d_in[13];
  const int* uids      = (const int*)d_in[14];
  const int* iids      = (const int*)d_in[15];
  const int* pos       = (const int*)d_in[16];
  const int* neg       = (const int*)d_in[17];
  float* out = (float*)d_out;

  const size_t NU64 = (size_t)C_NU * 64;
  const size_t NI64 = (size_t)C_NI * 64;
  const size_t B64  = (size_t)C_B * 64;

  float* w = (float*)d_ws;
  float* Eu1 = w; w += NU64;
  float* Ei1 = w; w += NI64;
  u16* Zu  = (u16*)w;            // 4 contiguous bf16 Z buffers; edgesA aliases
  u16* Zdu = Zu + NU64;
  u16* Zi  = Zdu + NU64;
  u16* Zdi = Zi + NI64;
  w += 2 * NU64;                 // 4 * NU64 u16 = 2 * NU64 floats
  float* Mu = w; w += 512;
  float* Mi = w; w += 512;
  u16* normbuf16 = (u16*)w; w += 6 * B64;     // 12 bf16 buffers of B64
  float* slots = w; w += 16;
  uint2* edgesB = (uint2*)w; w += 4 * C_NE;   // 32 MB final CSR (both dirs)
  u16* hyper16 = (u16*)edgesB;                // alias: edgesB dead before hyper
  u16* Wt16 = (u16*)w; w += 16384;
  uint32_t* cntA = (uint32_t*)w; w += NCB * NCHK * 2;
  uint32_t* offs = (uint32_t*)w; w += NCB * NCHK * 2;
  uint32_t* bsumA = (uint32_t*)w; w += NCB;
  uint32_t* boffA = (uint32_t*)w; w += NCB;
  uint32_t* startsAbs = (uint32_t*)w; w += 2 * (NROW + 1);
  u8* Eu0f = (u8*)w; w += NU64 / 4;           // fp8 gather tables
  u8* Ei0f = (u8*)w; w += NI64 / 4;
  u8* Eu1f = (u8*)w; w += NU64 / 4;
  u8* Ei1f = Ei0f;                            // alias: Ei0f dead after l0-dir0
  uint2* edgesA = (uint2*)Zu;                 // 32 MB coarse buffer (< Zu..Zi)
  if ((size_t)((char*)w - (char*)d_ws) > ws_size) return;

  // ---- host-side JAX key derivation (partitionable threefry) ----
  auto ksplit = [](uint32_t a, uint32_t b, uint32_t idx, uint32_t& o0, uint32_t& o1) {
    uint32_t x0 = 0u, x1 = idx;
    tf2x32(a, b, x0, x1);
    o0 = x0; o1 = x1;
  };
  uint32_t rk0 = 0u, rk1 = 42u;
  uint32_t lk[2][4][2];
  for (int l = 0; l < 2; ++l) {
    uint32_t n0, n1;
    ksplit(rk0, rk1, 0u, n0, n1);
    for (int i = 0; i < 4; ++i) ksplit(rk0, rk1, (uint32_t)(i + 1), lk[l][i][0], lk[l][i][1]);
    rk0 = n0; rk1 = n1;
  }
  NceKeys nk;
  {
    uint32_t mk0 = 0u, mk1 = 7u;
    for (int i = 0; i < 16; ++i) {
      uint32_t n0, n1;
      ksplit(mk0, mk1, 0u, n0, n1);
      ksplit(mk0, mk1, 1u, nk.k0[i], nk.k1[i]);
      mk0 = n0; mk1 = n1;
    }
  }
  DropKeys dk;
  dk.a[0] = lk[0][0][0]; dk.a[1] = lk[0][0][1];
  dk.a[2] = lk[1][0][0]; dk.a[3] = lk[1][0][1];
  dk.a[4] = lk[0][1][0]; dk.a[5] = lk[0][1][1];
  dk.a[6] = lk[1][1][0]; dk.a[7] = lk[1][1][1];
  WPtrs wp;
  wp.W[0] = W_ng; wp.W[1] = W_ng + 4096;
  wp.W[2] = W_nn;
  wp.W[3] = W_dg; wp.W[4] = W_dg + 4096;
  wp.W[5] = W_dd;
  wp.W[6] = W_nd; wp.W[7] = W_nd + 4096;

  // ---- sort + preps ----
  hipMemsetAsync(slots, 0, 16 * 4, stream);
  passA_hist<<<dim3(NCHK, 2), 256, 0, stream>>>(adj_rows, adj_cols, cntA);
  scanA1<<<NCB, 512, 0, stream>>>(cntA, offs, bsumA);
  scanA2<<<1, 256, 0, stream>>>(bsumA, boffA);
  scanA3<<<NCB, 512, 0, stream>>>(offs, boffA);
  passA_scatter<<<dim3(NCHK, 2), 256, 0, stream>>>(
      adj_rows, adj_cols, adjvals, offs, edgesA, dk);
  passB_kernel<<<dim3(NCB, 2), 512, 0, stream>>>(edgesA, offs, edgesB, startsAbs);
  fp8_convert<<<(int)(NU64 / 4 + 255) / 256, 256, 0, stream>>>(E_u_0, Eu0f, (int)(NU64 / 4));
  fp8_convert<<<(int)(NI64 / 4 + 255) / 256, 256, 0, stream>>>(E_i_0, Ei0f, (int)(NI64 / 4));
  w16_prep<<<(8 * 4096 + 255) / 256, 256, 0, stream>>>(wp, Wt16);

  const int gb = (int)(B64 / 256);  // 1024
  const int sb = (NROW + 3) / 4;    // 25000 blocks, 4 waves each

  for (int l = 0; l < 2; ++l) {
    hipMemsetAsync(Mu, 0, 1024 * 4, stream);  // Mu+Mi contiguous
    svd_reduce2<<<dim3(1024, 2), 256, 0, stream>>>(
        vt, (l == 0) ? E_i_0 : Ei1, ut, (l == 0) ? E_u_0 : Eu1, Mu, Mi);
    // dir0: items -> users (noise key k3)
    spmm_row<<<sb, 256, 0, stream>>>(
        edgesB, startsAbs, (l == 0) ? Ei0f : Ei1f,
        (l == 0) ? E_u_0 : nullptr, (l == 0) ? Eu1 : nullptr,
        (l == 0) ? Eu1f : nullptr, Zu, Zdu, lk[l][2][0], lk[l][2][1], l);
    // dir1: users -> items (noise key k4)
    spmm_row<<<sb, 256, 0, stream>>>(
        edgesB, startsAbs + (NROW + 1), (l == 0) ? Eu0f : Eu1f,
        (l == 0) ? E_i_0 : nullptr, (l == 0) ? Ei1 : nullptr,
        (l == 0) ? Ei1f : nullptr, Zi, Zdi, lk[l][3][0], lk[l][3][1], l);
    gather_norm<<<dim3(gb, 3), 256, 0, stream>>>(
        uids, Zu, Zdu, u_mul_s, Mu,
        normbuf16 + (size_t)(0 + l) * B64, normbuf16 + (size_t)(4 + l) * B64,
        normbuf16 + (size_t)(8 + l) * B64);
    gather_norm<<<dim3(gb, 3), 256, 0, stream>>>(
        iids, Zi, Zdi, v_mul_s, Mi,
        normbuf16 + (size_t)(2 + l) * B64, normbuf16 + (size_t)(6 + l) * B64,
        normbuf16 + (size_t)(10 + l) * B64);
  }

  hyper_mfma<<<dim3(C_B / 64, 16), 256, 0, stream>>>(normbuf16, Wt16, hyper16);
  nce_mfma<<<dim3(C_B / 128, 16), 256, 0, stream>>>(normbuf16, hyper16, slots, nk);
  loss_r_kernel<<<gb, 256, 0, stream>>>(E_u_0, Eu1, Zu, Zdu, E_i_0, Ei1, Zi, Zdi,
                                        uids, pos, neg, slots);
  final_kernel<<<1, 1, 0, stream>>>(slots, out);
}

// Round 10
// 655.203 us; speedup vs baseline: 12.9735x; 1.0487x over previous
//
#include <hip/hip_runtime.h>
#include <hip/hip_bf16.h>
#include <cstdint>

#define C_NU 100000
#define C_NI 100000
#define C_DIM 64
#define C_Q 5
#define C_NE 2000000
#define C_B 4096
#define C_P 10
#define NROW 100000
#define NCB 196      // coarse buckets of 512 rows
#define NCHK 256     // chunks in pass A
#define CHUNK 7813   // ceil(2M/256)

typedef unsigned short u16;
typedef unsigned char u8;
typedef __attribute__((ext_vector_type(8))) short short8;
typedef __attribute__((ext_vector_type(4))) float f32x4;

__device__ static inline int rfl(int v) { return __builtin_amdgcn_readfirstlane(v); }
__device__ static inline uint32_t rflu(uint32_t v) {
  return (uint32_t)__builtin_amdgcn_readfirstlane((int)v);
}

// ---------------- Threefry-2x32 (JAX-compatible), 20 rounds ----------------
__host__ __device__ static inline void tf2x32(uint32_t k0, uint32_t k1,
                                              uint32_t& x0, uint32_t& x1) {
  uint32_t k2 = k0 ^ k1 ^ 0x1BD11BDAu;
#define TFR(r) { x0 += x1; x1 = (x1 << r) | (x1 >> (32 - r)); x1 ^= x0; }
  x0 += k0; x1 += k1;
  TFR(13) TFR(15) TFR(26) TFR(6)
  x0 += k1; x1 += k2 + 1u;
  TFR(17) TFR(29) TFR(16) TFR(24)
  x0 += k2; x1 += k0 + 2u;
  TFR(13) TFR(15) TFR(26) TFR(6)
  x0 += k0; x1 += k1 + 3u;
  TFR(17) TFR(29) TFR(16) TFR(24)
  x0 += k1; x1 += k2 + 4u;
  TFR(13) TFR(15) TFR(26) TFR(6)
  x0 += k2; x1 += k0 + 5u;
#undef TFR
}

// partitionable-mode random bits at flat index idx (hi counter = 0)
__device__ static inline float tf_uniform(uint32_t k0, uint32_t k1, uint32_t idx) {
  uint32_t x0 = 0u, x1 = idx;
  tf2x32(k0, k1, x0, x1);
  uint32_t bits = x0 ^ x1;
  return __uint_as_float((bits >> 9) | 0x3F800000u) - 1.0f;
}

__device__ static inline float leaky(float x) { return x >= 0.f ? x : 0.5f * x; }

__device__ static inline u16 f2bf(float f) {  // RNE fp32->bf16
  uint32_t x = __float_as_uint(f);
  return (u16)((x + 0x7FFFu + ((x >> 16) & 1u)) >> 16);
}
__device__ static inline float bf2f(u16 u) {
  return __uint_as_float((uint32_t)u << 16);
}

// fp8 store: byte = sign | 7-bit (4-exp,3-mant) of (x*256), RNE, underflow->0.
// decode: val = as_float(((b&0x80)<<24)|((b&0x7F)<<20)) * 2^120; x = val*2^-8.
__device__ static inline u8 f2fp8(float x) {
  float t = x * 256.f;
  uint32_t sgn = (__float_as_uint(t) >> 24) & 0x80u;
  float a = fabsf(t) * 0x1p-120f;
  uint32_t u = __float_as_uint(a);
  u += 0x7FFFFu + ((u >> 20) & 1u);
  uint32_t mag = u >> 20;
  if (mag > 0x7Fu) mag = 0x7Fu;
  return (u8)(sgn | mag);
}

// ---------------- constant maps for the 16 info_nce calls ----------------
// normbuf slots: 0:Zu1 1:Zu2 2:Zi1 3:Zi2 4:Zdu1 5:Zdu2 6:Zdi1 7:Zdi2 8:Gu1 9:Gu2 10:Gi1 11:Gi2
__constant__ int c_gsel[16] = {0,1,2,3, 0,2, 4,5,6,7, 4,6, 0,1,2,3};
__constant__ int c_hsrc[16] = {8,9,10,11, 1,3, 8,9,10,11, 5,7, 4,5,6,7};
// W order: 0:ng0 1:ng1 2:nn 3:dg0 4:dg1 5:dd 6:nd0 7:nd1
__constant__ int c_wsel[16] = {0,1,0,1, 2,2, 3,4,3,4, 5,5, 6,7,6,7};
// slots: 0:n 1:d 2:nn 3:dd 4:nd (5: loss_r sum)
__constant__ int c_slot[16] = {0,0,0,0, 2,2, 1,1,1,1, 3,3, 4,4,4,4};

struct WPtrs { const float* W[8]; };
struct NceKeys { uint32_t k0[16]; uint32_t k1[16]; };
struct DropKeys { uint32_t a[8]; };

// ---------------- two-level counting sort ----------------

__global__ __launch_bounds__(256) void passA_hist(
    const int* __restrict__ rows, const int* __restrict__ cols,
    uint32_t* __restrict__ cntA) {
  __shared__ uint32_t h[NCB];
  const int dir = blockIdx.y, c = blockIdx.x, t = threadIdx.x;
  for (int i = t; i < NCB; i += 256) h[i] = 0u;
  __syncthreads();
  const int e0 = c * CHUNK, e1 = min(e0 + CHUNK, C_NE);
  const int* ids = dir ? cols : rows;
  for (int e = e0 + t; e < e1; e += 256) atomicAdd(&h[ids[e] >> 9], 1u);
  __syncthreads();
  for (int i = t; i < NCB; i += 256) cntA[(dir * NCB + i) * NCHK + c] = h[i];
}

__global__ __launch_bounds__(512) void scanA1(
    const uint32_t* __restrict__ cntA, uint32_t* __restrict__ offs,
    uint32_t* __restrict__ bsum) {
  __shared__ uint32_t s[512];
  const int b = blockIdx.x, t = threadIdx.x;
  const int idx = b * 512 + t;
  uint32_t v = cntA[idx];
  s[t] = v;
  __syncthreads();
  for (int off = 1; off < 512; off <<= 1) {
    uint32_t a = (t >= off) ? s[t - off] : 0u;
    __syncthreads();
    s[t] += a;
    __syncthreads();
  }
  offs[idx] = s[t] - v;
  if (t == 511) bsum[b] = s[511];
}

__global__ __launch_bounds__(256) void scanA2(
    const uint32_t* __restrict__ bsum, uint32_t* __restrict__ boff) {
  __shared__ uint32_t s[256];
  const int t = threadIdx.x;
  uint32_t v = (t < NCB) ? bsum[t] : 0u;
  s[t] = v;
  __syncthreads();
  for (int off = 1; off < 256; off <<= 1) {
    uint32_t a = (t >= off) ? s[t - off] : 0u;
    __syncthreads();
    s[t] += a;
    __syncthreads();
  }
  if (t < NCB) boff[t] = s[t] - v;
}

__global__ __launch_bounds__(512) void scanA3(
    uint32_t* __restrict__ offs, const uint32_t* __restrict__ boff) {
  offs[blockIdx.x * 512 + threadIdx.x] += boff[blockIdx.x];
}

// record.x = src(17b) | keepL0<<17 | keepL1<<18 | (dst&511)<<19
__global__ __launch_bounds__(256) void passA_scatter(
    const int* __restrict__ rows, const int* __restrict__ cols,
    const float* __restrict__ vals, const uint32_t* __restrict__ offs,
    uint2* __restrict__ edgesA, DropKeys dk) {
  __shared__ uint32_t lofs[NCB];
  const int dir = blockIdx.y, c = blockIdx.x, t = threadIdx.x;
  for (int i = t; i < NCB; i += 256) lofs[i] = offs[(dir * NCB + i) * NCHK + c];
  __syncthreads();
  const int e0 = c * CHUNK, e1 = min(e0 + CHUNK, C_NE);
  const uint32_t kA0 = dk.a[dir * 4 + 0], kA1 = dk.a[dir * 4 + 1];
  const uint32_t kB0 = dk.a[dir * 4 + 2], kB1 = dk.a[dir * 4 + 3];
  for (int e = e0 + t; e < e1; e += 256) {
    const int r = rows[e], cc = cols[e];
    const int dst = dir ? cc : r, src = dir ? r : cc;
    const uint32_t kl0 = (tf_uniform(kA0, kA1, (uint32_t)e) < 0.9f) ? 1u : 0u;
    const uint32_t kl1 = (tf_uniform(kB0, kB1, (uint32_t)e) < 0.9f) ? 1u : 0u;
    const uint32_t x = (uint32_t)src | (kl0 << 17) | (kl1 << 18) |
                       ((uint32_t)(dst & 511) << 19);
    const uint32_t pos = atomicAdd(&lofs[dst >> 9], 1u);
    edgesA[pos] = make_uint2(x, __float_as_uint(vals[e]));
  }
}

__global__ __launch_bounds__(512) void passB_kernel(
    const uint2* __restrict__ edgesA, const uint32_t* __restrict__ offs,
    uint2* __restrict__ edgesB, uint32_t* __restrict__ starts) {
  __shared__ uint32_t cnt[512];
  __shared__ uint32_t scn[512];
  const int dir = blockIdx.y, cb = blockIdx.x, t = threadIdx.x;
  const uint32_t segStart = offs[(dir * NCB + cb) * NCHK];
  const uint32_t segEnd = (dir == 1 && cb == NCB - 1)
                              ? (uint32_t)(2 * C_NE)
                              : offs[(dir * NCB + cb + 1) * NCHK];
  cnt[t] = 0u;
  __syncthreads();
  for (uint32_t e = segStart + t; e < segEnd; e += 512)
    atomicAdd(&cnt[(edgesA[e].x >> 19) & 511u], 1u);
  __syncthreads();
  uint32_t v = cnt[t];
  scn[t] = v;
  __syncthreads();
  for (int off = 1; off < 512; off <<= 1) {
    uint32_t a = (t >= off) ? scn[t - off] : 0u;
    __syncthreads();
    scn[t] += a;
    __syncthreads();
  }
  const uint32_t rstart = segStart + scn[t] - v;
  const int grow = cb * 512 + t;
  if (grow < NROW) starts[dir * (NROW + 1) + grow] = rstart;
  if (cb == NCB - 1 && t == 0) starts[dir * (NROW + 1) + NROW] = segEnd;
  cnt[t] = rstart;
  __syncthreads();
  for (uint32_t e = segStart + t; e < segEnd; e += 512) {
    const uint2 q = edgesA[e];
    const uint32_t pos = atomicAdd(&cnt[(q.x >> 19) & 511u], 1u);
    edgesB[pos] = q;
  }
}

// ---------------- fp32 -> fp8 table convert ----------------
__global__ __launch_bounds__(256) void fp8_convert(
    const float* __restrict__ src, u8* __restrict__ dst, int n4) {
  int i = blockIdx.x * 256 + threadIdx.x;
  if (i >= n4) return;
  float4 v = ((const float4*)src)[i];
  uint32_t o = (uint32_t)f2fp8(v.x) | ((uint32_t)f2fp8(v.y) << 8) |
               ((uint32_t)f2fp8(v.z) << 16) | ((uint32_t)f2fp8(v.w) << 24);
  ((uint32_t*)dst)[i] = o;
}

// Wt16[w][d][k] = bf16(W[w][k][d])  (pre-transposed for MFMA B-operand)
__global__ __launch_bounds__(256) void w16_prep(WPtrs wp, u16* __restrict__ Wt16) {
  int i = blockIdx.x * 256 + threadIdx.x;
  if (i >= 8 * 4096) return;
  int w = i >> 12, kd = i & 4095, k = kd >> 6, d = kd & 63;
  Wt16[w * 4096 + d * 64 + k] = f2bf(wp.W[w][k * 64 + d]);
}

// ---------------- fused spmm (wave/row, scalarized, fp8 gathers) ----------------
__global__ __launch_bounds__(256) void spmm_row(
    const uint2* __restrict__ edges, const uint32_t* __restrict__ starts,
    const u8* __restrict__ Einf, const float* __restrict__ Eprev,
    float* __restrict__ Enext, u8* __restrict__ Enf8,
    u16* __restrict__ Zout, u16* __restrict__ Zdout,
    uint32_t nk0, uint32_t nk1, int layer) {
  const int row = rfl(blockIdx.x * 4 + (threadIdx.x >> 6));
  const int lane = threadIdx.x & 63;
  if (row >= NROW) return;
  const uint32_t s0 = rflu(starts[row]);
  const uint32_t s1 = rflu(starts[row + 1]);
  const uint32_t kbit = 1u << (17 + layer);
  const float VS = 0x1p112f;  // fp8 decode scale (2^120) * table scale (2^-8)
  float z = 0.f, zd = 0.f;
  uint32_t e = s0;
  for (; e + 4 <= s1; e += 4) {
    const uint32_t p0 = rflu(edges[e].x),     w0 = rflu(edges[e].y);
    const uint32_t p1 = rflu(edges[e + 1].x), w1 = rflu(edges[e + 1].y);
    const uint32_t p2 = rflu(edges[e + 2].x), w2 = rflu(edges[e + 2].y);
    const uint32_t p3 = rflu(edges[e + 3].x), w3 = rflu(edges[e + 3].y);
    const uint32_t b0 = Einf[(size_t)(p0 & 0x1FFFFu) * 64 + lane];
    const uint32_t b1 = Einf[(size_t)(p1 & 0x1FFFFu) * 64 + lane];
    const uint32_t b2 = Einf[(size_t)(p2 & 0x1FFFFu) * 64 + lane];
    const uint32_t b3 = Einf[(size_t)(p3 & 0x1FFFFu) * 64 + lane];
    const float x0 = __uint_as_float(((b0 & 0x80u) << 24) | ((b0 & 0x7Fu) << 20));
    const float x1 = __uint_as_float(((b1 & 0x80u) << 24) | ((b1 & 0x7Fu) << 20));
    const float x2 = __uint_as_float(((b2 & 0x80u) << 24) | ((b2 & 0x7Fu) << 20));
    const float x3 = __uint_as_float(((b3 & 0x80u) << 24) | ((b3 & 0x7Fu) << 20));
    const float v0 = __uint_as_float(w0) * VS, v1 = __uint_as_float(w1) * VS;
    const float v2 = __uint_as_float(w2) * VS, v3 = __uint_as_float(w3) * VS;
    const float d0 = (p0 & kbit) ? v0 : 0.f;
    const float d1 = (p1 & kbit) ? v1 : 0.f;
    const float d2 = (p2 & kbit) ? v2 : 0.f;
    const float d3 = (p3 & kbit) ? v3 : 0.f;
    z += v0 * x0; zd += d0 * x0;
    z += v1 * x1; zd += d1 * x1;
    z += v2 * x2; zd += d2 * x2;
    z += v3 * x3; zd += d3 * x3;
  }
  for (; e < s1; ++e) {
    const uint32_t p = rflu(edges[e].x), wv = rflu(edges[e].y);
    const uint32_t b = Einf[(size_t)(p & 0x1FFFFu) * 64 + lane];
    const float x = __uint_as_float(((b & 0x80u) << 24) | ((b & 0x7Fu) << 20));
    const float v = __uint_as_float(wv) * VS;
    z += v * x;
    zd += ((p & kbit) ? v : 0.f) * x;
  }
  z = leaky(z);
  zd = leaky(zd * (1.0f / 0.9f));
  // noise-augmented view
  const float u = tf_uniform(nk0, nk1, (uint32_t)row * 64u + (uint32_t)lane);
  float ss = u * u;
#pragma unroll
  for (int off = 1; off < 64; off <<= 1) ss += __shfl_xor(ss, off);
  const float nrm = fmaxf(sqrtf(ss), 1e-12f);
  const float sg = (z > 0.f) ? 1.f : (z < 0.f ? -1.f : 0.f);
  z += sg * (u / nrm) * 0.1f;
  const size_t j = (size_t)row * 64 + lane;
  Zout[j] = f2bf(z);
  Zdout[j] = f2bf(zd);
  if (Enext) {  // layer 0 only: materialize E1 (fp32 + fp8 for next-layer gathers)
    const float en = z + zd + Eprev[j];
    Enext[j] = en;
    Enf8[j] = f2fp8(en);
  }
}

// ---------------- dual-dir SVD middle matrix, block-reduced atomics ----------------
__global__ __launch_bounds__(256) void svd_reduce2(
    const float* __restrict__ T0, const float* __restrict__ E0,
    const float* __restrict__ T1, const float* __restrict__ E1,
    float* __restrict__ Mu, float* __restrict__ Mi) {
  const int dir = blockIdx.y;
  const float* __restrict__ T = dir ? T1 : T0;
  const float* __restrict__ E = dir ? E1 : E0;
  float* __restrict__ M = dir ? Mi : Mu;
  const int lane = threadIdx.x & 63;
  const int wl = threadIdx.x >> 6;
  const int gw = blockIdx.x * 4 + wl;
  float a0 = 0.f, a1 = 0.f, a2 = 0.f, a3 = 0.f, a4 = 0.f;
  for (int i = gw; i < NROW; i += 4096) {
    const float x = E[(size_t)i * 64 + lane];
    a0 += T[i] * x;
    a1 += T[NROW + i] * x;
    a2 += T[2 * NROW + i] * x;
    a3 += T[3 * NROW + i] * x;
    a4 += T[4 * NROW + i] * x;
  }
  __shared__ float red[4][5][64];
  red[wl][0][lane] = a0; red[wl][1][lane] = a1; red[wl][2][lane] = a2;
  red[wl][3][lane] = a3; red[wl][4][lane] = a4;
  __syncthreads();
  for (int o = threadIdx.x; o < 320; o += 256) {
    const int q = o >> 6, d = o & 63;
    const float s = red[0][q][d] + red[1][q][d] + red[2][q][d] + red[3][q][d];
    atomicAdd(&M[o], s);
  }
}

// gather batch rows & L2-normalize -> bf16; blockIdx.y selects {Z, Zd, G}
__global__ __launch_bounds__(256) void gather_norm(
    const int* __restrict__ ids, const u16* __restrict__ Z,
    const u16* __restrict__ Zd, const float* __restrict__ mul_s,
    const float* __restrict__ M, u16* __restrict__ oZ,
    u16* __restrict__ oZd, u16* __restrict__ oG) {
  long long t = (long long)blockIdx.x * blockDim.x + threadIdx.x;
  int b = (int)(t >> 6);
  int d = (int)(t & 63);
  if (b >= C_B) return;
  int id = rfl(ids[b]);
  float v;
  u16* out;
  if (blockIdx.y == 0) { v = bf2f(Z[(size_t)id * 64 + d]); out = oZ; }
  else if (blockIdx.y == 1) { v = bf2f(Zd[(size_t)id * 64 + d]); out = oZd; }
  else {
    float s = 0.f;
#pragma unroll
    for (int q = 0; q < 5; ++q) s += mul_s[(size_t)id * 5 + q] * M[q * 64 + d];
    v = leaky(s);
    out = oG;
  }
  float ss = v * v;
#pragma unroll
  for (int off = 1; off < 64; off <<= 1) ss += __shfl_xor(ss, off);
  float nrm = fmaxf(sqrtf(ss), 1e-12f);
  out[(size_t)b * 64 + d] = f2bf(v / nrm);
}

// ---------------- MFMA hyper: hy[call] = (normbuf[hsrc] @ W[wsel]) * log2e/TEMP --
__global__ __launch_bounds__(256) void hyper_mfma(
    const u16* __restrict__ nb, const u16* __restrict__ Wt16,
    u16* __restrict__ hy) {
  const int call = blockIdx.y;
  const int b0 = blockIdx.x * 64;
  __shared__ u16 Xs[64 * 64];
  __shared__ u16 Ws[64 * 64];
  const int tid = threadIdx.x, lane = tid & 63, wid = tid >> 6;
  const u16* X = nb + (size_t)c_hsrc[call] * C_B * 64;
  const u16* Wt = Wt16 + (size_t)c_wsel[call] * 4096;
  {
    const int r = tid >> 2, seg = tid & 3;
    const int base = r * 128 + seg * 32, sw = (r & 7) << 4;
    const uint4* sx = (const uint4*)&X[(size_t)(b0 + r) * 64 + seg * 16];
    uint4 a = sx[0], b = sx[1];
    *(uint4*)((char*)Xs + (base ^ sw)) = a;
    *(uint4*)((char*)Xs + ((base + 16) ^ sw)) = b;
    const uint4* sv = (const uint4*)&Wt[r * 64 + seg * 16];
    uint4 c = sv[0], d = sv[1];
    *(uint4*)((char*)Ws + (base ^ sw)) = c;
    *(uint4*)((char*)Ws + ((base + 16) ^ sw)) = d;
  }
  __syncthreads();
  const int am = (wid << 4) + (lane & 15);
  short8 af[2];
#pragma unroll
  for (int ks = 0; ks < 2; ++ks) {
    const int off = (am * 128 + ks * 64 + ((lane >> 4) << 4)) ^ ((am & 7) << 4);
    af[ks] = *(const short8*)((const char*)Xs + off);
  }
  const int ob = b0 + (wid << 4) + ((lane >> 4) << 2);
#pragma unroll
  for (int n = 0; n < 4; ++n) {
    const int bn = (n << 4) + (lane & 15);
    f32x4 acc = {0.f, 0.f, 0.f, 0.f};
#pragma unroll
    for (int ks = 0; ks < 2; ++ks) {
      const int off = (bn * 128 + ks * 64 + ((lane >> 4) << 4)) ^ ((bn & 7) << 4);
      short8 bf = *(const short8*)((const char*)Ws + off);
      acc = __builtin_amdgcn_mfma_f32_16x16x32_bf16(af[ks], bf, acc, 0, 0, 0);
    }
    const int d = (n << 4) + (lane & 15);
#pragma unroll
    for (int j = 0; j < 4; ++j)
      hy[(size_t)call * C_B * 64 + (size_t)(ob + j) * 64 + d] =
          f2bf(acc[j] * 7.2134752f);  // fold log2(e)/TEMP into H
  }
}

// ---------------- MFMA info_nce partials: 128 g-rows x 16 H-tiles per block ----
// grid: (32 g-tiles, 4 jt-chunks, 16 calls)
__global__ __launch_bounds__(256) void nce_partial(
    const u16* __restrict__ nb, const u16* __restrict__ hy,
    float* __restrict__ rsbuf, float* __restrict__ psbuf) {
  const int call = blockIdx.z;
  const int jc = blockIdx.y;
  const u16* G = nb + (size_t)c_gsel[call] * C_B * 64;
  const u16* H = hy + (size_t)call * C_B * 64;
  const int br = blockIdx.x * 128;
  const int jt0 = jc * 16;
  __shared__ u16 Gs[128 * 64];
  __shared__ u16 Hs[2][64 * 64];
  const int tid = threadIdx.x, lane = tid & 63, wid = tid >> 6;
  // stage G tile (128 rows), swizzled
  {
    const int r2 = tid >> 1;
    const int sw2 = (r2 & 7) << 4;
#pragma unroll
    for (int p = 0; p < 2; ++p) {
      const int sg = (tid & 1) + p * 2;
      const uint4* src = (const uint4*)&G[(size_t)(br + r2) * 64 + sg * 16];
      uint4 a = src[0], b = src[1];
      const int bse = r2 * 128 + sg * 32;
      *(uint4*)((char*)Gs + (bse ^ sw2)) = a;
      *(uint4*)((char*)Gs + ((bse + 16) ^ sw2)) = b;
    }
  }
  const int r = tid >> 2, seg = tid & 3;
  const int base = r * 128 + seg * 32, sw = (r & 7) << 4;
  {
    const uint4* src = (const uint4*)&H[(size_t)(jt0 * 64 + r) * 64 + seg * 16];
    uint4 a = src[0], b = src[1];
    *(uint4*)((char*)Hs[0] + (base ^ sw)) = a;
    *(uint4*)((char*)Hs[0] + ((base + 16) ^ sw)) = b;
  }
  float rs[2] = {0.f, 0.f}, ps[2] = {0.f, 0.f};
  short8 bfG[2][2];
  const int jt_diag = (blockIdx.x << 1) + (wid >> 1);
  const int hsd0 = (wid & 1) << 1;
  int cur = 0;
  for (int jt = jt0; jt < jt0 + 16; ++jt) {
    __syncthreads();  // Hs[cur] (and Gs on first iter) ready
    if (jt == jt0) {
#pragma unroll
      for (int s = 0; s < 2; ++s)
#pragma unroll
        for (int ks = 0; ks < 2; ++ks) {
          const int gc = (wid << 5) + (s << 4) + (lane & 15);
          const int off = (gc * 128 + ks * 64 + ((lane >> 4) << 4)) ^ ((gc & 7) << 4);
          bfG[s][ks] = *(const short8*)((const char*)Gs + off);
        }
    }
    uint4 na, nb_;
    if (jt + 1 < jt0 + 16) {  // prefetch next H tile
      const uint4* src = (const uint4*)&H[(size_t)((jt + 1) * 64 + r) * 64 + seg * 16];
      na = src[0]; nb_ = src[1];
    }
    const bool dj = (jt == jt_diag);
    const char* Hb = (const char*)(Hs[cur]);
#pragma unroll
    for (int hs = 0; hs < 4; ++hs) {
      const int hr = (hs << 4) + (lane & 15);
      const int offA0 = (hr * 128 + ((lane >> 4) << 4)) ^ ((hr & 7) << 4);
      const int offA1 = (hr * 128 + 64 + ((lane >> 4) << 4)) ^ ((hr & 7) << 4);
      const short8 af0 = *(const short8*)(Hb + offA0);
      const short8 af1 = *(const short8*)(Hb + offA1);
      f32x4 acc0 = {0.f, 0.f, 0.f, 0.f}, acc1 = {0.f, 0.f, 0.f, 0.f};
      __builtin_amdgcn_s_setprio(1);
      acc0 = __builtin_amdgcn_mfma_f32_16x16x32_bf16(af0, bfG[0][0], acc0, 0, 0, 0);
      acc0 = __builtin_amdgcn_mfma_f32_16x16x32_bf16(af1, bfG[0][1], acc0, 0, 0, 0);
      acc1 = __builtin_amdgcn_mfma_f32_16x16x32_bf16(af0, bfG[1][0], acc1, 0, 0, 0);
      acc1 = __builtin_amdgcn_mfma_f32_16x16x32_bf16(af1, bfG[1][1], acc1, 0, 0, 0);
      __builtin_amdgcn_s_setprio(0);
      float e0[4], e1[4];
#pragma unroll
      for (int j = 0; j < 4; ++j) {
        e0[j] = exp2f(acc0[j]);  // H pre-scaled by log2e/TEMP
        e1[j] = exp2f(acc1[j]);
      }
      rs[0] += (e0[0] + e0[1]) + (e0[2] + e0[3]);
      rs[1] += (e1[0] + e1[1]) + (e1[2] + e1[3]);
      if (dj) {
        const int jm = (lane & 15) - ((lane >> 4) << 2);
        if (hs == hsd0) {
#pragma unroll
          for (int j = 0; j < 4; ++j)
            if (jm == j) ps[0] = e0[j];
        }
        if (hs == hsd0 + 1) {
#pragma unroll
          for (int j = 0; j < 4; ++j)
            if (jm == j) ps[1] = e1[j];
        }
      }
    }
    if (jt + 1 < jt0 + 16) {
      *(uint4*)((char*)Hs[cur ^ 1] + (base ^ sw)) = na;
      *(uint4*)((char*)Hs[cur ^ 1] + ((base + 16) ^ sw)) = nb_;
    }
    cur ^= 1;
  }
#pragma unroll
  for (int s = 0; s < 2; ++s) {
    rs[s] += __shfl_xor(rs[s], 16); rs[s] += __shfl_xor(rs[s], 32);
    ps[s] += __shfl_xor(ps[s], 16); ps[s] += __shfl_xor(ps[s], 32);
  }
  if ((lane >> 4) == 0) {
    const bool own_diag = ((jt_diag >> 4) == jc);  // wave-uniform
#pragma unroll
    for (int s = 0; s < 2; ++s) {
      const int gg = br + (wid << 5) + (s << 4) + (lane & 15);
      atomicAdd(&rsbuf[(size_t)call * C_B + gg], rs[s]);
      if (own_diag) psbuf[(size_t)call * C_B + gg] = ps[s];
    }
  }
}

// finalize: v = -log(ps/(rs+eps)+eps), mask, reduce to slots
__global__ __launch_bounds__(256) void nce_final(
    const float* __restrict__ rsbuf, const float* __restrict__ psbuf,
    float* __restrict__ slots, NceKeys nk) {
  const int call = blockIdx.y;
  const int g = blockIdx.x * 256 + threadIdx.x;
  const float rs = rsbuf[(size_t)call * C_B + g];
  const float ps = psbuf[(size_t)call * C_B + g];
  const float v = -__logf(ps / (rs + 1e-8f) + 1e-8f);
  const float u = tf_uniform(nk.k0[call], nk.k1[call], (uint32_t)g);
  float c = (u > 0.5f) ? v : 0.f;
#pragma unroll
  for (int off = 1; off < 64; off <<= 1) c += __shfl_xor(c, off);
  __shared__ float wsum[4];
  if ((threadIdx.x & 63) == 0) wsum[threadIdx.x >> 6] = c;
  __syncthreads();
  if (threadIdx.x == 0)
    atomicAdd(&slots[c_slot[call]], wsum[0] + wsum[1] + wsum[2] + wsum[3]);
}

// E_sum = E0 + 2*E1 + Z2 + Zd2  (E2 never materialized; Z in bf16)
__global__ __launch_bounds__(256) void loss_r_kernel(
    const float* __restrict__ E0u, const float* __restrict__ Eu1,
    const u16* __restrict__ Zu, const u16* __restrict__ Zdu,
    const float* __restrict__ E0i, const float* __restrict__ Ei1,
    const u16* __restrict__ Zi, const u16* __restrict__ Zdi,
    const int* __restrict__ uids, const int* __restrict__ pos,
    const int* __restrict__ neg, float* __restrict__ slots) {
  long long t = (long long)blockIdx.x * blockDim.x + threadIdx.x;
  int b = (int)(t >> 6);
  int d = (int)(t & 63);
  if (b >= C_B) return;
  size_t ju = (size_t)rfl(uids[b]) * 64 + d;
  float u = E0u[ju] + 2.f * Eu1[ju] + bf2f(Zu[ju]) + bf2f(Zdu[ju]);
  float bpr = 0.f, pmin = 3.4e38f, nmax = -3.4e38f;
  for (int p = 0; p < C_P; ++p) {
    size_t jp = (size_t)rfl(pos[b * C_P + p]) * 64 + d;
    size_t jn = (size_t)rfl(neg[b * C_P + p]) * 64 + d;
    float pe = E0i[jp] + 2.f * Ei1[jp] + bf2f(Zi[jp]) + bf2f(Zdi[jp]);
    float ne = E0i[jn] + 2.f * Ei1[jn] + bf2f(Zi[jn]) + bf2f(Zdi[jn]);
    float psc = u * pe, nsc = u * ne;
#pragma unroll
    for (int off = 1; off < 64; off <<= 1) {
      psc += __shfl_xor(psc, off);
      nsc += __shfl_xor(nsc, off);
    }
    pmin = fminf(pmin, psc);
    nmax = fmaxf(nmax, nsc);
    bpr += fmaxf(1.f - psc + nsc, 0.f);
  }
  if (d == 0) {
    float hd = (nmax - pmin > 0.005f) ? 10.f * (nmax - pmin) : 0.f;
    atomicAdd(&slots[5], bpr + hd);
  }
}

__global__ void final_kernel(const float* __restrict__ slots, float* __restrict__ out) {
  if (threadIdx.x == 0 && blockIdx.x == 0) {
    float n = slots[0], dl = slots[1], nn = slots[2], dd = slots[3], nd = slots[4];
    float lr = slots[5] / (float)C_B;
    out[0] = lr + 0.2f * (n + dl) + 0.2f * (nn + dd + nd);
    out[1] = lr;
    out[2] = dl;
    out[3] = n;
  }
}

// ---------------- host ----------------
extern "C" void kernel_launch(void* const* d_in, const int* in_sizes, int n_in,
                              void* d_out, int out_size, void* d_ws, size_t ws_size,
                              hipStream_t stream) {
  (void)in_sizes; (void)n_in; (void)out_size;
  const float* E_u_0   = (const float*)d_in[0];
  const float* E_i_0   = (const float*)d_in[1];
  const float* adjvals = (const float*)d_in[2];
  const float* u_mul_s = (const float*)d_in[3];
  const float* v_mul_s = (const float*)d_in[4];
  const float* ut      = (const float*)d_in[5];
  const float* vt      = (const float*)d_in[6];
  const float* W_nn    = (const float*)d_in[7];
  const float* W_dd    = (const float*)d_in[8];
  const float* W_ng    = (const float*)d_in[9];
  const float* W_dg    = (const float*)d_in[10];
  const float* W_nd    = (const float*)d_in[11];
  const int* adj_rows  = (const int*)d_in[12];
  const int* adj_cols  = (const int*)d_in[13];
  const int* uids      = (const int*)d_in[14];
  const int* iids      = (const int*)d_in[15];
  const int* pos       = (const int*)d_in[16];
  const int* neg       = (const int*)d_in[17];
  float* out = (float*)d_out;

  const size_t NU64 = (size_t)C_NU * 64;
  const size_t NI64 = (size_t)C_NI * 64;
  const size_t B64  = (size_t)C_B * 64;

  float* w = (float*)d_ws;
  float* Eu1 = w; w += NU64;
  float* Ei1 = w; w += NI64;
  u16* Zu  = (u16*)w;            // 4 contiguous bf16 Z buffers; edgesA aliases
  u16* Zdu = Zu + NU64;
  u16* Zi  = Zdu + NU64;
  u16* Zdi = Zi + NI64;
  w += 2 * NU64;                 // 4 * NU64 u16 = 2 * NU64 floats
  float* Mu = w; w += 512;
  float* Mi = w; w += 512;
  u16* normbuf16 = (u16*)w; w += 6 * B64;     // 12 bf16 buffers of B64
  float* slots = w; w += 16;
  uint2* edgesB = (uint2*)w; w += 4 * C_NE;   // 32 MB final CSR (both dirs)
  u16* hyper16 = (u16*)edgesB;                // alias: edgesB dead before hyper
  u16* Wt16 = (u16*)w; w += 16384;
  uint32_t* cntA = (uint32_t*)w; w += NCB * NCHK * 2;
  uint32_t* offs = (uint32_t*)w; w += NCB * NCHK * 2;
  uint32_t* bsumA = (uint32_t*)w; w += NCB;
  uint32_t* boffA = (uint32_t*)w; w += NCB;
  uint32_t* startsAbs = (uint32_t*)w; w += 2 * (NROW + 1);
  u8* Eu0f = (u8*)w; w += NU64 / 4;           // fp8 gather tables
  u8* Ei0f = (u8*)w; w += NI64 / 4;
  u8* Eu1f = (u8*)w; w += NU64 / 4;
  u8* Ei1f = Ei0f;                            // alias: Ei0f dead after l0-dir0
  float* rsbuf = w; w += 16 * C_B;            // nce partial denominators
  float* psbuf = w; w += 16 * C_B;            // nce diag numerators
  uint2* edgesA = (uint2*)Zu;                 // 32 MB coarse buffer (< Zu..Zi)
  if ((size_t)((char*)w - (char*)d_ws) > ws_size) return;

  // ---- host-side JAX key derivation (partitionable threefry) ----
  auto ksplit = [](uint32_t a, uint32_t b, uint32_t idx, uint32_t& o0, uint32_t& o1) {
    uint32_t x0 = 0u, x1 = idx;
    tf2x32(a, b, x0, x1);
    o0 = x0; o1 = x1;
  };
  uint32_t rk0 = 0u, rk1 = 42u;
  uint32_t lk[2][4][2];
  for (int l = 0; l < 2; ++l) {
    uint32_t n0, n1;
    ksplit(rk0, rk1, 0u, n0, n1);
    for (int i = 0; i < 4; ++i) ksplit(rk0, rk1, (uint32_t)(i + 1), lk[l][i][0], lk[l][i][1]);
    rk0 = n0; rk1 = n1;
  }
  NceKeys nk;
  {
    uint32_t mk0 = 0u, mk1 = 7u;
    for (int i = 0; i < 16; ++i) {
      uint32_t n0, n1;
      ksplit(mk0, mk1, 0u, n0, n1);
      ksplit(mk0, mk1, 1u, nk.k0[i], nk.k1[i]);
      mk0 = n0; mk1 = n1;
    }
  }
  DropKeys dk;
  dk.a[0] = lk[0][0][0]; dk.a[1] = lk[0][0][1];
  dk.a[2] = lk[1][0][0]; dk.a[3] = lk[1][0][1];
  dk.a[4] = lk[0][1][0]; dk.a[5] = lk[0][1][1];
  dk.a[6] = lk[1][1][0]; dk.a[7] = lk[1][1][1];
  WPtrs wp;
  wp.W[0] = W_ng; wp.W[1] = W_ng + 4096;
  wp.W[2] = W_nn;
  wp.W[3] = W_dg; wp.W[4] = W_dg + 4096;
  wp.W[5] = W_dd;
  wp.W[6] = W_nd; wp.W[7] = W_nd + 4096;

  // ---- sort + preps ----
  hipMemsetAsync(slots, 0, 16 * 4, stream);
  hipMemsetAsync(rsbuf, 0, 16 * C_B * 4, stream);
  passA_hist<<<dim3(NCHK, 2), 256, 0, stream>>>(adj_rows, adj_cols, cntA);
  scanA1<<<NCB, 512, 0, stream>>>(cntA, offs, bsumA);
  scanA2<<<1, 256, 0, stream>>>(bsumA, boffA);
  scanA3<<<NCB, 512, 0, stream>>>(offs, boffA);
  passA_scatter<<<dim3(NCHK, 2), 256, 0, stream>>>(
      adj_rows, adj_cols, adjvals, offs, edgesA, dk);
  passB_kernel<<<dim3(NCB, 2), 512, 0, stream>>>(edgesA, offs, edgesB, startsAbs);
  fp8_convert<<<(int)(NU64 / 4 + 255) / 256, 256, 0, stream>>>(E_u_0, Eu0f, (int)(NU64 / 4));
  fp8_convert<<<(int)(NI64 / 4 + 255) / 256, 256, 0, stream>>>(E_i_0, Ei0f, (int)(NI64 / 4));
  w16_prep<<<(8 * 4096 + 255) / 256, 256, 0, stream>>>(wp, Wt16);

  const int gb = (int)(B64 / 256);  // 1024
  const int sb = (NROW + 3) / 4;    // 25000 blocks, 4 waves each

  for (int l = 0; l < 2; ++l) {
    hipMemsetAsync(Mu, 0, 1024 * 4, stream);  // Mu+Mi contiguous
    svd_reduce2<<<dim3(1024, 2), 256, 0, stream>>>(
        vt, (l == 0) ? E_i_0 : Ei1, ut, (l == 0) ? E_u_0 : Eu1, Mu, Mi);
    // dir0: items -> users (noise key k3)
    spmm_row<<<sb, 256, 0, stream>>>(
        edgesB, startsAbs, (l == 0) ? Ei0f : Ei1f,
        (l == 0) ? E_u_0 : nullptr, (l == 0) ? Eu1 : nullptr,
        (l == 0) ? Eu1f : nullptr, Zu, Zdu, lk[l][2][0], lk[l][2][1], l);
    // dir1: users -> items (noise key k4)
    spmm_row<<<sb, 256, 0, stream>>>(
        edgesB, startsAbs + (NROW + 1), (l == 0) ? Eu0f : Eu1f,
        (l == 0) ? E_i_0 : nullptr, (l == 0) ? Ei1 : nullptr,
        (l == 0) ? Ei1f : nullptr, Zi, Zdi, lk[l][3][0], lk[l][3][1], l);
    gather_norm<<<dim3(gb, 3), 256, 0, stream>>>(
        uids, Zu, Zdu, u_mul_s, Mu,
        normbuf16 + (size_t)(0 + l) * B64, normbuf16 + (size_t)(4 + l) * B64,
        normbuf16 + (size_t)(8 + l) * B64);
    gather_norm<<<dim3(gb, 3), 256, 0, stream>>>(
        iids, Zi, Zdi, v_mul_s, Mi,
        normbuf16 + (size_t)(2 + l) * B64, normbuf16 + (size_t)(6 + l) * B64,
        normbuf16 + (size_t)(10 + l) * B64);
  }

  hyper_mfma<<<dim3(C_B / 64, 16), 256, 0, stream>>>(normbuf16, Wt16, hyper16);
  nce_partial<<<dim3(C_B / 128, 4, 16), 256, 0, stream>>>(normbuf16, hyper16,
                                                          rsbuf, psbuf);
  nce_final<<<dim3(C_B / 256, 16), 256, 0, stream>>>(rsbuf, psbuf, slots, nk);
  loss_r_kernel<<<gb, 256, 0, stream>>>(E_u_0, Eu1, Zu, Zdu, E_i_0, Ei1, Zi, Zdi,
                                        uids, pos, neg, slots);
  final_kernel<<<1, 1, 0, stream>>>(slots, out);
}

// Round 11
// 625.399 us; speedup vs baseline: 13.5917x; 1.0477x over previous
//
#include <hip/hip_runtime.h>
#include <hip/hip_bf16.h>
#include <cstdint>

#define C_NU 100000
#define C_NI 100000
#define C_DIM 64
#define C_Q 5
#define C_NE 2000000
#define C_B 4096
#define C_P 10
#define NROW 100000
#define NCB 196      // coarse buckets of 512 rows
#define NCHK 256     // chunks in pass A
#define CHUNK 7813   // ceil(2M/256)

typedef unsigned short u16;
typedef unsigned char u8;
typedef __attribute__((ext_vector_type(8))) short short8;
typedef __attribute__((ext_vector_type(4))) float f32x4;

__device__ static inline int rfl(int v) { return __builtin_amdgcn_readfirstlane(v); }
__device__ static inline uint32_t rflu(uint32_t v) {
  return (uint32_t)__builtin_amdgcn_readfirstlane((int)v);
}

// single-instruction exp2 (exp2f lowers to a slow OCML sequence without fast-math)
__device__ static inline float fast_exp2(float x) {
  float r;
  asm("v_exp_f32 %0, %1" : "=v"(r) : "v"(x));
  return r;
}

// ---------------- Threefry-2x32 (JAX-compatible), 20 rounds ----------------
__host__ __device__ static inline void tf2x32(uint32_t k0, uint32_t k1,
                                              uint32_t& x0, uint32_t& x1) {
  uint32_t k2 = k0 ^ k1 ^ 0x1BD11BDAu;
#define TFR(r) { x0 += x1; x1 = (x1 << r) | (x1 >> (32 - r)); x1 ^= x0; }
  x0 += k0; x1 += k1;
  TFR(13) TFR(15) TFR(26) TFR(6)
  x0 += k1; x1 += k2 + 1u;
  TFR(17) TFR(29) TFR(16) TFR(24)
  x0 += k2; x1 += k0 + 2u;
  TFR(13) TFR(15) TFR(26) TFR(6)
  x0 += k0; x1 += k1 + 3u;
  TFR(17) TFR(29) TFR(16) TFR(24)
  x0 += k1; x1 += k2 + 4u;
  TFR(13) TFR(15) TFR(26) TFR(6)
  x0 += k2; x1 += k0 + 5u;
#undef TFR
}

// partitionable-mode random bits at flat index idx (hi counter = 0)
__device__ static inline float tf_uniform(uint32_t k0, uint32_t k1, uint32_t idx) {
  uint32_t x0 = 0u, x1 = idx;
  tf2x32(k0, k1, x0, x1);
  uint32_t bits = x0 ^ x1;
  return __uint_as_float((bits >> 9) | 0x3F800000u) - 1.0f;
}

__device__ static inline float leaky(float x) { return x >= 0.f ? x : 0.5f * x; }

__device__ static inline u16 f2bf(float f) {  // RNE fp32->bf16
  uint32_t x = __float_as_uint(f);
  return (u16)((x + 0x7FFFu + ((x >> 16) & 1u)) >> 16);
}
__device__ static inline float bf2f(u16 u) {
  return __uint_as_float((uint32_t)u << 16);
}

// fp8 store: byte = sign | 7-bit (4-exp,3-mant) of (x*256), RNE, underflow->0.
__device__ static inline u8 f2fp8(float x) {
  float t = x * 256.f;
  uint32_t sgn = (__float_as_uint(t) >> 24) & 0x80u;
  float a = fabsf(t) * 0x1p-120f;
  uint32_t u = __float_as_uint(a);
  u += 0x7FFFFu + ((u >> 20) & 1u);
  uint32_t mag = u >> 20;
  if (mag > 0x7Fu) mag = 0x7Fu;
  return (u8)(sgn | mag);
}

// ---------------- constant maps for the 16 info_nce calls ----------------
// normbuf slots: 0:Zu1 1:Zu2 2:Zi1 3:Zi2 4:Zdu1 5:Zdu2 6:Zdi1 7:Zdi2 8:Gu1 9:Gu2 10:Gi1 11:Gi2
__constant__ int c_gsel[16] = {0,1,2,3, 0,2, 4,5,6,7, 4,6, 0,1,2,3};
__constant__ int c_hsrc[16] = {8,9,10,11, 1,3, 8,9,10,11, 5,7, 4,5,6,7};
// W order: 0:ng0 1:ng1 2:nn 3:dg0 4:dg1 5:dd 6:nd0 7:nd1
__constant__ int c_wsel[16] = {0,1,0,1, 2,2, 3,4,3,4, 5,5, 6,7,6,7};
// slots: 0:n 1:d 2:nn 3:dd 4:nd (5: loss_r sum)
__constant__ int c_slot[16] = {0,0,0,0, 2,2, 1,1,1,1, 3,3, 4,4,4,4};

struct WPtrs { const float* W[8]; };
struct NceKeys { uint32_t k0[16]; uint32_t k1[16]; };
struct DropKeys { uint32_t a[8]; };
struct SpmmArgs {
  const u8* Einf[2];
  const float* Eprev[2];
  float* Enext[2];
  u8* Enf8[2];
  u16* Z[2];
  u16* Zd[2];
  uint32_t nk[2][2];
};

// ---------------- two-level counting sort ----------------

__global__ __launch_bounds__(256) void passA_hist(
    const int* __restrict__ rows, const int* __restrict__ cols,
    uint32_t* __restrict__ cntA) {
  __shared__ uint32_t h[NCB];
  const int dir = blockIdx.y, c = blockIdx.x, t = threadIdx.x;
  for (int i = t; i < NCB; i += 256) h[i] = 0u;
  __syncthreads();
  const int e0 = c * CHUNK, e1 = min(e0 + CHUNK, C_NE);
  const int* ids = dir ? cols : rows;
  for (int e = e0 + t; e < e1; e += 256) atomicAdd(&h[ids[e] >> 9], 1u);
  __syncthreads();
  for (int i = t; i < NCB; i += 256) cntA[(dir * NCB + i) * NCHK + c] = h[i];
}

__global__ __launch_bounds__(512) void scanA1(
    const uint32_t* __restrict__ cntA, uint32_t* __restrict__ offs,
    uint32_t* __restrict__ bsum) {
  __shared__ uint32_t s[512];
  const int b = blockIdx.x, t = threadIdx.x;
  const int idx = b * 512 + t;
  uint32_t v = cntA[idx];
  s[t] = v;
  __syncthreads();
  for (int off = 1; off < 512; off <<= 1) {
    uint32_t a = (t >= off) ? s[t - off] : 0u;
    __syncthreads();
    s[t] += a;
    __syncthreads();
  }
  offs[idx] = s[t] - v;
  if (t == 511) bsum[b] = s[511];
}

__global__ __launch_bounds__(256) void scanA2(
    const uint32_t* __restrict__ bsum, uint32_t* __restrict__ boff) {
  __shared__ uint32_t s[256];
  const int t = threadIdx.x;
  uint32_t v = (t < NCB) ? bsum[t] : 0u;
  s[t] = v;
  __syncthreads();
  for (int off = 1; off < 256; off <<= 1) {
    uint32_t a = (t >= off) ? s[t - off] : 0u;
    __syncthreads();
    s[t] += a;
    __syncthreads();
  }
  if (t < NCB) boff[t] = s[t] - v;
}

__global__ __launch_bounds__(512) void scanA3(
    uint32_t* __restrict__ offs, const uint32_t* __restrict__ boff) {
  offs[blockIdx.x * 512 + threadIdx.x] += boff[blockIdx.x];
}

// record.x = src(17b) | keepL0<<17 | keepL1<<18 | (dst&511)<<19
__global__ __launch_bounds__(256) void passA_scatter(
    const int* __restrict__ rows, const int* __restrict__ cols,
    const float* __restrict__ vals, const uint32_t* __restrict__ offs,
    uint2* __restrict__ edgesA, DropKeys dk) {
  __shared__ uint32_t lofs[NCB];
  const int dir = blockIdx.y, c = blockIdx.x, t = threadIdx.x;
  for (int i = t; i < NCB; i += 256) lofs[i] = offs[(dir * NCB + i) * NCHK + c];
  __syncthreads();
  const int e0 = c * CHUNK, e1 = min(e0 + CHUNK, C_NE);
  const uint32_t kA0 = dk.a[dir * 4 + 0], kA1 = dk.a[dir * 4 + 1];
  const uint32_t kB0 = dk.a[dir * 4 + 2], kB1 = dk.a[dir * 4 + 3];
  for (int e = e0 + t; e < e1; e += 256) {
    const int r = rows[e], cc = cols[e];
    const int dst = dir ? cc : r, src = dir ? r : cc;
    const uint32_t kl0 = (tf_uniform(kA0, kA1, (uint32_t)e) < 0.9f) ? 1u : 0u;
    const uint32_t kl1 = (tf_uniform(kB0, kB1, (uint32_t)e) < 0.9f) ? 1u : 0u;
    const uint32_t x = (uint32_t)src | (kl0 << 17) | (kl1 << 18) |
                       ((uint32_t)(dst & 511) << 19);
    const uint32_t pos = atomicAdd(&lofs[dst >> 9], 1u);
    edgesA[pos] = make_uint2(x, __float_as_uint(vals[e]));
  }
}

__global__ __launch_bounds__(512) void passB_kernel(
    const uint2* __restrict__ edgesA, const uint32_t* __restrict__ offs,
    uint2* __restrict__ edgesB, uint32_t* __restrict__ starts) {
  __shared__ uint32_t cnt[512];
  __shared__ uint32_t scn[512];
  const int dir = blockIdx.y, cb = blockIdx.x, t = threadIdx.x;
  const uint32_t segStart = offs[(dir * NCB + cb) * NCHK];
  const uint32_t segEnd = (dir == 1 && cb == NCB - 1)
                              ? (uint32_t)(2 * C_NE)
                              : offs[(dir * NCB + cb + 1) * NCHK];
  cnt[t] = 0u;
  __syncthreads();
  for (uint32_t e = segStart + t; e < segEnd; e += 512)
    atomicAdd(&cnt[(edgesA[e].x >> 19) & 511u], 1u);
  __syncthreads();
  uint32_t v = cnt[t];
  scn[t] = v;
  __syncthreads();
  for (int off = 1; off < 512; off <<= 1) {
    uint32_t a = (t >= off) ? scn[t - off] : 0u;
    __syncthreads();
    scn[t] += a;
    __syncthreads();
  }
  const uint32_t rstart = segStart + scn[t] - v;
  const int grow = cb * 512 + t;
  if (grow < NROW) starts[dir * (NROW + 1) + grow] = rstart;
  if (cb == NCB - 1 && t == 0) starts[dir * (NROW + 1) + NROW] = segEnd;
  cnt[t] = rstart;
  __syncthreads();
  for (uint32_t e = segStart + t; e < segEnd; e += 512) {
    const uint2 q = edgesA[e];
    const uint32_t pos = atomicAdd(&cnt[(q.x >> 19) & 511u], 1u);
    edgesB[pos] = q;
  }
}

// ---------------- fp32 -> fp8 table convert ----------------
__global__ __launch_bounds__(256) void fp8_convert(
    const float* __restrict__ src, u8* __restrict__ dst, int n4) {
  int i = blockIdx.x * 256 + threadIdx.x;
  if (i >= n4) return;
  float4 v = ((const float4*)src)[i];
  uint32_t o = (uint32_t)f2fp8(v.x) | ((uint32_t)f2fp8(v.y) << 8) |
               ((uint32_t)f2fp8(v.z) << 16) | ((uint32_t)f2fp8(v.w) << 24);
  ((uint32_t*)dst)[i] = o;
}

// Wt16[w][d][k] = bf16(W[w][k][d])  (pre-transposed for MFMA B-operand)
__global__ __launch_bounds__(256) void w16_prep(WPtrs wp, u16* __restrict__ Wt16) {
  int i = blockIdx.x * 256 + threadIdx.x;
  if (i >= 8 * 4096) return;
  int w = i >> 12, kd = i & 4095, k = kd >> 6, d = kd & 63;
  Wt16[w * 4096 + d * 64 + k] = f2bf(wp.W[w][k * 64 + d]);
}

// ---------------- fused spmm (wave/row, scalarized, fp8, both dirs) ----------------
__global__ __launch_bounds__(256) void spmm_row(
    const uint2* __restrict__ edges, const uint32_t* __restrict__ startsAbs,
    SpmmArgs a, int layer) {
  const int dir = blockIdx.y;
  const int row = rfl(blockIdx.x * 4 + (threadIdx.x >> 6));
  const int lane = threadIdx.x & 63;
  if (row >= NROW) return;
  const uint32_t* starts = startsAbs + dir * (NROW + 1);
  const u8* __restrict__ Einf = a.Einf[dir];
  const uint32_t s0 = rflu(starts[row]);
  const uint32_t s1 = rflu(starts[row + 1]);
  const uint32_t kbit = 1u << (17 + layer);
  const float VS = 0x1p112f;  // fp8 decode scale (2^120) * table scale (2^-8)
  float z = 0.f, zd = 0.f;
  uint32_t e = s0;
  for (; e + 4 <= s1; e += 4) {
    const uint32_t p0 = rflu(edges[e].x),     w0 = rflu(edges[e].y);
    const uint32_t p1 = rflu(edges[e + 1].x), w1 = rflu(edges[e + 1].y);
    const uint32_t p2 = rflu(edges[e + 2].x), w2 = rflu(edges[e + 2].y);
    const uint32_t p3 = rflu(edges[e + 3].x), w3 = rflu(edges[e + 3].y);
    const uint32_t b0 = Einf[(size_t)(p0 & 0x1FFFFu) * 64 + lane];
    const uint32_t b1 = Einf[(size_t)(p1 & 0x1FFFFu) * 64 + lane];
    const uint32_t b2 = Einf[(size_t)(p2 & 0x1FFFFu) * 64 + lane];
    const uint32_t b3 = Einf[(size_t)(p3 & 0x1FFFFu) * 64 + lane];
    const float x0 = __uint_as_float(((b0 & 0x80u) << 24) | ((b0 & 0x7Fu) << 20));
    const float x1 = __uint_as_float(((b1 & 0x80u) << 24) | ((b1 & 0x7Fu) << 20));
    const float x2 = __uint_as_float(((b2 & 0x80u) << 24) | ((b2 & 0x7Fu) << 20));
    const float x3 = __uint_as_float(((b3 & 0x80u) << 24) | ((b3 & 0x7Fu) << 20));
    const float v0 = __uint_as_float(w0) * VS, v1 = __uint_as_float(w1) * VS;
    const float v2 = __uint_as_float(w2) * VS, v3 = __uint_as_float(w3) * VS;
    const float d0 = (p0 & kbit) ? v0 : 0.f;
    const float d1 = (p1 & kbit) ? v1 : 0.f;
    const float d2 = (p2 & kbit) ? v2 : 0.f;
    const float d3 = (p3 & kbit) ? v3 : 0.f;
    z += v0 * x0; zd += d0 * x0;
    z += v1 * x1; zd += d1 * x1;
    z += v2 * x2; zd += d2 * x2;
    z += v3 * x3; zd += d3 * x3;
  }
  for (; e < s1; ++e) {
    const uint32_t p = rflu(edges[e].x), wv = rflu(edges[e].y);
    const uint32_t b = Einf[(size_t)(p & 0x1FFFFu) * 64 + lane];
    const float x = __uint_as_float(((b & 0x80u) << 24) | ((b & 0x7Fu) << 20));
    const float v = __uint_as_float(wv) * VS;
    z += v * x;
    zd += ((p & kbit) ? v : 0.f) * x;
  }
  z = leaky(z);
  zd = leaky(zd * (1.0f / 0.9f));
  // noise-augmented view
  const float u = tf_uniform(a.nk[dir][0], a.nk[dir][1],
                             (uint32_t)row * 64u + (uint32_t)lane);
  float ss = u * u;
#pragma unroll
  for (int off = 1; off < 64; off <<= 1) ss += __shfl_xor(ss, off);
  const float nrm = fmaxf(sqrtf(ss), 1e-12f);
  const float sg = (z > 0.f) ? 1.f : (z < 0.f ? -1.f : 0.f);
  z += sg * (u / nrm) * 0.1f;
  const size_t j = (size_t)row * 64 + lane;
  a.Z[dir][j] = f2bf(z);
  a.Zd[dir][j] = f2bf(zd);
  if (a.Enext[dir]) {  // layer 0 only
    const float en = z + zd + a.Eprev[dir][j];
    a.Enext[dir][j] = en;
    a.Enf8[dir][j] = f2fp8(en);
  }
}

// ---------------- dual-dir SVD middle matrix, block-reduced atomics ----------------
__global__ __launch_bounds__(256) void svd_reduce2(
    const float* __restrict__ T0, const float* __restrict__ E0,
    const float* __restrict__ T1, const float* __restrict__ E1,
    float* __restrict__ Mu, float* __restrict__ Mi) {
  const int dir = blockIdx.y;
  const float* __restrict__ T = dir ? T1 : T0;
  const float* __restrict__ E = dir ? E1 : E0;
  float* __restrict__ M = dir ? Mi : Mu;
  const int lane = threadIdx.x & 63;
  const int wl = threadIdx.x >> 6;
  const int gw = blockIdx.x * 4 + wl;
  float a0 = 0.f, a1 = 0.f, a2 = 0.f, a3 = 0.f, a4 = 0.f;
  for (int i = gw; i < NROW; i += 4096) {
    const float x = E[(size_t)i * 64 + lane];
    a0 += T[i] * x;
    a1 += T[NROW + i] * x;
    a2 += T[2 * NROW + i] * x;
    a3 += T[3 * NROW + i] * x;
    a4 += T[4 * NROW + i] * x;
  }
  __shared__ float red[4][5][64];
  red[wl][0][lane] = a0; red[wl][1][lane] = a1; red[wl][2][lane] = a2;
  red[wl][3][lane] = a3; red[wl][4][lane] = a4;
  __syncthreads();
  for (int o = threadIdx.x; o < 320; o += 256) {
    const int q = o >> 6, d = o & 63;
    const float s = red[0][q][d] + red[1][q][d] + red[2][q][d] + red[3][q][d];
    atomicAdd(&M[o], s);
  }
}

// gather batch rows & L2-normalize -> bf16; blockIdx.y selects {Z, Zd, G}
__global__ __launch_bounds__(256) void gather_norm(
    const int* __restrict__ ids, const u16* __restrict__ Z,
    const u16* __restrict__ Zd, const float* __restrict__ mul_s,
    const float* __restrict__ M, u16* __restrict__ oZ,
    u16* __restrict__ oZd, u16* __restrict__ oG) {
  long long t = (long long)blockIdx.x * blockDim.x + threadIdx.x;
  int b = (int)(t >> 6);
  int d = (int)(t & 63);
  if (b >= C_B) return;
  int id = rfl(ids[b]);
  float v;
  u16* out;
  if (blockIdx.y == 0) { v = bf2f(Z[(size_t)id * 64 + d]); out = oZ; }
  else if (blockIdx.y == 1) { v = bf2f(Zd[(size_t)id * 64 + d]); out = oZd; }
  else {
    float s = 0.f;
#pragma unroll
    for (int q = 0; q < 5; ++q) s += mul_s[(size_t)id * 5 + q] * M[q * 64 + d];
    v = leaky(s);
    out = oG;
  }
  float ss = v * v;
#pragma unroll
  for (int off = 1; off < 64; off <<= 1) ss += __shfl_xor(ss, off);
  float nrm = fmaxf(sqrtf(ss), 1e-12f);
  out[(size_t)b * 64 + d] = f2bf(v / nrm);
}

// ---------------- MFMA hyper (LDS-free): hy = (X @ W) * log2e/TEMP ----------------
__global__ __launch_bounds__(256) void hyper_mfma(
    const u16* __restrict__ nb, const u16* __restrict__ Wt16,
    u16* __restrict__ hy) {
  const int call = blockIdx.y;
  const int b0 = blockIdx.x * 64;
  const int lane = threadIdx.x & 63, wid = threadIdx.x >> 6;
  const u16* X = nb + (size_t)c_hsrc[call] * C_B * 64;
  const u16* Wt = Wt16 + (size_t)c_wsel[call] * 4096;
  const int am = (wid << 4) + (lane & 15);
  const int ke = ((lane >> 4) << 3);  // fragment k-offset (elements)
  short8 af[2];
#pragma unroll
  for (int ks = 0; ks < 2; ++ks)
    af[ks] = *(const short8*)&X[(size_t)(b0 + am) * 64 + ks * 32 + ke];
  const int ob = b0 + (wid << 4) + ((lane >> 4) << 2);
#pragma unroll
  for (int n = 0; n < 4; ++n) {
    const int bn = (n << 4) + (lane & 15);
    f32x4 acc = {0.f, 0.f, 0.f, 0.f};
#pragma unroll
    for (int ks = 0; ks < 2; ++ks) {
      short8 bf = *(const short8*)&Wt[(size_t)bn * 64 + ks * 32 + ke];
      acc = __builtin_amdgcn_mfma_f32_16x16x32_bf16(af[ks], bf, acc, 0, 0, 0);
    }
    const int d = (n << 4) + (lane & 15);
#pragma unroll
    for (int j = 0; j < 4; ++j)
      hy[(size_t)call * C_B * 64 + (size_t)(ob + j) * 64 + d] =
          f2bf(acc[j] * 7.2134752f);  // fold log2(e)/TEMP into H
  }
}

// ---------------- MFMA info_nce partials: 128 g-rows x 16 H-tiles per block ----
// grid: (32 g-tiles, 4 jt-chunks, 16 calls); G fragments loaded direct from global
__global__ __launch_bounds__(256) void nce_partial(
    const u16* __restrict__ nb, const u16* __restrict__ hy,
    float* __restrict__ rsbuf, float* __restrict__ psbuf) {
  const int call = blockIdx.z;
  const int jc = blockIdx.y;
  const u16* G = nb + (size_t)c_gsel[call] * C_B * 64;
  const u16* H = hy + (size_t)call * C_B * 64;
  const int br = blockIdx.x * 128;
  const int jt0 = jc * 16;
  __shared__ u16 Hs[2][64 * 64];
  const int tid = threadIdx.x, lane = tid & 63, wid = tid >> 6;
  const int ke = ((lane >> 4) << 3);
  // direct-load G fragments (identical data to the verified swizzled-LDS read)
  short8 bfG[2][2];
#pragma unroll
  for (int s = 0; s < 2; ++s)
#pragma unroll
    for (int ks = 0; ks < 2; ++ks) {
      const int gc = (wid << 5) + (s << 4) + (lane & 15);
      bfG[s][ks] = *(const short8*)&G[(size_t)(br + gc) * 64 + ks * 32 + ke];
    }
  const int r = tid >> 2, seg = tid & 3;
  const int base = r * 128 + seg * 32, sw = (r & 7) << 4;
  {
    const uint4* src = (const uint4*)&H[(size_t)(jt0 * 64 + r) * 64 + seg * 16];
    uint4 a = src[0], b = src[1];
    *(uint4*)((char*)Hs[0] + (base ^ sw)) = a;
    *(uint4*)((char*)Hs[0] + ((base + 16) ^ sw)) = b;
  }
  float rs[2] = {0.f, 0.f}, ps[2] = {0.f, 0.f};
  const int jt_diag = (blockIdx.x << 1) + (wid >> 1);
  const int hsd0 = (wid & 1) << 1;
  int cur = 0;
  for (int jt = jt0; jt < jt0 + 16; ++jt) {
    __syncthreads();  // Hs[cur] ready
    uint4 na, nb_;
    if (jt + 1 < jt0 + 16) {  // prefetch next H tile
      const uint4* src = (const uint4*)&H[(size_t)((jt + 1) * 64 + r) * 64 + seg * 16];
      na = src[0]; nb_ = src[1];
    }
    const bool dj = (jt == jt_diag);
    const char* Hb = (const char*)(Hs[cur]);
#pragma unroll
    for (int hs = 0; hs < 4; ++hs) {
      const int hr = (hs << 4) + (lane & 15);
      const int offA0 = (hr * 128 + ((lane >> 4) << 4)) ^ ((hr & 7) << 4);
      const int offA1 = (hr * 128 + 64 + ((lane >> 4) << 4)) ^ ((hr & 7) << 4);
      const short8 af0 = *(const short8*)(Hb + offA0);
      const short8 af1 = *(const short8*)(Hb + offA1);
      f32x4 acc0 = {0.f, 0.f, 0.f, 0.f}, acc1 = {0.f, 0.f, 0.f, 0.f};
      __builtin_amdgcn_s_setprio(1);
      acc0 = __builtin_amdgcn_mfma_f32_16x16x32_bf16(af0, bfG[0][0], acc0, 0, 0, 0);
      acc0 = __builtin_amdgcn_mfma_f32_16x16x32_bf16(af1, bfG[0][1], acc0, 0, 0, 0);
      acc1 = __builtin_amdgcn_mfma_f32_16x16x32_bf16(af0, bfG[1][0], acc1, 0, 0, 0);
      acc1 = __builtin_amdgcn_mfma_f32_16x16x32_bf16(af1, bfG[1][1], acc1, 0, 0, 0);
      __builtin_amdgcn_s_setprio(0);
      float e0[4], e1[4];
#pragma unroll
      for (int j = 0; j < 4; ++j) {
        e0[j] = fast_exp2(acc0[j]);  // H pre-scaled by log2e/TEMP
        e1[j] = fast_exp2(acc1[j]);
      }
      rs[0] += (e0[0] + e0[1]) + (e0[2] + e0[3]);
      rs[1] += (e1[0] + e1[1]) + (e1[2] + e1[3]);
      if (dj) {
        const int jm = (lane & 15) - ((lane >> 4) << 2);
        if (hs == hsd0) {
#pragma unroll
          for (int j = 0; j < 4; ++j)
            if (jm == j) ps[0] = e0[j];
        }
        if (hs == hsd0 + 1) {
#pragma unroll
          for (int j = 0; j < 4; ++j)
            if (jm == j) ps[1] = e1[j];
        }
      }
    }
    if (jt + 1 < jt0 + 16) {
      *(uint4*)((char*)Hs[cur ^ 1] + (base ^ sw)) = na;
      *(uint4*)((char*)Hs[cur ^ 1] + ((base + 16) ^ sw)) = nb_;
    }
    cur ^= 1;
  }
#pragma unroll
  for (int s = 0; s < 2; ++s) {
    rs[s] += __shfl_xor(rs[s], 16); rs[s] += __shfl_xor(rs[s], 32);
    ps[s] += __shfl_xor(ps[s], 16); ps[s] += __shfl_xor(ps[s], 32);
  }
  if ((lane >> 4) == 0) {
    const bool own_diag = ((jt_diag >> 4) == jc);  // wave-uniform
#pragma unroll
    for (int s = 0; s < 2; ++s) {
      const int gg = br + (wid << 5) + (s << 4) + (lane & 15);
      atomicAdd(&rsbuf[(size_t)call * C_B + gg], rs[s]);
      if (own_diag) psbuf[(size_t)call * C_B + gg] = ps[s];
    }
  }
}

// finalize: v = -log(ps/(rs+eps)+eps), mask, reduce to slots
__global__ __launch_bounds__(256) void nce_final(
    const float* __restrict__ rsbuf, const float* __restrict__ psbuf,
    float* __restrict__ slots, NceKeys nk) {
  const int call = blockIdx.y;
  const int g = blockIdx.x * 256 + threadIdx.x;
  const float rs = rsbuf[(size_t)call * C_B + g];
  const float ps = psbuf[(size_t)call * C_B + g];
  const float v = -__logf(ps / (rs + 1e-8f) + 1e-8f);
  const float u = tf_uniform(nk.k0[call], nk.k1[call], (uint32_t)g);
  float c = (u > 0.5f) ? v : 0.f;
#pragma unroll
  for (int off = 1; off < 64; off <<= 1) c += __shfl_xor(c, off);
  __shared__ float wsum[4];
  if ((threadIdx.x & 63) == 0) wsum[threadIdx.x >> 6] = c;
  __syncthreads();
  if (threadIdx.x == 0)
    atomicAdd(&slots[c_slot[call]], wsum[0] + wsum[1] + wsum[2] + wsum[3]);
}

// E_sum = E0 + 2*E1 + Z2 + Zd2  (E2 never materialized; Z in bf16)
__global__ __launch_bounds__(256) void loss_r_kernel(
    const float* __restrict__ E0u, const float* __restrict__ Eu1,
    const u16* __restrict__ Zu, const u16* __restrict__ Zdu,
    const float* __restrict__ E0i, const float* __restrict__ Ei1,
    const u16* __restrict__ Zi, const u16* __restrict__ Zdi,
    const int* __restrict__ uids, const int* __restrict__ pos,
    const int* __restrict__ neg, float* __restrict__ slots) {
  long long t = (long long)blockIdx.x * blockDim.x + threadIdx.x;
  int b = (int)(t >> 6);
  int d = (int)(t & 63);
  if (b >= C_B) return;
  size_t ju = (size_t)rfl(uids[b]) * 64 + d;
  float u = E0u[ju] + 2.f * Eu1[ju] + bf2f(Zu[ju]) + bf2f(Zdu[ju]);
  float bpr = 0.f, pmin = 3.4e38f, nmax = -3.4e38f;
  for (int p = 0; p < C_P; ++p) {
    size_t jp = (size_t)rfl(pos[b * C_P + p]) * 64 + d;
    size_t jn = (size_t)rfl(neg[b * C_P + p]) * 64 + d;
    float pe = E0i[jp] + 2.f * Ei1[jp] + bf2f(Zi[jp]) + bf2f(Zdi[jp]);
    float ne = E0i[jn] + 2.f * Ei1[jn] + bf2f(Zi[jn]) + bf2f(Zdi[jn]);
    float psc = u * pe, nsc = u * ne;
#pragma unroll
    for (int off = 1; off < 64; off <<= 1) {
      psc += __shfl_xor(psc, off);
      nsc += __shfl_xor(nsc, off);
    }
    pmin = fminf(pmin, psc);
    nmax = fmaxf(nmax, nsc);
    bpr += fmaxf(1.f - psc + nsc, 0.f);
  }
  if (d == 0) {
    float hd = (nmax - pmin > 0.005f) ? 10.f * (nmax - pmin) : 0.f;
    atomicAdd(&slots[5], bpr + hd);
  }
}

__global__ void final_kernel(const float* __restrict__ slots, float* __restrict__ out) {
  if (threadIdx.x == 0 && blockIdx.x == 0) {
    float n = slots[0], dl = slots[1], nn = slots[2], dd = slots[3], nd = slots[4];
    float lr = slots[5] / (float)C_B;
    out[0] = lr + 0.2f * (n + dl) + 0.2f * (nn + dd + nd);
    out[1] = lr;
    out[2] = dl;
    out[3] = n;
  }
}

// ---------------- host ----------------
extern "C" void kernel_launch(void* const* d_in, const int* in_sizes, int n_in,
                              void* d_out, int out_size, void* d_ws, size_t ws_size,
                              hipStream_t stream) {
  (void)in_sizes; (void)n_in; (void)out_size;
  const float* E_u_0   = (const float*)d_in[0];
  const float* E_i_0   = (const float*)d_in[1];
  const float* adjvals = (const float*)d_in[2];
  const float* u_mul_s = (const float*)d_in[3];
  const float* v_mul_s = (const float*)d_in[4];
  const float* ut      = (const float*)d_in[5];
  const float* vt      = (const float*)d_in[6];
  const float* W_nn    = (const float*)d_in[7];
  const float* W_dd    = (const float*)d_in[8];
  const float* W_ng    = (const float*)d_in[9];
  const float* W_dg    = (const float*)d_in[10];
  const float* W_nd    = (const float*)d_in[11];
  const int* adj_rows  = (const int*)d_in[12];
  const int* adj_cols  = (const int*)d_in[13];
  const int* uids      = (const int*)d_in[14];
  const int* iids      = (const int*)d_in[15];
  const int* pos       = (const int*)d_in[16];
  const int* neg       = (const int*)d_in[17];
  float* out = (float*)d_out;

  const size_t NU64 = (size_t)C_NU * 64;
  const size_t NI64 = (size_t)C_NI * 64;
  const size_t B64  = (size_t)C_B * 64;

  float* w = (float*)d_ws;
  float* Eu1 = w; w += NU64;
  float* Ei1 = w; w += NI64;
  u16* Zu  = (u16*)w;            // 4 contiguous bf16 Z buffers; edgesA aliases
  u16* Zdu = Zu + NU64;
  u16* Zi  = Zdu + NU64;
  u16* Zdi = Zi + NI64;
  w += 2 * NU64;                 // 4 * NU64 u16 = 2 * NU64 floats
  float* Mu = w; w += 512;
  float* Mi = w; w += 512;
  u16* normbuf16 = (u16*)w; w += 6 * B64;     // 12 bf16 buffers of B64
  float* slots = w; w += 16;
  uint2* edgesB = (uint2*)w; w += 4 * C_NE;   // 32 MB final CSR (both dirs)
  u16* hyper16 = (u16*)edgesB;                // alias: edgesB dead before hyper
  u16* Wt16 = (u16*)w; w += 16384;
  uint32_t* cntA = (uint32_t*)w; w += NCB * NCHK * 2;
  uint32_t* offs = (uint32_t*)w; w += NCB * NCHK * 2;
  uint32_t* bsumA = (uint32_t*)w; w += NCB;
  uint32_t* boffA = (uint32_t*)w; w += NCB;
  uint32_t* startsAbs = (uint32_t*)w; w += 2 * (NROW + 1);
  u8* Eu0f = (u8*)w; w += NU64 / 4;           // fp8 gather tables
  u8* Ei0f = (u8*)w; w += NI64 / 4;
  u8* Eu1f = (u8*)w; w += NU64 / 4;
  u8* Ei1f = Ei0f;                            // alias: Ei0f dead after layer 0
  float* rsbuf = w; w += 16 * C_B;            // nce partial denominators
  float* psbuf = w; w += 16 * C_B;            // nce diag numerators
  uint2* edgesA = (uint2*)Zu;                 // 32 MB coarse buffer (< Zu..Zi)
  if ((size_t)((char*)w - (char*)d_ws) > ws_size) return;

  // ---- host-side JAX key derivation (partitionable threefry) ----
  auto ksplit = [](uint32_t a, uint32_t b, uint32_t idx, uint32_t& o0, uint32_t& o1) {
    uint32_t x0 = 0u, x1 = idx;
    tf2x32(a, b, x0, x1);
    o0 = x0; o1 = x1;
  };
  uint32_t rk0 = 0u, rk1 = 42u;
  uint32_t lk[2][4][2];
  for (int l = 0; l < 2; ++l) {
    uint32_t n0, n1;
    ksplit(rk0, rk1, 0u, n0, n1);
    for (int i = 0; i < 4; ++i) ksplit(rk0, rk1, (uint32_t)(i + 1), lk[l][i][0], lk[l][i][1]);
    rk0 = n0; rk1 = n1;
  }
  NceKeys nk;
  {
    uint32_t mk0 = 0u, mk1 = 7u;
    for (int i = 0; i < 16; ++i) {
      uint32_t n0, n1;
      ksplit(mk0, mk1, 0u, n0, n1);
      ksplit(mk0, mk1, 1u, nk.k0[i], nk.k1[i]);
      mk0 = n0; mk1 = n1;
    }
  }
  DropKeys dk;
  dk.a[0] = lk[0][0][0]; dk.a[1] = lk[0][0][1];
  dk.a[2] = lk[1][0][0]; dk.a[3] = lk[1][0][1];
  dk.a[4] = lk[0][1][0]; dk.a[5] = lk[0][1][1];
  dk.a[6] = lk[1][1][0]; dk.a[7] = lk[1][1][1];
  WPtrs wp;
  wp.W[0] = W_ng; wp.W[1] = W_ng + 4096;
  wp.W[2] = W_nn;
  wp.W[3] = W_dg; wp.W[4] = W_dg + 4096;
  wp.W[5] = W_dd;
  wp.W[6] = W_nd; wp.W[7] = W_nd + 4096;

  // ---- sort + preps ----
  hipMemsetAsync(slots, 0, 16 * 4, stream);
  hipMemsetAsync(rsbuf, 0, 16 * C_B * 4, stream);
  passA_hist<<<dim3(NCHK, 2), 256, 0, stream>>>(adj_rows, adj_cols, cntA);
  scanA1<<<NCB, 512, 0, stream>>>(cntA, offs, bsumA);
  scanA2<<<1, 256, 0, stream>>>(bsumA, boffA);
  scanA3<<<NCB, 512, 0, stream>>>(offs, boffA);
  passA_scatter<<<dim3(NCHK, 2), 256, 0, stream>>>(
      adj_rows, adj_cols, adjvals, offs, edgesA, dk);
  passB_kernel<<<dim3(NCB, 2), 512, 0, stream>>>(edgesA, offs, edgesB, startsAbs);
  fp8_convert<<<(int)(NU64 / 4 + 255) / 256, 256, 0, stream>>>(E_u_0, Eu0f, (int)(NU64 / 4));
  fp8_convert<<<(int)(NI64 / 4 + 255) / 256, 256, 0, stream>>>(E_i_0, Ei0f, (int)(NI64 / 4));
  w16_prep<<<(8 * 4096 + 255) / 256, 256, 0, stream>>>(wp, Wt16);

  const int gb = (int)(B64 / 256);  // 1024
  const int sb = (NROW + 3) / 4;    // 25000 blocks, 4 waves each

  for (int l = 0; l < 2; ++l) {
    hipMemsetAsync(Mu, 0, 1024 * 4, stream);  // Mu+Mi contiguous
    svd_reduce2<<<dim3(1024, 2), 256, 0, stream>>>(
        vt, (l == 0) ? E_i_0 : Ei1, ut, (l == 0) ? E_u_0 : Eu1, Mu, Mi);
    SpmmArgs sa;
    sa.Einf[0] = (l == 0) ? Ei0f : Ei1f;  // dir0 gathers items
    sa.Einf[1] = (l == 0) ? Eu0f : Eu1f;  // dir1 gathers users
    sa.Eprev[0] = (l == 0) ? E_u_0 : nullptr;
    sa.Eprev[1] = (l == 0) ? E_i_0 : nullptr;
    sa.Enext[0] = (l == 0) ? Eu1 : nullptr;
    sa.Enext[1] = (l == 0) ? Ei1 : nullptr;
    sa.Enf8[0] = (l == 0) ? Eu1f : nullptr;
    sa.Enf8[1] = (l == 0) ? Ei1f : nullptr;
    sa.Z[0] = Zu; sa.Zd[0] = Zdu;
    sa.Z[1] = Zi; sa.Zd[1] = Zdi;
    sa.nk[0][0] = lk[l][2][0]; sa.nk[0][1] = lk[l][2][1];
    sa.nk[1][0] = lk[l][3][0]; sa.nk[1][1] = lk[l][3][1];
    spmm_row<<<dim3(sb, 2), 256, 0, stream>>>(edgesB, startsAbs, sa, l);
    gather_norm<<<dim3(gb, 3), 256, 0, stream>>>(
        uids, Zu, Zdu, u_mul_s, Mu,
        normbuf16 + (size_t)(0 + l) * B64, normbuf16 + (size_t)(4 + l) * B64,
        normbuf16 + (size_t)(8 + l) * B64);
    gather_norm<<<dim3(gb, 3), 256, 0, stream>>>(
        iids, Zi, Zdi, v_mul_s, Mi,
        normbuf16 + (size_t)(2 + l) * B64, normbuf16 + (size_t)(6 + l) * B64,
        normbuf16 + (size_t)(10 + l) * B64);
  }

  hyper_mfma<<<dim3(C_B / 64, 16), 256, 0, stream>>>(normbuf16, Wt16, hyper16);
  nce_partial<<<dim3(C_B / 128, 4, 16), 256, 0, stream>>>(normbuf16, hyper16,
                                                          rsbuf, psbuf);
  nce_final<<<dim3(C_B / 256, 16), 256, 0, stream>>>(rsbuf, psbuf, slots, nk);
  loss_r_kernel<<<gb, 256, 0, stream>>>(E_u_0, Eu1, Zu, Zdu, E_i_0, Ei1, Zi, Zdi,
                                        uids, pos, neg, slots);
  final_kernel<<<1, 1, 0, stream>>>(slots, out);
}